// Round 16
// baseline (356.488 us; speedup 1.0000x reference)
//
#include <hip/hip_runtime.h>
#include <math.h>

#define NPT 2048
#define BB 4
#define KNN 20
#define EPSV 1e-6f

typedef unsigned short u16;
typedef unsigned int u32;
typedef _Float16 half8 __attribute__((ext_vector_type(8)));
typedef __attribute__((ext_vector_type(4))) float f32x4;
typedef __attribute__((ext_vector_type(4))) u32 uint4v;

#define MFMAH(a,b,c) __builtin_amdgcn_mfma_f32_16x16x32_f16((a),(b),(c),0,0,0)

__device__ __forceinline__ u16 f2h(float f) {
    _Float16 h = (_Float16)f;
    return __builtin_bit_cast(u16, h);
}
__device__ __forceinline__ float h2f(u16 b) {
    return (float)__builtin_bit_cast(_Float16, b);
}

// -------------------- kNN top-20 (radix-select) + fused edge conv + mean_k
__global__ __launch_bounds__(256)
void knn_edge_kernel(const float* __restrict__ p,
                     const float* __restrict__ wf, const float* __restrict__ wd,
                     u16* __restrict__ net1) {
    int bn = blockIdx.x;
    int b = bn >> 11, n = bn & (NPT - 1);
    const float* pb = p + (size_t)b * NPT * 3;
    float qx = pb[n*3+0], qy = pb[n*3+1], qz = pb[n*3+2];
    float qq = qx*qx + qy*qy + qz*qz;
    __shared__ u32 keys[NPT];
    __shared__ int hist[4][256];
    __shared__ int wtot[4];
    __shared__ int sh_byte, sh_ngt, sure_cnt, tie_cnt;
    __shared__ int tie_m[64];
    __shared__ int sel[KNN];
    __shared__ float nb[KNN][3];
    int tid = threadIdx.x;
    int lane = tid & 63, wv = tid >> 6;
    for (int m = tid; m < NPT; m += 256) {
        float px = pb[m*3+0], py = pb[m*3+1], pz = pb[m*3+2];
        float sc = 2.f*(qx*px + qy*py + qz*pz) - qq - (px*px + py*py + pz*pz);
        u32 u = __builtin_bit_cast(u32, sc);
        keys[m] = u ^ (u32)(((int)u >> 31) | (int)0x80000000);
    }
    if (tid == 0) { sure_cnt = 0; tie_cnt = 0; }
    __syncthreads();
    u32 prefix = 0; int need = KNN;
    for (int pass = 3; pass >= 0; --pass) {
        int shift = pass * 8;
        u32 maskhi = (pass == 3) ? 0u : (0xFFFFFFFFu << (shift + 8));
        hist[0][tid] = 0; hist[1][tid] = 0; hist[2][tid] = 0; hist[3][tid] = 0;
        __syncthreads();
        int prevbin = -1, cnt = 0;
        #pragma unroll
        for (int j = 0; j < 8; ++j) {
            u32 key = keys[tid + 256*j];
            int bin = ((key & maskhi) == (prefix & maskhi)) ? (int)((key >> shift) & 255) : -1;
            if (bin == prevbin) { ++cnt; }
            else {
                if (prevbin >= 0) atomicAdd(&hist[wv][prevbin], cnt);
                prevbin = bin; cnt = 1;
            }
        }
        if (prevbin >= 0) atomicAdd(&hist[wv][prevbin], cnt);
        __syncthreads();
        int own = hist[0][tid] + hist[1][tid] + hist[2][tid] + hist[3][tid];
        int sum = own;
        #pragma unroll
        for (int off = 1; off < 64; off <<= 1) {
            int v = __shfl_down(sum, off, 64);
            if (lane + off < 64) sum += v;
        }
        if (lane == 0) wtot[wv] = sum;
        __syncthreads();
        int addhi = 0;
        #pragma unroll
        for (int w2 = 0; w2 < 4; ++w2) if (w2 > wv) addhi += wtot[w2];
        int cnt_ge = sum + addhi;
        int cnt_gt = cnt_ge - own;
        if (cnt_ge >= need && cnt_gt < need) { sh_byte = tid; sh_ngt = cnt_gt; }
        __syncthreads();
        prefix |= ((u32)sh_byte) << shift;
        need -= sh_ngt;
        __syncthreads();
    }
    u32 T = prefix;
    #pragma unroll
    for (int j = 0; j < 8; ++j) {
        int m = tid + 256*j;
        u32 key = keys[m];
        if (key > T) {
            int slot = atomicAdd(&sure_cnt, 1);
            sel[slot] = m;
        } else if (key == T) {
            int t = atomicAdd(&tie_cnt, 1);
            if (t < 64) tie_m[t] = m;
        }
    }
    __syncthreads();
    if (tid == 0) {
        int base = sure_cnt;
        int r = KNN - base;
        int tc = tie_cnt;
        if (tc == r) {
            for (int t2 = 0; t2 < r; ++t2) sel[base + t2] = tie_m[t2];
        } else if (tc <= 64) {
            for (int t2 = 0; t2 < r; ++t2) {
                int best = 1 << 30, bj = 0;
                for (int t3 = 0; t3 < tc; ++t3)
                    if (tie_m[t3] < best) { best = tie_m[t3]; bj = t3; }
                tie_m[bj] = 1 << 30;
                sel[base + t2] = best;
            }
        } else {
            int got = 0;
            for (int m = 0; m < NPT && got < r; ++m)
                if (keys[m] == T) { sel[base + got] = m; ++got; }
        }
    }
    __syncthreads();
    if (tid < KNN) {
        int j = sel[tid];
        nb[tid][0] = pb[j*3+0]; nb[tid][1] = pb[j*3+1]; nb[tid][2] = pb[j*3+2];
    }
    __syncthreads();
    if (tid < 128) {
        int o = tid;
        float wfa = wf[o*3+0], wfb = wf[o*3+1], wfc = wf[o*3+2];
        float wda = wd[o*3+0], wdb = wd[o*3+1], wdc = wd[o*3+2];
        float cx = qx, cy = qy, cz = qz;
        float a0 = 0.f, a1 = 0.f, a2 = 0.f;
        #pragma unroll 4
        for (int k = 0; k < KNN; ++k) {
            float nx = nb[k][0], ny = nb[k][1], nz = nb[k][2];
            float rx = nx-cx, ry = ny-cy, rz = nz-cz;
            float sx = ny*cz - nz*cy;
            float sy = nz*cx - nx*cz;
            float sz = nx*cy - ny*cx;
            float fx = wfa*rx + wfb*cx + wfc*sx;
            float fy = wfa*ry + wfb*cy + wfc*sy;
            float fz = wfa*rz + wfb*cz + wfc*sz;
            float dx0 = wda*rx + wdb*cx + wdc*sx;
            float dy0 = wda*ry + wdb*cy + wdc*sy;
            float dz0 = wda*rz + wdb*cz + wdc*sz;
            float dot = fx*dx0 + fy*dy0 + fz*dz0;
            float dsq = dx0*dx0 + dy0*dy0 + dz0*dz0;
            float t = dot / (dsq + EPSV);
            bool pos = dot >= 0.f;
            float gx = pos ? fx : (fx - t*dx0);
            float gy = pos ? fy : (fy - t*dy0);
            float gz = pos ? fz : (fz - t*dz0);
            a0 += 0.2f*fx + 0.8f*gx;
            a1 += 0.2f*fy + 0.8f*gy;
            a2 += 0.2f*fz + 0.8f*gz;
        }
        const float s = 1.f / (float)KNN;
        net1[(size_t)(b*6144 +          n)*128 + o] = f2h(a0*s);
        net1[(size_t)(b*6144 + 2048  + n)*128 + o] = f2h(a1*s);
        net1[(size_t)(b*6144 + 4096  + n)*128 + o] = f2h(a2*s);
    }
}

// ------------------------------------------------------ MFMA fp16 GEMM
// Tile 64o x 64m, K-step 64, 256 thr (4 waves = 2o x 2m).
template<int O, int C1, int C2, bool POOL, bool BIASED>
__global__ __launch_bounds__(256) void gemm_plain(
    const u16* __restrict__ W1, int ldw1,
    const u16* __restrict__ X1, int sx1,
    const u16* __restrict__ W2, int ldw2,
    const u16* __restrict__ X2, int sx2,
    const float* __restrict__ WscF, const float* __restrict__ PmPrev,
    u16* __restrict__ Y, int sy,
    float* __restrict__ PmOut)
{
    __shared__ __align__(16) char smem[18432];      // stage 18432; sd 17408
    __shared__ float pms[128];
    __shared__ float biasS_s[64];
    const int m0 = blockIdx.x * 64;
    const int ob = blockIdx.y * 64;
    const int b   = m0 / 6144;
    const int vec = (m0 % 6144) / 2048;
    const int tid = threadIdx.x;
    const int lane = tid & 63;
    const int wid = __builtin_amdgcn_readfirstlane(tid >> 6);
    const int wr = wid & 1, wc = wid >> 1;
    const int l15 = lane & 15, l4 = lane >> 4;

    if (BIASED) {
        if (tid < 128) pms[tid] = PmPrev[(size_t)(b*128 + tid)*3 + vec];
        __syncthreads();
        if (tid < 64) {
            const float* wrow = WscF + (size_t)(ob + tid)*256 + 128;
            float s = 0.f;
            #pragma unroll 4
            for (int c = 0; c < 128; ++c) s += wrow[c]*pms[c];
            biasS_s[tid] = s;
        }
        __syncthreads();
    }

    f32x4 acc[2][2];
    #pragma unroll
    for (int io = 0; io < 2; ++io) {
        float bv[4];
        #pragma unroll
        for (int r = 0; r < 4; ++r)
            bv[r] = BIASED ? biasS_s[wr*32 + io*16 + l4*4 + r] : 0.f;
        #pragma unroll
        for (int jc = 0; jc < 2; ++jc)
            #pragma unroll
            for (int r = 0; r < 4; ++r) acc[io][jc][r] = bv[r];
    }

    constexpr int NS = (C1 + C2) / 64;
    auto ldaddr = [&](int st, int u) -> const u16* {
        const bool ph2 = (st >= C1/64);
        const u16* w = ph2 ? W2 : W1; const u16* x = ph2 ? X2 : X1;
        int ldw = ph2 ? ldw2 : ldw1; int sx = ph2 ? sx2 : sx1;
        int cc = (ph2 ? (st - C1/64) : st) * 64;
        if (u < 512) {
            int row = u >> 3, q = u & 7;
            return w + (size_t)(ob + row)*ldw + cc + q*8;
        }
        int uu = u - 512;
        int row = uu >> 3, q = uu & 7;
        return x + (size_t)(m0 + row)*sx + cc + q*8;
    };
    auto lds_dst = [&](int u) -> char* {
        if (u < 512) { int row = u >> 3, q = u & 7; return smem + row*144 + q*16; }
        int uu = u - 512;
        int row = uu >> 3, q = uu & 7;
        return smem + 9216 + row*144 + q*16;
    };

    uint4v pf[4];
    #pragma unroll
    for (int j = 0; j < 4; ++j) pf[j] = *reinterpret_cast<const uint4v*>(ldaddr(0, tid + 256*j));
    #pragma unroll
    for (int j = 0; j < 4; ++j) *reinterpret_cast<uint4v*>(lds_dst(tid + 256*j)) = pf[j];

    for (int st = 0; st < NS; ++st) {
        __syncthreads();
        if (st + 1 < NS) {
            #pragma unroll
            for (int j = 0; j < 4; ++j)
                pf[j] = *reinterpret_cast<const uint4v*>(ldaddr(st+1, tid + 256*j));
        }
        #pragma unroll
        for (int ks = 0; ks < 2; ++ks) {
            half8 fA[2], fB[2];
            #pragma unroll
            for (int io = 0; io < 2; ++io)
                fA[io] = *reinterpret_cast<const half8*>(smem + (wr*32 + io*16 + l15)*144 + ks*64 + l4*16);
            #pragma unroll
            for (int i = 0; i < 2; ++i)
                fB[i] = *reinterpret_cast<const half8*>(smem + 9216 + (wc*32 + i*16 + l15)*144 + ks*64 + l4*16);
            #pragma unroll
            for (int io = 0; io < 2; ++io)
                #pragma unroll
                for (int jc = 0; jc < 2; ++jc)
                    acc[io][jc] = MFMAH(fA[io], fB[jc], acc[io][jc]);
        }
        __syncthreads();
        if (st + 1 < NS) {
            #pragma unroll
            for (int j = 0; j < 4; ++j)
                *reinterpret_cast<uint4v*>(lds_dst(tid + 256*j)) = pf[j];
        }
    }

    float* sd = (float*)smem;
    #pragma unroll
    for (int io = 0; io < 2; ++io)
        #pragma unroll
        for (int jc = 0; jc < 2; ++jc) {
            int jj = wc*32 + jc*16 + l15;
            int orow = wr*32 + io*16 + l4*4;
            *reinterpret_cast<f32x4*>(sd + jj*68 + orow) = acc[io][jc];
        }
    __syncthreads();

    #pragma unroll
    for (int rep = 0; rep < 2; ++rep) {
        int task = tid + 256*rep;
        int oc = task & 7, ml = task >> 3;
        const float* dp = sd + ml*68 + oc*8;
        u32 hw[4];
        #pragma unroll
        for (int e2 = 0; e2 < 4; ++e2)
            hw[e2] = (u32)f2h(dp[2*e2]) | ((u32)f2h(dp[2*e2+1]) << 16);
        *reinterpret_cast<uint4v*>(Y + (size_t)(m0 + ml)*sy + ob + oc*8) =
            (uint4v){hw[0],hw[1],hw[2],hw[3]};
    }

    if (POOL) {
        int o_l = tid & 63, qtr = tid >> 6;
        float sum = 0.f;
        #pragma unroll 8
        for (int c = 0; c < 16; ++c) sum += sd[(qtr*16 + c)*68 + o_l];
        atomicAdd(&PmOut[(size_t)(b*128 + ob + o_l)*3 + vec], sum * (1.f/(float)NPT));
    }
}

// ------------------- MFMA fp16 dir GEMM + fused VN-leaky(0) epilogue
// Tile 64o x 96cols (3 vec x 32 n), 256 thr (4 waves = 2o x 2c).
// BUG FIX vs rounds 14/15: pmd[384] must be loaded with a strided loop —
// "if (tid < 384)" in a 256-thread block left pmd[256..383] uninitialized,
// corrupting biasD for channels >= 85 (the 0.11-0.13 failures).
template<int O, int CIN, bool VIRT>
__global__ __launch_bounds__(256) void gemm_dir(
    const u16* __restrict__ W_, int ldw,
    const u16* __restrict__ X1, int sx,
    const float* __restrict__ WdF, const float* __restrict__ Pm,
    u16* __restrict__ Ov, int so,
    float* __restrict__ PmZero)
{
    __shared__ __align__(16) char smem[26112];      // stage 23040; sd 26112
    __shared__ float pmd[384];
    __shared__ float biasD_s[192];
    const int gx = blockIdx.x;
    const int b  = gx >> 6;
    const int n0 = (gx & 63) * 32;
    const int ob = blockIdx.y * 64;
    const int tid = threadIdx.x;
    const int lane = tid & 63;
    const int wid = __builtin_amdgcn_readfirstlane(tid >> 6);
    const int wr = wid & 1, wc = wid >> 1;
    const int l15 = lane & 15, l4 = lane >> 4;

    if (PmZero != nullptr && gx == 0 && blockIdx.y == 0)
        for (int t = tid; t < 1536; t += 256) PmZero[t] = 0.f;

    if (VIRT) {
        for (int t = tid; t < 384; t += 256) pmd[t] = Pm[(size_t)b*384 + t];
        __syncthreads();
        if (tid < 192) {
            int o_l = tid / 3, v = tid - o_l*3;
            const float* wrow = WdF + (size_t)(ob + o_l)*256 + 128;
            float s = 0.f;
            #pragma unroll 4
            for (int c = 0; c < 128; ++c) s += wrow[c]*pmd[c*3 + v];
            biasD_s[tid] = s;
        }
        __syncthreads();
    }

    f32x4 acc[2][3];
    #pragma unroll
    for (int io = 0; io < 2; ++io)
        #pragma unroll
        for (int jc = 0; jc < 3; ++jc) {
            int v = (wc*48 + jc*16) >> 5;
            #pragma unroll
            for (int r = 0; r < 4; ++r) {
                int o_l = wr*32 + io*16 + l4*4 + r;
                acc[io][jc][r] = VIRT ? biasD_s[o_l*3 + v] : 0.f;
            }
        }

    constexpr int NS = CIN / 64;
    auto ldaddr = [&](int st, int u) -> const u16* {
        int cc = st*64;
        if (u < 512) {
            int row = u >> 3, q = u & 7;
            return W_ + (size_t)(ob + row)*ldw + cc + q*8;
        }
        int uu = u - 512;
        int row = uu >> 3, q = uu & 7;
        int m = b*6144 + (row >> 5)*2048 + n0 + (row & 31);
        return X1 + (size_t)m*sx + cc + q*8;
    };
    auto lds_dst = [&](int u) -> char* {
        if (u < 512) { int row = u >> 3, q = u & 7; return smem + row*144 + q*16; }
        int uu = u - 512;
        int row = uu >> 3, q = uu & 7;
        return smem + 9216 + row*144 + q*16;
    };

    uint4v pf[5];
    #pragma unroll
    for (int j = 0; j < 5; ++j) pf[j] = *reinterpret_cast<const uint4v*>(ldaddr(0, tid + 256*j));
    #pragma unroll
    for (int j = 0; j < 5; ++j) *reinterpret_cast<uint4v*>(lds_dst(tid + 256*j)) = pf[j];

    for (int st = 0; st < NS; ++st) {
        __syncthreads();
        if (st + 1 < NS) {
            #pragma unroll
            for (int j = 0; j < 5; ++j)
                pf[j] = *reinterpret_cast<const uint4v*>(ldaddr(st+1, tid + 256*j));
        }
        #pragma unroll
        for (int ks = 0; ks < 2; ++ks) {
            half8 fA[2], fB[3];
            #pragma unroll
            for (int io = 0; io < 2; ++io)
                fA[io] = *reinterpret_cast<const half8*>(smem + (wr*32 + io*16 + l15)*144 + ks*64 + l4*16);
            #pragma unroll
            for (int i = 0; i < 3; ++i)
                fB[i] = *reinterpret_cast<const half8*>(smem + 9216 + (wc*48 + i*16 + l15)*144 + ks*64 + l4*16);
            #pragma unroll
            for (int io = 0; io < 2; ++io)
                #pragma unroll
                for (int jc = 0; jc < 3; ++jc)
                    acc[io][jc] = MFMAH(fA[io], fB[jc], acc[io][jc]);
        }
        __syncthreads();
        if (st + 1 < NS) {
            #pragma unroll
            for (int j = 0; j < 5; ++j)
                *reinterpret_cast<uint4v*>(lds_dst(tid + 256*j)) = pf[j];
        }
    }

    float* sd = (float*)smem;
    #pragma unroll
    for (int io = 0; io < 2; ++io)
        #pragma unroll
        for (int jc = 0; jc < 3; ++jc) {
            int jj = wc*48 + jc*16 + l15;
            int orow = wr*32 + io*16 + l4*4;
            *reinterpret_cast<f32x4*>(sd + jj*68 + orow) = acc[io][jc];
        }
    __syncthreads();

    {
        int oc = tid & 7, nl = (tid >> 3) & 31;
        float d[3][8], x[3][8];
        #pragma unroll
        for (int v = 0; v < 3; ++v) {
            const float* dp = sd + (v*32 + nl)*68 + oc*8;
            #pragma unroll
            for (int e = 0; e < 8; ++e) d[v][e] = dp[e];
        }
        if (VIRT && ob >= 128) {
            #pragma unroll
            for (int e = 0; e < 8; ++e) {
                int c = ob - 128 + oc*8 + e;
                #pragma unroll
                for (int v = 0; v < 3; ++v)
                    x[v][e] = Pm[(size_t)(b*128 + c)*3 + v];
            }
        } else {
            #pragma unroll
            for (int v = 0; v < 3; ++v) {
                size_t m = (size_t)(b*6144 + v*2048 + n0 + nl);
                uint4v hx = *reinterpret_cast<const uint4v*>(X1 + m*sx + ob + oc*8);
                #pragma unroll
                for (int w = 0; w < 4; ++w) {
                    x[v][2*w]   = h2f((u16)(hx[w] & 0xffffu));
                    x[v][2*w+1] = h2f((u16)(hx[w] >> 16));
                }
            }
        }
        #pragma unroll
        for (int e = 0; e < 8; ++e) {
            float d0 = d[0][e], d1 = d[1][e], d2 = d[2][e];
            float dot = x[0][e]*d0 + x[1][e]*d1 + x[2][e]*d2;
            float dsq = d0*d0 + d1*d1 + d2*d2;
            float t = dot / (dsq + EPSV);
            if (dot < 0.f) { x[0][e] -= t*d0; x[1][e] -= t*d1; x[2][e] -= t*d2; }
        }
        #pragma unroll
        for (int v = 0; v < 3; ++v) {
            u32 hw[4];
            #pragma unroll
            for (int e2 = 0; e2 < 4; ++e2)
                hw[e2] = (u32)f2h(x[v][2*e2]) | ((u32)f2h(x[v][2*e2+1]) << 16);
            *reinterpret_cast<uint4v*>(Ov + (size_t)(b*6144 + v*2048 + n0 + nl)*so + ob + oc*8) =
                (uint4v){hw[0],hw[1],hw[2],hw[3]};
        }
    }
}

// ------------------------------------------------- weight fp16 convert
#define WO_FCPOS 0
#define WO_DIR0  32768
#define WO_FC0   360448
#define WO_DIR1  524288
#define WO_FC1   606208
#define WO_SC    688128
#define WTOT     851968
__global__ __launch_bounds__(256)
void convert_w_kernel(const float* __restrict__ s0, const float* __restrict__ s1,
                      const float* __restrict__ s2, const float* __restrict__ s3,
                      const float* __restrict__ s4, const float* __restrict__ s5,
                      u16* __restrict__ Wf) {
    int t = blockIdx.x*256 + threadIdx.x;
    if (t >= WTOT) return;
    const float* src; int base;
    if      (t < WO_DIR0) { src = s0; base = WO_FCPOS; }
    else if (t < WO_FC0)  { src = s1; base = WO_DIR0; }
    else if (t < WO_DIR1) { src = s2; base = WO_FC0; }
    else if (t < WO_FC1)  { src = s3; base = WO_DIR1; }
    else if (t < WO_SC)   { src = s4; base = WO_FC1; }
    else                  { src = s5; base = WO_SC; }
    Wf[t] = f2h(src[t - base]);
}

// ----------------------------------------------------- head: leaky(0.2)+fc_c
__global__ __launch_bounds__(128)
void final_head_kernel(const float* __restrict__ q, const float* __restrict__ Wdir,
                       const float* __restrict__ Wfc, float* __restrict__ out) {
    int b = blockIdx.x; int o = threadIdx.x;
    __shared__ float qs[128][3];
    __shared__ float zs[128][3];
    qs[o][0] = q[((size_t)b*128 + o)*3 + 0];
    qs[o][1] = q[((size_t)b*128 + o)*3 + 1];
    qs[o][2] = q[((size_t)b*128 + o)*3 + 2];
    __syncthreads();
    float d0 = 0.f, d1 = 0.f, d2 = 0.f;
    for (int c = 0; c < 128; ++c) {
        float w = Wdir[o*128 + c];
        d0 += w*qs[c][0]; d1 += w*qs[c][1]; d2 += w*qs[c][2];
    }
    float x0 = qs[o][0], x1 = qs[o][1], x2 = qs[o][2];
    float dot = d0*x0 + d1*x1 + d2*x2;
    float dsq = d0*d0 + d1*d1 + d2*d2;
    float t = dot / (dsq + EPSV);
    bool pos = dot >= 0.f;
    float g0 = pos ? x0 : (x0 - t*d0);
    float g1 = pos ? x1 : (x1 - t*d1);
    float g2 = pos ? x2 : (x2 - t*d2);
    zs[o][0] = 0.2f*x0 + 0.8f*g0;
    zs[o][1] = 0.2f*x1 + 0.8f*g1;
    zs[o][2] = 0.2f*x2 + 0.8f*g2;
    __syncthreads();
    float c0 = 0.f, c1 = 0.f, c2 = 0.f;
    for (int c = 0; c < 128; ++c) {
        float w = Wfc[o*128 + c];
        c0 += w*zs[c][0]; c1 += w*zs[c][1]; c2 += w*zs[c][2];
    }
    out[((size_t)b*128 + o)*3 + 0] = c0;
    out[((size_t)b*128 + o)*3 + 1] = c1;
    out[((size_t)b*128 + o)*3 + 2] = c2;
}

extern "C" void kernel_launch(void* const* d_in, const int* in_sizes, int n_in,
                              void* d_out, int out_size, void* d_ws, size_t ws_size,
                              hipStream_t stream) {
    const float* p           = (const float*)d_in[0];
    const float* w_conv_feat = (const float*)d_in[1];
    const float* w_conv_dir  = (const float*)d_in[2];
    const float* w_fc_pos    = (const float*)d_in[3];
    const float* blk_dir0    = (const float*)d_in[4];
    const float* blk_fc0     = (const float*)d_in[5];
    const float* blk_dir1    = (const float*)d_in[6];
    const float* blk_fc1     = (const float*)d_in[7];
    const float* blk_sc      = (const float*)d_in[8];
    const float* w_actc_dir  = (const float*)d_in[9];
    const float* w_fc_c      = (const float*)d_in[10];
    float* out = (float*)d_out;

    char* wsb = (char*)d_ws;
    size_t cur = 0;
    auto carve = [&](size_t nbytes) -> char* {
        char* r = wsb + cur;
        cur += (nbytes + 255) & ~(size_t)255;
        return r;
    };
    const size_t MTOT = (size_t)BB*3*NPT;      // 24576 columns
    float* Pm0   = (float*)carve(1536*4);
    float* Pm1   = (float*)carve(1536*4);
    u16* Wf    = (u16*)carve((size_t)WTOT*2);
    u16* net1  = (u16*)carve(MTOT*128*2);      // fc_pos input; later T
    u16* X0    = (u16*)carve(MTOT*256*2);      // fc_pos out; later Y ping
    u16* Ab    = (u16*)carve(MTOT*256*2);      // A; also U
    u16* Yb    = (u16*)carve(MTOT*128*2);      // Y pong
    float* PmBuf[2] = { Pm0, Pm1 };

    convert_w_kernel<<<(WTOT+255)/256, 256, 0, stream>>>(
        w_fc_pos, blk_dir0, blk_fc0, blk_dir1, blk_fc1, blk_sc, Wf);
    knn_edge_kernel<<<BB*NPT, 256, 0, stream>>>(p, w_conv_feat, w_conv_dir, net1);

    // fc_pos: [256 x 128] x net1 -> X0
    gemm_plain<256,128,0,false,false><<<dim3(384,4), 256, 0, stream>>>(
        Wf+WO_FCPOS, 128, net1, 128,
        nullptr, 0, nullptr, 0,
        nullptr, nullptr, X0, 256, nullptr);

    const u16* Yp = nullptr;
    for (int i = 0; i < 5; ++i) {
        size_t od0 = WO_DIR0 + (size_t)i*65536;
        size_t of0 = WO_FC0  + (size_t)i*32768;
        size_t od1 = WO_DIR1 + (size_t)i*16384;
        size_t of1 = WO_FC1  + (size_t)i*16384;
        size_t osc = WO_SC   + (size_t)i*32768;
        float* PmPrev = PmBuf[(i+1) & 1];
        float* PmCur  = PmBuf[i & 1];

        // dir0 also zeroes all 1536 floats of PmCur (block (0,0)).
        if (i == 0) {
            gemm_dir<256,256,false><<<dim3(BB*64,4), 256, 0, stream>>>(
                Wf+od0, 256, X0, 256, nullptr, nullptr, Ab, 256, PmCur);
        } else {
            gemm_dir<256,128,true><<<dim3(BB*64,4), 256, 0, stream>>>(
                Wf+od0, 256, Yp, 128,
                blk_dir0 + (size_t)i*65536, PmPrev, Ab, 256, PmCur);
        }
        gemm_plain<128,256,0,false,false><<<dim3(384,2), 256, 0, stream>>>(
            Wf+of0, 256, Ab, 256,
            nullptr, 0, nullptr, 0,
            nullptr, nullptr, net1, 128, nullptr);
        gemm_dir<128,128,false><<<dim3(BB*64,2), 256, 0, stream>>>(
            Wf+od1, 128, net1, 128, nullptr, nullptr, Ab, 128, nullptr);

        u16* outv = (i % 2 == 0) ? Yb : X0;
        if (i == 0) {
            gemm_plain<128,128,256,true,false><<<dim3(384,2), 256, 0, stream>>>(
                Wf+of1, 128, Ab, 128,
                Wf+osc, 256, X0, 256,
                nullptr, nullptr, outv, 128, PmCur);
        } else {
            gemm_plain<128,128,128,true,true><<<dim3(384,2), 256, 0, stream>>>(
                Wf+of1, 128, Ab, 128,
                Wf+osc, 256, Yp, 128,
                blk_sc + (size_t)i*32768, PmPrev, outv, 128, PmCur);
        }
        Yp = outv;
    }

    final_head_kernel<<<BB, 128, 0, stream>>>(PmBuf[0], w_actc_dir, w_fc_c, out);
}

// Round 17
// 339.243 us; speedup vs baseline: 1.0508x; 1.0508x over previous
//
#include <hip/hip_runtime.h>
#include <math.h>

#define NPT 2048
#define BB 4
#define KNN 20
#define EPSV 1e-6f

typedef unsigned short u16;
typedef unsigned int u32;
typedef _Float16 half8 __attribute__((ext_vector_type(8)));
typedef __attribute__((ext_vector_type(4))) float f32x4;
typedef __attribute__((ext_vector_type(4))) u32 uint4v;

#define MFMAH(a,b,c) __builtin_amdgcn_mfma_f32_16x16x32_f16((a),(b),(c),0,0,0)

__device__ __forceinline__ u16 f2h(float f) {
    _Float16 h = (_Float16)f;
    return __builtin_bit_cast(u16, h);
}
__device__ __forceinline__ float h2f(u16 b) {
    return (float)__builtin_bit_cast(_Float16, b);
}

// -------------------- kNN top-20 (radix-select) + fused edge conv + mean_k
__global__ __launch_bounds__(256)
void knn_edge_kernel(const float* __restrict__ p,
                     const float* __restrict__ wf, const float* __restrict__ wd,
                     u16* __restrict__ net1) {
    int bn = blockIdx.x;
    int b = bn >> 11, n = bn & (NPT - 1);
    const float* pb = p + (size_t)b * NPT * 3;
    float qx = pb[n*3+0], qy = pb[n*3+1], qz = pb[n*3+2];
    float qq = qx*qx + qy*qy + qz*qz;
    __shared__ u32 keys[NPT];
    __shared__ int hist[4][256];
    __shared__ int wtot[4];
    __shared__ int sh_byte, sh_ngt, sure_cnt, tie_cnt;
    __shared__ int tie_m[64];
    __shared__ int sel[KNN];
    __shared__ float nb[KNN][3];
    int tid = threadIdx.x;
    int lane = tid & 63, wv = tid >> 6;
    for (int m = tid; m < NPT; m += 256) {
        float px = pb[m*3+0], py = pb[m*3+1], pz = pb[m*3+2];
        float sc = 2.f*(qx*px + qy*py + qz*pz) - qq - (px*px + py*py + pz*pz);
        u32 u = __builtin_bit_cast(u32, sc);
        keys[m] = u ^ (u32)(((int)u >> 31) | (int)0x80000000);
    }
    if (tid == 0) { sure_cnt = 0; tie_cnt = 0; }
    __syncthreads();
    u32 prefix = 0; int need = KNN;
    for (int pass = 3; pass >= 0; --pass) {
        int shift = pass * 8;
        u32 maskhi = (pass == 3) ? 0u : (0xFFFFFFFFu << (shift + 8));
        hist[0][tid] = 0; hist[1][tid] = 0; hist[2][tid] = 0; hist[3][tid] = 0;
        __syncthreads();
        int prevbin = -1, cnt = 0;
        #pragma unroll
        for (int j = 0; j < 8; ++j) {
            u32 key = keys[tid + 256*j];
            int bin = ((key & maskhi) == (prefix & maskhi)) ? (int)((key >> shift) & 255) : -1;
            if (bin == prevbin) { ++cnt; }
            else {
                if (prevbin >= 0) atomicAdd(&hist[wv][prevbin], cnt);
                prevbin = bin; cnt = 1;
            }
        }
        if (prevbin >= 0) atomicAdd(&hist[wv][prevbin], cnt);
        __syncthreads();
        int own = hist[0][tid] + hist[1][tid] + hist[2][tid] + hist[3][tid];
        int sum = own;
        #pragma unroll
        for (int off = 1; off < 64; off <<= 1) {
            int v = __shfl_down(sum, off, 64);
            if (lane + off < 64) sum += v;
        }
        if (lane == 0) wtot[wv] = sum;
        __syncthreads();
        int addhi = 0;
        #pragma unroll
        for (int w2 = 0; w2 < 4; ++w2) if (w2 > wv) addhi += wtot[w2];
        int cnt_ge = sum + addhi;
        int cnt_gt = cnt_ge - own;
        if (cnt_ge >= need && cnt_gt < need) { sh_byte = tid; sh_ngt = cnt_gt; }
        __syncthreads();
        prefix |= ((u32)sh_byte) << shift;
        need -= sh_ngt;
        __syncthreads();
    }
    u32 T = prefix;
    #pragma unroll
    for (int j = 0; j < 8; ++j) {
        int m = tid + 256*j;
        u32 key = keys[m];
        if (key > T) {
            int slot = atomicAdd(&sure_cnt, 1);
            sel[slot] = m;
        } else if (key == T) {
            int t = atomicAdd(&tie_cnt, 1);
            if (t < 64) tie_m[t] = m;
        }
    }
    __syncthreads();
    if (tid == 0) {
        int base = sure_cnt;
        int r = KNN - base;
        int tc = tie_cnt;
        if (tc == r) {
            for (int t2 = 0; t2 < r; ++t2) sel[base + t2] = tie_m[t2];
        } else if (tc <= 64) {
            for (int t2 = 0; t2 < r; ++t2) {
                int best = 1 << 30, bj = 0;
                for (int t3 = 0; t3 < tc; ++t3)
                    if (tie_m[t3] < best) { best = tie_m[t3]; bj = t3; }
                tie_m[bj] = 1 << 30;
                sel[base + t2] = best;
            }
        } else {
            int got = 0;
            for (int m = 0; m < NPT && got < r; ++m)
                if (keys[m] == T) { sel[base + got] = m; ++got; }
        }
    }
    __syncthreads();
    if (tid < KNN) {
        int j = sel[tid];
        nb[tid][0] = pb[j*3+0]; nb[tid][1] = pb[j*3+1]; nb[tid][2] = pb[j*3+2];
    }
    __syncthreads();
    if (tid < 128) {
        int o = tid;
        float wfa = wf[o*3+0], wfb = wf[o*3+1], wfc = wf[o*3+2];
        float wda = wd[o*3+0], wdb = wd[o*3+1], wdc = wd[o*3+2];
        float cx = qx, cy = qy, cz = qz;
        float a0 = 0.f, a1 = 0.f, a2 = 0.f;
        #pragma unroll 4
        for (int k = 0; k < KNN; ++k) {
            float nx = nb[k][0], ny = nb[k][1], nz = nb[k][2];
            float rx = nx-cx, ry = ny-cy, rz = nz-cz;
            float sx = ny*cz - nz*cy;
            float sy = nz*cx - nx*cz;
            float sz = nx*cy - ny*cx;
            float fx = wfa*rx + wfb*cx + wfc*sx;
            float fy = wfa*ry + wfb*cy + wfc*sy;
            float fz = wfa*rz + wfb*cz + wfc*sz;
            float dx0 = wda*rx + wdb*cx + wdc*sx;
            float dy0 = wda*ry + wdb*cy + wdc*sy;
            float dz0 = wda*rz + wdb*cz + wdc*sz;
            float dot = fx*dx0 + fy*dy0 + fz*dz0;
            float dsq = dx0*dx0 + dy0*dy0 + dz0*dz0;
            float t = dot / (dsq + EPSV);
            bool pos = dot >= 0.f;
            float gx = pos ? fx : (fx - t*dx0);
            float gy = pos ? fy : (fy - t*dy0);
            float gz = pos ? fz : (fz - t*dz0);
            a0 += 0.2f*fx + 0.8f*gx;
            a1 += 0.2f*fy + 0.8f*gy;
            a2 += 0.2f*fz + 0.8f*gz;
        }
        const float s = 1.f / (float)KNN;
        net1[(size_t)(b*6144 +          n)*128 + o] = f2h(a0*s);
        net1[(size_t)(b*6144 + 2048  + n)*128 + o] = f2h(a1*s);
        net1[(size_t)(b*6144 + 4096  + n)*128 + o] = f2h(a2*s);
    }
}

// ------------------------------------------------------ MFMA fp16 GEMM
// Tile 128o x 64m, K-step 64, 256 thr (4 waves = 2o x 2m). LDS-staged.
template<int O, int C1, int C2, bool POOL, bool BIASED>
__global__ __launch_bounds__(256) void gemm_plain(
    const u16* __restrict__ W1, int ldw1,
    const u16* __restrict__ X1, int sx1,
    const u16* __restrict__ W2, int ldw2,
    const u16* __restrict__ X2, int sx2,
    const float* __restrict__ WscF, const float* __restrict__ PmPrev,
    u16* __restrict__ Y, int sy,
    float* __restrict__ PmOut)
{
    __shared__ __align__(16) char smem[64*132*4];
    __shared__ float pms[128];
    __shared__ float biasS_s[128];
    const int m0 = blockIdx.x * 64;
    const int ob = blockIdx.y * 128;
    const int b   = m0 / 6144;
    const int vec = (m0 % 6144) / 2048;
    const int tid = threadIdx.x;
    const int lane = tid & 63;
    const int wid = __builtin_amdgcn_readfirstlane(tid >> 6);
    const int wr = wid & 1, wc = wid >> 1;
    const int l15 = lane & 15, l4 = lane >> 4;

    if (BIASED) {
        if (tid < 128) pms[tid] = PmPrev[(size_t)(b*128 + tid)*3 + vec];
        __syncthreads();
        if (tid < 128) {
            const float* wrow = WscF + (size_t)tid*256 + 128;
            float s = 0.f;
            #pragma unroll 4
            for (int c = 0; c < 128; ++c) s += wrow[c]*pms[c];
            biasS_s[tid] = s;
        }
        __syncthreads();
    }

    f32x4 acc[4][2];
    #pragma unroll
    for (int io = 0; io < 4; ++io) {
        float bv[4];
        #pragma unroll
        for (int r = 0; r < 4; ++r)
            bv[r] = BIASED ? biasS_s[wr*64 + io*16 + l4*4 + r] : 0.f;
        #pragma unroll
        for (int jc = 0; jc < 2; ++jc)
            #pragma unroll
            for (int r = 0; r < 4; ++r) acc[io][jc][r] = bv[r];
    }

    constexpr int NS = (C1 + C2) / 64;
    auto ldaddr = [&](int st, int u) -> const u16* {
        const bool ph2 = (st >= C1/64);
        const u16* w = ph2 ? W2 : W1; const u16* x = ph2 ? X2 : X1;
        int ldw = ph2 ? ldw2 : ldw1; int sx = ph2 ? sx2 : sx1;
        int cc = (ph2 ? (st - C1/64) : st) * 64;
        if (u < 1024) {
            int row = u >> 3, q = u & 7;
            return w + (size_t)(ob + row)*ldw + cc + q*8;
        }
        int uu = u - 1024;
        int row = uu >> 3, q = uu & 7;
        return x + (size_t)(m0 + row)*sx + cc + q*8;
    };
    auto lds_dst = [&](int u) -> char* {
        if (u < 1024) { int row = u >> 3, q = u & 7; return smem + row*144 + q*16; }
        int uu = u - 1024;
        int row = uu >> 3, q = uu & 7;
        return smem + 18432 + row*144 + q*16;
    };

    uint4v pf[6];
    #pragma unroll
    for (int j = 0; j < 6; ++j) pf[j] = *reinterpret_cast<const uint4v*>(ldaddr(0, tid + 256*j));
    #pragma unroll
    for (int j = 0; j < 6; ++j) *reinterpret_cast<uint4v*>(lds_dst(tid + 256*j)) = pf[j];

    for (int st = 0; st < NS; ++st) {
        __syncthreads();
        if (st + 1 < NS) {
            #pragma unroll
            for (int j = 0; j < 6; ++j)
                pf[j] = *reinterpret_cast<const uint4v*>(ldaddr(st+1, tid + 256*j));
        }
        #pragma unroll
        for (int ks = 0; ks < 2; ++ks) {
            half8 fA[4], fB[2];
            #pragma unroll
            for (int io = 0; io < 4; ++io)
                fA[io] = *reinterpret_cast<const half8*>(smem + (wr*64 + io*16 + l15)*144 + ks*64 + l4*16);
            #pragma unroll
            for (int i = 0; i < 2; ++i)
                fB[i] = *reinterpret_cast<const half8*>(smem + 18432 + (wc*32 + i*16 + l15)*144 + ks*64 + l4*16);
            #pragma unroll
            for (int io = 0; io < 4; ++io)
                #pragma unroll
                for (int jc = 0; jc < 2; ++jc)
                    acc[io][jc] = MFMAH(fA[io], fB[jc], acc[io][jc]);
        }
        __syncthreads();
        if (st + 1 < NS) {
            #pragma unroll
            for (int j = 0; j < 6; ++j)
                *reinterpret_cast<uint4v*>(lds_dst(tid + 256*j)) = pf[j];
        }
    }

    float* sd = (float*)smem;
    #pragma unroll
    for (int io = 0; io < 4; ++io)
        #pragma unroll
        for (int jc = 0; jc < 2; ++jc) {
            int jj = wc*32 + jc*16 + l15;
            int orow = wr*64 + io*16 + l4*4;
            *reinterpret_cast<f32x4*>(sd + jj*132 + orow) = acc[io][jc];
        }
    __syncthreads();

    #pragma unroll
    for (int rep = 0; rep < 4; ++rep) {
        int task = tid + 256*rep;
        int oc = task & 15, ml = task >> 4;
        const float* dp = sd + ml*132 + oc*8;
        u32 hw[4];
        #pragma unroll
        for (int e2 = 0; e2 < 4; ++e2)
            hw[e2] = (u32)f2h(dp[2*e2]) | ((u32)f2h(dp[2*e2+1]) << 16);
        *reinterpret_cast<uint4v*>(Y + (size_t)(m0 + ml)*sy + ob + oc*8) =
            (uint4v){hw[0],hw[1],hw[2],hw[3]};
    }

    if (POOL) {
        int o_l = tid & 127, half = tid >> 7;
        float sum = 0.f;
        #pragma unroll 8
        for (int c = 0; c < 32; ++c) sum += sd[(half*32 + c)*132 + o_l];
        atomicAdd(&PmOut[(size_t)(b*128 + o_l)*3 + vec], sum * (1.f/(float)NPT));
    }
}

// ------------------- MFMA fp16 dir GEMM + fused VN-leaky(0) epilogue
template<int O, int CIN, bool VIRT>
__global__ __launch_bounds__(256) void gemm_dir(
    const u16* __restrict__ W_, int ldw,
    const u16* __restrict__ X1, int sx,
    const float* __restrict__ WdF, const float* __restrict__ Pm,
    u16* __restrict__ Ov, int so,
    float* __restrict__ PmZero)
{
    __shared__ __align__(16) char smem[96*132*4];
    __shared__ float pmd[384];
    __shared__ float biasD_s[384];
    const int gx = blockIdx.x;
    const int b  = gx >> 6;
    const int n0 = (gx & 63) * 32;
    const int ob = blockIdx.y * 128;
    const int tid = threadIdx.x;
    const int lane = tid & 63;
    const int wid = __builtin_amdgcn_readfirstlane(tid >> 6);
    const int wr = wid & 1, wc = wid >> 1;
    const int l15 = lane & 15, l4 = lane >> 4;

    if (PmZero != nullptr && gx == 0 && blockIdx.y == 0)
        for (int t = tid; t < 1536; t += 256) PmZero[t] = 0.f;

    if (VIRT) {
        for (int t = tid; t < 384; t += 256) pmd[t] = Pm[(size_t)b*384 + t];
        __syncthreads();
        for (int t = tid; t < 384; t += 256) {
            int o_l = t / 3, v = t - o_l*3;
            const float* wrow = WdF + (size_t)(ob + o_l)*256 + 128;
            float s = 0.f;
            #pragma unroll 4
            for (int c = 0; c < 128; ++c) s += wrow[c]*pmd[c*3 + v];
            biasD_s[t] = s;
        }
        __syncthreads();
    }

    f32x4 acc[4][3];
    #pragma unroll
    for (int io = 0; io < 4; ++io)
        #pragma unroll
        for (int jc = 0; jc < 3; ++jc) {
            int v = (wc*48 + jc*16) >> 5;
            #pragma unroll
            for (int r = 0; r < 4; ++r) {
                int o_l = wr*64 + io*16 + l4*4 + r;
                acc[io][jc][r] = VIRT ? biasD_s[o_l*3 + v] : 0.f;
            }
        }

    constexpr int NS = CIN / 64;
    auto ldaddr = [&](int st, int u) -> const u16* {
        int cc = st*64;
        if (u < 1024) {
            int row = u >> 3, q = u & 7;
            return W_ + (size_t)(ob + row)*ldw + cc + q*8;
        }
        int uu = u - 1024;
        int row = uu >> 3, q = uu & 7;
        int m = b*6144 + (row >> 5)*2048 + n0 + (row & 31);
        return X1 + (size_t)m*sx + cc + q*8;
    };
    auto lds_dst = [&](int u) -> char* {
        if (u < 1024) { int row = u >> 3, q = u & 7; return smem + row*144 + q*16; }
        int uu = u - 1024;
        int row = uu >> 3, q = uu & 7;
        return smem + 18432 + row*144 + q*16;
    };

    uint4v pf[7];
    #pragma unroll
    for (int j = 0; j < 7; ++j) pf[j] = *reinterpret_cast<const uint4v*>(ldaddr(0, tid + 256*j));
    #pragma unroll
    for (int j = 0; j < 7; ++j) *reinterpret_cast<uint4v*>(lds_dst(tid + 256*j)) = pf[j];

    for (int st = 0; st < NS; ++st) {
        __syncthreads();
        if (st + 1 < NS) {
            #pragma unroll
            for (int j = 0; j < 7; ++j)
                pf[j] = *reinterpret_cast<const uint4v*>(ldaddr(st+1, tid + 256*j));
        }
        #pragma unroll
        for (int ks = 0; ks < 2; ++ks) {
            half8 fA[4], fB[3];
            #pragma unroll
            for (int io = 0; io < 4; ++io)
                fA[io] = *reinterpret_cast<const half8*>(smem + (wr*64 + io*16 + l15)*144 + ks*64 + l4*16);
            #pragma unroll
            for (int i = 0; i < 3; ++i)
                fB[i] = *reinterpret_cast<const half8*>(smem + 18432 + (wc*48 + i*16 + l15)*144 + ks*64 + l4*16);
            #pragma unroll
            for (int io = 0; io < 4; ++io)
                #pragma unroll
                for (int jc = 0; jc < 3; ++jc)
                    acc[io][jc] = MFMAH(fA[io], fB[jc], acc[io][jc]);
        }
        __syncthreads();
        if (st + 1 < NS) {
            #pragma unroll
            for (int j = 0; j < 7; ++j)
                *reinterpret_cast<uint4v*>(lds_dst(tid + 256*j)) = pf[j];
        }
    }

    float* sd = (float*)smem;
    #pragma unroll
    for (int io = 0; io < 4; ++io)
        #pragma unroll
        for (int jc = 0; jc < 3; ++jc) {
            int jj = wc*48 + jc*16 + l15;
            int orow = wr*64 + io*16 + l4*4;
            *reinterpret_cast<f32x4*>(sd + jj*132 + orow) = acc[io][jc];
        }
    __syncthreads();

    #pragma unroll
    for (int rep = 0; rep < 2; ++rep) {
        int task = tid + 256*rep;
        int oc = task & 15, nl = (task >> 4) & 31;
        float d[3][8], x[3][8];
        #pragma unroll
        for (int v = 0; v < 3; ++v) {
            const float* dp = sd + (v*32 + nl)*132 + oc*8;
            #pragma unroll
            for (int e = 0; e < 8; ++e) d[v][e] = dp[e];
        }
        if (VIRT && ob != 0) {
            #pragma unroll
            for (int e = 0; e < 8; ++e) {
                int c = oc*8 + e;
                #pragma unroll
                for (int v = 0; v < 3; ++v)
                    x[v][e] = Pm[(size_t)(b*128 + c)*3 + v];
            }
        } else {
            #pragma unroll
            for (int v = 0; v < 3; ++v) {
                size_t m = (size_t)(b*6144 + v*2048 + n0 + nl);
                uint4v hx = *reinterpret_cast<const uint4v*>(X1 + m*sx + ob + oc*8);
                #pragma unroll
                for (int w = 0; w < 4; ++w) {
                    x[v][2*w]   = h2f((u16)(hx[w] & 0xffffu));
                    x[v][2*w+1] = h2f((u16)(hx[w] >> 16));
                }
            }
        }
        #pragma unroll
        for (int e = 0; e < 8; ++e) {
            float d0 = d[0][e], d1 = d[1][e], d2 = d[2][e];
            float dot = x[0][e]*d0 + x[1][e]*d1 + x[2][e]*d2;
            float dsq = d0*d0 + d1*d1 + d2*d2;
            float t = dot / (dsq + EPSV);
            if (dot < 0.f) { x[0][e] -= t*d0; x[1][e] -= t*d1; x[2][e] -= t*d2; }
        }
        #pragma unroll
        for (int v = 0; v < 3; ++v) {
            u32 hw[4];
            #pragma unroll
            for (int e2 = 0; e2 < 4; ++e2)
                hw[e2] = (u32)f2h(x[v][2*e2]) | ((u32)f2h(x[v][2*e2+1]) << 16);
            *reinterpret_cast<uint4v*>(Ov + (size_t)(b*6144 + v*2048 + n0 + nl)*so + ob + oc*8) =
                (uint4v){hw[0],hw[1],hw[2],hw[3]};
        }
    }
}

// ------------------------------------------------- weight fp16 convert
#define WO_FCPOS 0
#define WO_DIR0  32768
#define WO_FC0   360448
#define WO_DIR1  524288
#define WO_FC1   606208
#define WO_SC    688128
#define WTOT     851968
__global__ __launch_bounds__(256)
void convert_w_kernel(const float* __restrict__ s0, const float* __restrict__ s1,
                      const float* __restrict__ s2, const float* __restrict__ s3,
                      const float* __restrict__ s4, const float* __restrict__ s5,
                      u16* __restrict__ Wf) {
    int t = blockIdx.x*256 + threadIdx.x;
    if (t >= WTOT) return;
    const float* src; int base;
    if      (t < WO_DIR0) { src = s0; base = WO_FCPOS; }
    else if (t < WO_FC0)  { src = s1; base = WO_DIR0; }
    else if (t < WO_DIR1) { src = s2; base = WO_FC0; }
    else if (t < WO_FC1)  { src = s3; base = WO_DIR1; }
    else if (t < WO_SC)   { src = s4; base = WO_FC1; }
    else                  { src = s5; base = WO_SC; }
    Wf[t] = f2h(src[t - base]);
}

// ----------------------------------------------------- head: leaky(0.2)+fc_c
__global__ __launch_bounds__(128)
void final_head_kernel(const float* __restrict__ q, const float* __restrict__ Wdir,
                       const float* __restrict__ Wfc, float* __restrict__ out) {
    int b = blockIdx.x; int o = threadIdx.x;
    __shared__ float qs[128][3];
    __shared__ float zs[128][3];
    qs[o][0] = q[((size_t)b*128 + o)*3 + 0];
    qs[o][1] = q[((size_t)b*128 + o)*3 + 1];
    qs[o][2] = q[((size_t)b*128 + o)*3 + 2];
    __syncthreads();
    float d0 = 0.f, d1 = 0.f, d2 = 0.f;
    for (int c = 0; c < 128; ++c) {
        float w = Wdir[o*128 + c];
        d0 += w*qs[c][0]; d1 += w*qs[c][1]; d2 += w*qs[c][2];
    }
    float x0 = qs[o][0], x1 = qs[o][1], x2 = qs[o][2];
    float dot = d0*x0 + d1*x1 + d2*x2;
    float dsq = d0*d0 + d1*d1 + d2*d2;
    float t = dot / (dsq + EPSV);
    bool pos = dot >= 0.f;
    float g0 = pos ? x0 : (x0 - t*d0);
    float g1 = pos ? x1 : (x1 - t*d1);
    float g2 = pos ? x2 : (x2 - t*d2);
    zs[o][0] = 0.2f*x0 + 0.8f*g0;
    zs[o][1] = 0.2f*x1 + 0.8f*g1;
    zs[o][2] = 0.2f*x2 + 0.8f*g2;
    __syncthreads();
    float c0 = 0.f, c1 = 0.f, c2 = 0.f;
    for (int c = 0; c < 128; ++c) {
        float w = Wfc[o*128 + c];
        c0 += w*zs[c][0]; c1 += w*zs[c][1]; c2 += w*zs[c][2];
    }
    out[((size_t)b*128 + o)*3 + 0] = c0;
    out[((size_t)b*128 + o)*3 + 1] = c1;
    out[((size_t)b*128 + o)*3 + 2] = c2;
}

extern "C" void kernel_launch(void* const* d_in, const int* in_sizes, int n_in,
                              void* d_out, int out_size, void* d_ws, size_t ws_size,
                              hipStream_t stream) {
    const float* p           = (const float*)d_in[0];
    const float* w_conv_feat = (const float*)d_in[1];
    const float* w_conv_dir  = (const float*)d_in[2];
    const float* w_fc_pos    = (const float*)d_in[3];
    const float* blk_dir0    = (const float*)d_in[4];
    const float* blk_fc0     = (const float*)d_in[5];
    const float* blk_dir1    = (const float*)d_in[6];
    const float* blk_fc1     = (const float*)d_in[7];
    const float* blk_sc      = (const float*)d_in[8];
    const float* w_actc_dir  = (const float*)d_in[9];
    const float* w_fc_c      = (const float*)d_in[10];
    float* out = (float*)d_out;

    char* wsb = (char*)d_ws;
    size_t cur = 0;
    auto carve = [&](size_t nbytes) -> char* {
        char* r = wsb + cur;
        cur += (nbytes + 255) & ~(size_t)255;
        return r;
    };
    const size_t MTOT = (size_t)BB*3*NPT;      // 24576 columns
    float* Pm0   = (float*)carve(1536*4);
    float* Pm1   = (float*)carve(1536*4);
    u16* Wf    = (u16*)carve((size_t)WTOT*2);
    u16* net1  = (u16*)carve(MTOT*128*2);      // fc_pos input; later T
    u16* X0    = (u16*)carve(MTOT*256*2);      // fc_pos out; later Y ping
    u16* Ab    = (u16*)carve(MTOT*256*2);      // A; also U
    u16* Yb    = (u16*)carve(MTOT*128*2);      // Y pong
    float* PmBuf[2] = { Pm0, Pm1 };

    convert_w_kernel<<<(WTOT+255)/256, 256, 0, stream>>>(
        w_fc_pos, blk_dir0, blk_fc0, blk_dir1, blk_fc1, blk_sc, Wf);
    knn_edge_kernel<<<BB*NPT, 256, 0, stream>>>(p, w_conv_feat, w_conv_dir, net1);

    // fc_pos: [256 x 128] x net1 -> X0
    gemm_plain<256,128,0,false,false><<<dim3(384,2), 256, 0, stream>>>(
        Wf+WO_FCPOS, 128, net1, 128,
        nullptr, 0, nullptr, 0,
        nullptr, nullptr, X0, 256, nullptr);

    const u16* Yp = nullptr;
    for (int i = 0; i < 5; ++i) {
        size_t od0 = WO_DIR0 + (size_t)i*65536;
        size_t of0 = WO_FC0  + (size_t)i*32768;
        size_t od1 = WO_DIR1 + (size_t)i*16384;
        size_t of1 = WO_FC1  + (size_t)i*16384;
        size_t osc = WO_SC   + (size_t)i*32768;
        float* PmPrev = PmBuf[(i+1) & 1];
        float* PmCur  = PmBuf[i & 1];

        // dir0 also zeroes all 1536 floats of PmCur (block 0) — replaces memset.
        if (i == 0) {
            gemm_dir<256,256,false><<<dim3(BB*64,2), 256, 0, stream>>>(
                Wf+od0, 256, X0, 256, nullptr, nullptr, Ab, 256, PmCur);
        } else {
            gemm_dir<256,128,true><<<dim3(BB*64,2), 256, 0, stream>>>(
                Wf+od0, 256, Yp, 128,
                blk_dir0 + (size_t)i*65536, PmPrev, Ab, 256, PmCur);
        }
        gemm_plain<128,256,0,false,false><<<dim3(384,1), 256, 0, stream>>>(
            Wf+of0, 256, Ab, 256,
            nullptr, 0, nullptr, 0,
            nullptr, nullptr, net1, 128, nullptr);
        gemm_dir<128,128,false><<<dim3(BB*64,1), 256, 0, stream>>>(
            Wf+od1, 128, net1, 128, nullptr, nullptr, Ab, 128, nullptr);

        u16* outv = (i % 2 == 0) ? Yb : X0;
        if (i == 0) {
            gemm_plain<128,128,256,true,false><<<dim3(384,1), 256, 0, stream>>>(
                Wf+of1, 128, Ab, 128,
                Wf+osc, 256, X0, 256,
                nullptr, nullptr, outv, 128, PmCur);
        } else {
            gemm_plain<128,128,128,true,true><<<dim3(384,1), 256, 0, stream>>>(
                Wf+of1, 128, Ab, 128,
                Wf+osc, 256, Yp, 128,
                blk_sc + (size_t)i*32768, PmPrev, outv, 128, PmCur);
        }
        Yp = outv;
    }

    final_head_kernel<<<BB, 128, 0, stream>>>(PmBuf[0], w_actc_dir, w_fc_c, out);
}

// Round 18
// 326.877 us; speedup vs baseline: 1.0906x; 1.0378x over previous
//
#include <hip/hip_runtime.h>
#include <math.h>

#define NPT 2048
#define BB 4
#define KNN 20
#define EPSV 1e-6f

typedef unsigned short u16;
typedef unsigned int u32;
typedef _Float16 half8 __attribute__((ext_vector_type(8)));
typedef __attribute__((ext_vector_type(4))) float f32x4;
typedef __attribute__((ext_vector_type(4))) u32 uint4v;

#define MFMAH(a,b,c) __builtin_amdgcn_mfma_f32_16x16x32_f16((a),(b),(c),0,0,0)

__device__ __forceinline__ u16 f2h(float f) {
    _Float16 h = (_Float16)f;
    return __builtin_bit_cast(u16, h);
}
__device__ __forceinline__ float h2f(u16 b) {
    return (float)__builtin_bit_cast(_Float16, b);
}

// -------------------- kNN top-20 (radix-select) + fused edge conv + mean_k
// ONLY change vs round 17 (passed, 339us): edge-conv tail split across all
// 256 threads (kh = tid>>7 handles 10 of 20 neighbors; fp32 partials combined
// via LDS aliased on the dead keys buffer).
__global__ __launch_bounds__(256)
void knn_edge_kernel(const float* __restrict__ p,
                     const float* __restrict__ wf, const float* __restrict__ wd,
                     u16* __restrict__ net1) {
    int bn = blockIdx.x;
    int b = bn >> 11, n = bn & (NPT - 1);
    const float* pb = p + (size_t)b * NPT * 3;
    float qx = pb[n*3+0], qy = pb[n*3+1], qz = pb[n*3+2];
    float qq = qx*qx + qy*qy + qz*qz;
    __shared__ u32 keys[NPT];
    __shared__ int hist[4][256];
    __shared__ int wtot[4];
    __shared__ int sh_byte, sh_ngt, sure_cnt, tie_cnt;
    __shared__ int tie_m[64];
    __shared__ int sel[KNN];
    __shared__ float nb[KNN][3];
    int tid = threadIdx.x;
    int lane = tid & 63, wv = tid >> 6;
    for (int m = tid; m < NPT; m += 256) {
        float px = pb[m*3+0], py = pb[m*3+1], pz = pb[m*3+2];
        float sc = 2.f*(qx*px + qy*py + qz*pz) - qq - (px*px + py*py + pz*pz);
        u32 u = __builtin_bit_cast(u32, sc);
        keys[m] = u ^ (u32)(((int)u >> 31) | (int)0x80000000);
    }
    if (tid == 0) { sure_cnt = 0; tie_cnt = 0; }
    __syncthreads();
    u32 prefix = 0; int need = KNN;
    for (int pass = 3; pass >= 0; --pass) {
        int shift = pass * 8;
        u32 maskhi = (pass == 3) ? 0u : (0xFFFFFFFFu << (shift + 8));
        hist[0][tid] = 0; hist[1][tid] = 0; hist[2][tid] = 0; hist[3][tid] = 0;
        __syncthreads();
        int prevbin = -1, cnt = 0;
        #pragma unroll
        for (int j = 0; j < 8; ++j) {
            u32 key = keys[tid + 256*j];
            int bin = ((key & maskhi) == (prefix & maskhi)) ? (int)((key >> shift) & 255) : -1;
            if (bin == prevbin) { ++cnt; }
            else {
                if (prevbin >= 0) atomicAdd(&hist[wv][prevbin], cnt);
                prevbin = bin; cnt = 1;
            }
        }
        if (prevbin >= 0) atomicAdd(&hist[wv][prevbin], cnt);
        __syncthreads();
        int own = hist[0][tid] + hist[1][tid] + hist[2][tid] + hist[3][tid];
        int sum = own;
        #pragma unroll
        for (int off = 1; off < 64; off <<= 1) {
            int v = __shfl_down(sum, off, 64);
            if (lane + off < 64) sum += v;
        }
        if (lane == 0) wtot[wv] = sum;
        __syncthreads();
        int addhi = 0;
        #pragma unroll
        for (int w2 = 0; w2 < 4; ++w2) if (w2 > wv) addhi += wtot[w2];
        int cnt_ge = sum + addhi;
        int cnt_gt = cnt_ge - own;
        if (cnt_ge >= need && cnt_gt < need) { sh_byte = tid; sh_ngt = cnt_gt; }
        __syncthreads();
        prefix |= ((u32)sh_byte) << shift;
        need -= sh_ngt;
        __syncthreads();
    }
    u32 T = prefix;
    #pragma unroll
    for (int j = 0; j < 8; ++j) {
        int m = tid + 256*j;
        u32 key = keys[m];
        if (key > T) {
            int slot = atomicAdd(&sure_cnt, 1);
            sel[slot] = m;
        } else if (key == T) {
            int t = atomicAdd(&tie_cnt, 1);
            if (t < 64) tie_m[t] = m;
        }
    }
    __syncthreads();
    if (tid == 0) {
        int base = sure_cnt;
        int r = KNN - base;
        int tc = tie_cnt;
        if (tc == r) {
            for (int t2 = 0; t2 < r; ++t2) sel[base + t2] = tie_m[t2];
        } else if (tc <= 64) {
            for (int t2 = 0; t2 < r; ++t2) {
                int best = 1 << 30, bj = 0;
                for (int t3 = 0; t3 < tc; ++t3)
                    if (tie_m[t3] < best) { best = tie_m[t3]; bj = t3; }
                tie_m[bj] = 1 << 30;
                sel[base + t2] = best;
            }
        } else {
            int got = 0;
            for (int m = 0; m < NPT && got < r; ++m)
                if (keys[m] == T) { sel[base + got] = m; ++got; }
        }
    }
    __syncthreads();
    if (tid < KNN) {
        int j = sel[tid];
        nb[tid][0] = pb[j*3+0]; nb[tid][1] = pb[j*3+1]; nb[tid][2] = pb[j*3+2];
    }
    __syncthreads();
    // ---- edge conv: all 256 threads; k halves combined via LDS partials.
    // keys[] is dead past this barrier — reuse as fp32 partial buffer.
    {
        float* part = (float*)keys;
        int o = tid & 127, kh = tid >> 7;
        float wfa = wf[o*3+0], wfb = wf[o*3+1], wfc = wf[o*3+2];
        float wda = wd[o*3+0], wdb = wd[o*3+1], wdc = wd[o*3+2];
        float cx = qx, cy = qy, cz = qz;
        float a0 = 0.f, a1 = 0.f, a2 = 0.f;
        int k0 = kh * 10;
        #pragma unroll
        for (int k = 0; k < 10; ++k) {
            float nx = nb[k0+k][0], ny = nb[k0+k][1], nz = nb[k0+k][2];
            float rx = nx-cx, ry = ny-cy, rz = nz-cz;
            float sx = ny*cz - nz*cy;
            float sy = nz*cx - nx*cz;
            float sz = nx*cy - ny*cx;
            float fx = wfa*rx + wfb*cx + wfc*sx;
            float fy = wfa*ry + wfb*cy + wfc*sy;
            float fz = wfa*rz + wfb*cz + wfc*sz;
            float dx0 = wda*rx + wdb*cx + wdc*sx;
            float dy0 = wda*ry + wdb*cy + wdc*sy;
            float dz0 = wda*rz + wdb*cz + wdc*sz;
            float dot = fx*dx0 + fy*dy0 + fz*dz0;
            float dsq = dx0*dx0 + dy0*dy0 + dz0*dz0;
            float t = dot / (dsq + EPSV);
            bool pos = dot >= 0.f;
            float gx = pos ? fx : (fx - t*dx0);
            float gy = pos ? fy : (fy - t*dy0);
            float gz = pos ? fz : (fz - t*dz0);
            a0 += 0.2f*fx + 0.8f*gx;
            a1 += 0.2f*fy + 0.8f*gy;
            a2 += 0.2f*fz + 0.8f*gz;
        }
        if (kh == 1) { part[o*3+0] = a0; part[o*3+1] = a1; part[o*3+2] = a2; }
        __syncthreads();
        if (kh == 0) {
            a0 += part[o*3+0]; a1 += part[o*3+1]; a2 += part[o*3+2];
            const float s = 1.f / (float)KNN;
            net1[(size_t)(b*6144 +          n)*128 + o] = f2h(a0*s);
            net1[(size_t)(b*6144 + 2048  + n)*128 + o] = f2h(a1*s);
            net1[(size_t)(b*6144 + 4096  + n)*128 + o] = f2h(a2*s);
        }
    }
}

// ------------------------------------------------------ MFMA fp16 GEMM
// Tile 128o x 64m, K-step 64, 256 thr (4 waves = 2o x 2m). LDS-staged.
// (round-17 version, verbatim — passed)
template<int O, int C1, int C2, bool POOL, bool BIASED>
__global__ __launch_bounds__(256) void gemm_plain(
    const u16* __restrict__ W1, int ldw1,
    const u16* __restrict__ X1, int sx1,
    const u16* __restrict__ W2, int ldw2,
    const u16* __restrict__ X2, int sx2,
    const float* __restrict__ WscF, const float* __restrict__ PmPrev,
    u16* __restrict__ Y, int sy,
    float* __restrict__ PmOut)
{
    __shared__ __align__(16) char smem[64*132*4];
    __shared__ float pms[128];
    __shared__ float biasS_s[128];
    const int m0 = blockIdx.x * 64;
    const int ob = blockIdx.y * 128;
    const int b   = m0 / 6144;
    const int vec = (m0 % 6144) / 2048;
    const int tid = threadIdx.x;
    const int lane = tid & 63;
    const int wid = __builtin_amdgcn_readfirstlane(tid >> 6);
    const int wr = wid & 1, wc = wid >> 1;
    const int l15 = lane & 15, l4 = lane >> 4;

    if (BIASED) {
        if (tid < 128) pms[tid] = PmPrev[(size_t)(b*128 + tid)*3 + vec];
        __syncthreads();
        if (tid < 128) {
            const float* wrow = WscF + (size_t)tid*256 + 128;
            float s = 0.f;
            #pragma unroll 4
            for (int c = 0; c < 128; ++c) s += wrow[c]*pms[c];
            biasS_s[tid] = s;
        }
        __syncthreads();
    }

    f32x4 acc[4][2];
    #pragma unroll
    for (int io = 0; io < 4; ++io) {
        float bv[4];
        #pragma unroll
        for (int r = 0; r < 4; ++r)
            bv[r] = BIASED ? biasS_s[wr*64 + io*16 + l4*4 + r] : 0.f;
        #pragma unroll
        for (int jc = 0; jc < 2; ++jc)
            #pragma unroll
            for (int r = 0; r < 4; ++r) acc[io][jc][r] = bv[r];
    }

    constexpr int NS = (C1 + C2) / 64;
    auto ldaddr = [&](int st, int u) -> const u16* {
        const bool ph2 = (st >= C1/64);
        const u16* w = ph2 ? W2 : W1; const u16* x = ph2 ? X2 : X1;
        int ldw = ph2 ? ldw2 : ldw1; int sx = ph2 ? sx2 : sx1;
        int cc = (ph2 ? (st - C1/64) : st) * 64;
        if (u < 1024) {
            int row = u >> 3, q = u & 7;
            return w + (size_t)(ob + row)*ldw + cc + q*8;
        }
        int uu = u - 1024;
        int row = uu >> 3, q = uu & 7;
        return x + (size_t)(m0 + row)*sx + cc + q*8;
    };
    auto lds_dst = [&](int u) -> char* {
        if (u < 1024) { int row = u >> 3, q = u & 7; return smem + row*144 + q*16; }
        int uu = u - 1024;
        int row = uu >> 3, q = uu & 7;
        return smem + 18432 + row*144 + q*16;
    };

    uint4v pf[6];
    #pragma unroll
    for (int j = 0; j < 6; ++j) pf[j] = *reinterpret_cast<const uint4v*>(ldaddr(0, tid + 256*j));
    #pragma unroll
    for (int j = 0; j < 6; ++j) *reinterpret_cast<uint4v*>(lds_dst(tid + 256*j)) = pf[j];

    for (int st = 0; st < NS; ++st) {
        __syncthreads();
        if (st + 1 < NS) {
            #pragma unroll
            for (int j = 0; j < 6; ++j)
                pf[j] = *reinterpret_cast<const uint4v*>(ldaddr(st+1, tid + 256*j));
        }
        #pragma unroll
        for (int ks = 0; ks < 2; ++ks) {
            half8 fA[4], fB[2];
            #pragma unroll
            for (int io = 0; io < 4; ++io)
                fA[io] = *reinterpret_cast<const half8*>(smem + (wr*64 + io*16 + l15)*144 + ks*64 + l4*16);
            #pragma unroll
            for (int i = 0; i < 2; ++i)
                fB[i] = *reinterpret_cast<const half8*>(smem + 18432 + (wc*32 + i*16 + l15)*144 + ks*64 + l4*16);
            #pragma unroll
            for (int io = 0; io < 4; ++io)
                #pragma unroll
                for (int jc = 0; jc < 2; ++jc)
                    acc[io][jc] = MFMAH(fA[io], fB[jc], acc[io][jc]);
        }
        __syncthreads();
        if (st + 1 < NS) {
            #pragma unroll
            for (int j = 0; j < 6; ++j)
                *reinterpret_cast<uint4v*>(lds_dst(tid + 256*j)) = pf[j];
        }
    }

    float* sd = (float*)smem;
    #pragma unroll
    for (int io = 0; io < 4; ++io)
        #pragma unroll
        for (int jc = 0; jc < 2; ++jc) {
            int jj = wc*32 + jc*16 + l15;
            int orow = wr*64 + io*16 + l4*4;
            *reinterpret_cast<f32x4*>(sd + jj*132 + orow) = acc[io][jc];
        }
    __syncthreads();

    #pragma unroll
    for (int rep = 0; rep < 4; ++rep) {
        int task = tid + 256*rep;
        int oc = task & 15, ml = task >> 4;
        const float* dp = sd + ml*132 + oc*8;
        u32 hw[4];
        #pragma unroll
        for (int e2 = 0; e2 < 4; ++e2)
            hw[e2] = (u32)f2h(dp[2*e2]) | ((u32)f2h(dp[2*e2+1]) << 16);
        *reinterpret_cast<uint4v*>(Y + (size_t)(m0 + ml)*sy + ob + oc*8) =
            (uint4v){hw[0],hw[1],hw[2],hw[3]};
    }

    if (POOL) {
        int o_l = tid & 127, half = tid >> 7;
        float sum = 0.f;
        #pragma unroll 8
        for (int c = 0; c < 32; ++c) sum += sd[(half*32 + c)*132 + o_l];
        atomicAdd(&PmOut[(size_t)(b*128 + o_l)*3 + vec], sum * (1.f/(float)NPT));
    }
}

// ------------------- MFMA fp16 dir GEMM + fused VN-leaky(0) epilogue
// (round-17 version, verbatim — passed)
template<int O, int CIN, bool VIRT>
__global__ __launch_bounds__(256) void gemm_dir(
    const u16* __restrict__ W_, int ldw,
    const u16* __restrict__ X1, int sx,
    const float* __restrict__ WdF, const float* __restrict__ Pm,
    u16* __restrict__ Ov, int so,
    float* __restrict__ PmZero)
{
    __shared__ __align__(16) char smem[96*132*4];
    __shared__ float pmd[384];
    __shared__ float biasD_s[384];
    const int gx = blockIdx.x;
    const int b  = gx >> 6;
    const int n0 = (gx & 63) * 32;
    const int ob = blockIdx.y * 128;
    const int tid = threadIdx.x;
    const int lane = tid & 63;
    const int wid = __builtin_amdgcn_readfirstlane(tid >> 6);
    const int wr = wid & 1, wc = wid >> 1;
    const int l15 = lane & 15, l4 = lane >> 4;

    if (PmZero != nullptr && gx == 0 && blockIdx.y == 0)
        for (int t = tid; t < 1536; t += 256) PmZero[t] = 0.f;

    if (VIRT) {
        for (int t = tid; t < 384; t += 256) pmd[t] = Pm[(size_t)b*384 + t];
        __syncthreads();
        for (int t = tid; t < 384; t += 256) {
            int o_l = t / 3, v = t - o_l*3;
            const float* wrow = WdF + (size_t)(ob + o_l)*256 + 128;
            float s = 0.f;
            #pragma unroll 4
            for (int c = 0; c < 128; ++c) s += wrow[c]*pmd[c*3 + v];
            biasD_s[t] = s;
        }
        __syncthreads();
    }

    f32x4 acc[4][3];
    #pragma unroll
    for (int io = 0; io < 4; ++io)
        #pragma unroll
        for (int jc = 0; jc < 3; ++jc) {
            int v = (wc*48 + jc*16) >> 5;
            #pragma unroll
            for (int r = 0; r < 4; ++r) {
                int o_l = wr*64 + io*16 + l4*4 + r;
                acc[io][jc][r] = VIRT ? biasD_s[o_l*3 + v] : 0.f;
            }
        }

    constexpr int NS = CIN / 64;
    auto ldaddr = [&](int st, int u) -> const u16* {
        int cc = st*64;
        if (u < 1024) {
            int row = u >> 3, q = u & 7;
            return W_ + (size_t)(ob + row)*ldw + cc + q*8;
        }
        int uu = u - 1024;
        int row = uu >> 3, q = uu & 7;
        int m = b*6144 + (row >> 5)*2048 + n0 + (row & 31);
        return X1 + (size_t)m*sx + cc + q*8;
    };
    auto lds_dst = [&](int u) -> char* {
        if (u < 1024) { int row = u >> 3, q = u & 7; return smem + row*144 + q*16; }
        int uu = u - 1024;
        int row = uu >> 3, q = uu & 7;
        return smem + 18432 + row*144 + q*16;
    };

    uint4v pf[7];
    #pragma unroll
    for (int j = 0; j < 7; ++j) pf[j] = *reinterpret_cast<const uint4v*>(ldaddr(0, tid + 256*j));
    #pragma unroll
    for (int j = 0; j < 7; ++j) *reinterpret_cast<uint4v*>(lds_dst(tid + 256*j)) = pf[j];

    for (int st = 0; st < NS; ++st) {
        __syncthreads();
        if (st + 1 < NS) {
            #pragma unroll
            for (int j = 0; j < 7; ++j)
                pf[j] = *reinterpret_cast<const uint4v*>(ldaddr(st+1, tid + 256*j));
        }
        #pragma unroll
        for (int ks = 0; ks < 2; ++ks) {
            half8 fA[4], fB[3];
            #pragma unroll
            for (int io = 0; io < 4; ++io)
                fA[io] = *reinterpret_cast<const half8*>(smem + (wr*64 + io*16 + l15)*144 + ks*64 + l4*16);
            #pragma unroll
            for (int i = 0; i < 3; ++i)
                fB[i] = *reinterpret_cast<const half8*>(smem + 18432 + (wc*48 + i*16 + l15)*144 + ks*64 + l4*16);
            #pragma unroll
            for (int io = 0; io < 4; ++io)
                #pragma unroll
                for (int jc = 0; jc < 3; ++jc)
                    acc[io][jc] = MFMAH(fA[io], fB[jc], acc[io][jc]);
        }
        __syncthreads();
        if (st + 1 < NS) {
            #pragma unroll
            for (int j = 0; j < 7; ++j)
                *reinterpret_cast<uint4v*>(lds_dst(tid + 256*j)) = pf[j];
        }
    }

    float* sd = (float*)smem;
    #pragma unroll
    for (int io = 0; io < 4; ++io)
        #pragma unroll
        for (int jc = 0; jc < 3; ++jc) {
            int jj = wc*48 + jc*16 + l15;
            int orow = wr*64 + io*16 + l4*4;
            *reinterpret_cast<f32x4*>(sd + jj*132 + orow) = acc[io][jc];
        }
    __syncthreads();

    #pragma unroll
    for (int rep = 0; rep < 2; ++rep) {
        int task = tid + 256*rep;
        int oc = task & 15, nl = (task >> 4) & 31;
        float d[3][8], x[3][8];
        #pragma unroll
        for (int v = 0; v < 3; ++v) {
            const float* dp = sd + (v*32 + nl)*132 + oc*8;
            #pragma unroll
            for (int e = 0; e < 8; ++e) d[v][e] = dp[e];
        }
        if (VIRT && ob != 0) {
            #pragma unroll
            for (int e = 0; e < 8; ++e) {
                int c = oc*8 + e;
                #pragma unroll
                for (int v = 0; v < 3; ++v)
                    x[v][e] = Pm[(size_t)(b*128 + c)*3 + v];
            }
        } else {
            #pragma unroll
            for (int v = 0; v < 3; ++v) {
                size_t m = (size_t)(b*6144 + v*2048 + n0 + nl);
                uint4v hx = *reinterpret_cast<const uint4v*>(X1 + m*sx + ob + oc*8);
                #pragma unroll
                for (int w = 0; w < 4; ++w) {
                    x[v][2*w]   = h2f((u16)(hx[w] & 0xffffu));
                    x[v][2*w+1] = h2f((u16)(hx[w] >> 16));
                }
            }
        }
        #pragma unroll
        for (int e = 0; e < 8; ++e) {
            float d0 = d[0][e], d1 = d[1][e], d2 = d[2][e];
            float dot = x[0][e]*d0 + x[1][e]*d1 + x[2][e]*d2;
            float dsq = d0*d0 + d1*d1 + d2*d2;
            float t = dot / (dsq + EPSV);
            if (dot < 0.f) { x[0][e] -= t*d0; x[1][e] -= t*d1; x[2][e] -= t*d2; }
        }
        #pragma unroll
        for (int v = 0; v < 3; ++v) {
            u32 hw[4];
            #pragma unroll
            for (int e2 = 0; e2 < 4; ++e2)
                hw[e2] = (u32)f2h(x[v][2*e2]) | ((u32)f2h(x[v][2*e2+1]) << 16);
            *reinterpret_cast<uint4v*>(Ov + (size_t)(b*6144 + v*2048 + n0 + nl)*so + ob + oc*8) =
                (uint4v){hw[0],hw[1],hw[2],hw[3]};
        }
    }
}

// ------------------------------------------------- weight fp16 convert
#define WO_FCPOS 0
#define WO_DIR0  32768
#define WO_FC0   360448
#define WO_DIR1  524288
#define WO_FC1   606208
#define WO_SC    688128
#define WTOT     851968
__global__ __launch_bounds__(256)
void convert_w_kernel(const float* __restrict__ s0, const float* __restrict__ s1,
                      const float* __restrict__ s2, const float* __restrict__ s3,
                      const float* __restrict__ s4, const float* __restrict__ s5,
                      u16* __restrict__ Wf) {
    int t = blockIdx.x*256 + threadIdx.x;
    if (t >= WTOT) return;
    const float* src; int base;
    if      (t < WO_DIR0) { src = s0; base = WO_FCPOS; }
    else if (t < WO_FC0)  { src = s1; base = WO_DIR0; }
    else if (t < WO_DIR1) { src = s2; base = WO_FC0; }
    else if (t < WO_FC1)  { src = s3; base = WO_DIR1; }
    else if (t < WO_SC)   { src = s4; base = WO_FC1; }
    else                  { src = s5; base = WO_SC; }
    Wf[t] = f2h(src[t - base]);
}

// ----------------------------------------------------- head: leaky(0.2)+fc_c
__global__ __launch_bounds__(128)
void final_head_kernel(const float* __restrict__ q, const float* __restrict__ Wdir,
                       const float* __restrict__ Wfc, float* __restrict__ out) {
    int b = blockIdx.x; int o = threadIdx.x;
    __shared__ float qs[128][3];
    __shared__ float zs[128][3];
    qs[o][0] = q[((size_t)b*128 + o)*3 + 0];
    qs[o][1] = q[((size_t)b*128 + o)*3 + 1];
    qs[o][2] = q[((size_t)b*128 + o)*3 + 2];
    __syncthreads();
    float d0 = 0.f, d1 = 0.f, d2 = 0.f;
    for (int c = 0; c < 128; ++c) {
        float w = Wdir[o*128 + c];
        d0 += w*qs[c][0]; d1 += w*qs[c][1]; d2 += w*qs[c][2];
    }
    float x0 = qs[o][0], x1 = qs[o][1], x2 = qs[o][2];
    float dot = d0*x0 + d1*x1 + d2*x2;
    float dsq = d0*d0 + d1*d1 + d2*d2;
    float t = dot / (dsq + EPSV);
    bool pos = dot >= 0.f;
    float g0 = pos ? x0 : (x0 - t*d0);
    float g1 = pos ? x1 : (x1 - t*d1);
    float g2 = pos ? x2 : (x2 - t*d2);
    zs[o][0] = 0.2f*x0 + 0.8f*g0;
    zs[o][1] = 0.2f*x1 + 0.8f*g1;
    zs[o][2] = 0.2f*x2 + 0.8f*g2;
    __syncthreads();
    float c0 = 0.f, c1 = 0.f, c2 = 0.f;
    for (int c = 0; c < 128; ++c) {
        float w = Wfc[o*128 + c];
        c0 += w*zs[c][0]; c1 += w*zs[c][1]; c2 += w*zs[c][2];
    }
    out[((size_t)b*128 + o)*3 + 0] = c0;
    out[((size_t)b*128 + o)*3 + 1] = c1;
    out[((size_t)b*128 + o)*3 + 2] = c2;
}

extern "C" void kernel_launch(void* const* d_in, const int* in_sizes, int n_in,
                              void* d_out, int out_size, void* d_ws, size_t ws_size,
                              hipStream_t stream) {
    const float* p           = (const float*)d_in[0];
    const float* w_conv_feat = (const float*)d_in[1];
    const float* w_conv_dir  = (const float*)d_in[2];
    const float* w_fc_pos    = (const float*)d_in[3];
    const float* blk_dir0    = (const float*)d_in[4];
    const float* blk_fc0     = (const float*)d_in[5];
    const float* blk_dir1    = (const float*)d_in[6];
    const float* blk_fc1     = (const float*)d_in[7];
    const float* blk_sc      = (const float*)d_in[8];
    const float* w_actc_dir  = (const float*)d_in[9];
    const float* w_fc_c      = (const float*)d_in[10];
    float* out = (float*)d_out;

    char* wsb = (char*)d_ws;
    size_t cur = 0;
    auto carve = [&](size_t nbytes) -> char* {
        char* r = wsb + cur;
        cur += (nbytes + 255) & ~(size_t)255;
        return r;
    };
    const size_t MTOT = (size_t)BB*3*NPT;      // 24576 columns
    float* Pm0   = (float*)carve(1536*4);
    float* Pm1   = (float*)carve(1536*4);
    u16* Wf    = (u16*)carve((size_t)WTOT*2);
    u16* net1  = (u16*)carve(MTOT*128*2);      // fc_pos input; later T
    u16* X0    = (u16*)carve(MTOT*256*2);      // fc_pos out; later Y ping
    u16* Ab    = (u16*)carve(MTOT*256*2);      // A; also U
    u16* Yb    = (u16*)carve(MTOT*128*2);      // Y pong
    float* PmBuf[2] = { Pm0, Pm1 };

    convert_w_kernel<<<(WTOT+255)/256, 256, 0, stream>>>(
        w_fc_pos, blk_dir0, blk_fc0, blk_dir1, blk_fc1, blk_sc, Wf);
    knn_edge_kernel<<<BB*NPT, 256, 0, stream>>>(p, w_conv_feat, w_conv_dir, net1);

    // fc_pos: [256 x 128] x net1 -> X0
    gemm_plain<256,128,0,false,false><<<dim3(384,2), 256, 0, stream>>>(
        Wf+WO_FCPOS, 128, net1, 128,
        nullptr, 0, nullptr, 0,
        nullptr, nullptr, X0, 256, nullptr);

    const u16* Yp = nullptr;
    for (int i = 0; i < 5; ++i) {
        size_t od0 = WO_DIR0 + (size_t)i*65536;
        size_t of0 = WO_FC0  + (size_t)i*32768;
        size_t od1 = WO_DIR1 + (size_t)i*16384;
        size_t of1 = WO_FC1  + (size_t)i*16384;
        size_t osc = WO_SC   + (size_t)i*32768;
        float* PmPrev = PmBuf[(i+1) & 1];
        float* PmCur  = PmBuf[i & 1];

        // dir0 also zeroes all 1536 floats of PmCur (block 0) — replaces memset.
        if (i == 0) {
            gemm_dir<256,256,false><<<dim3(BB*64,2), 256, 0, stream>>>(
                Wf+od0, 256, X0, 256, nullptr, nullptr, Ab, 256, PmCur);
        } else {
            gemm_dir<256,128,true><<<dim3(BB*64,2), 256, 0, stream>>>(
                Wf+od0, 256, Yp, 128,
                blk_dir0 + (size_t)i*65536, PmPrev, Ab, 256, PmCur);
        }
        gemm_plain<128,256,0,false,false><<<dim3(384,1), 256, 0, stream>>>(
            Wf+of0, 256, Ab, 256,
            nullptr, 0, nullptr, 0,
            nullptr, nullptr, net1, 128, nullptr);
        gemm_dir<128,128,false><<<dim3(BB*64,1), 256, 0, stream>>>(
            Wf+od1, 128, net1, 128, nullptr, nullptr, Ab, 128, nullptr);

        u16* outv = (i % 2 == 0) ? Yb : X0;
        if (i == 0) {
            gemm_plain<128,128,256,true,false><<<dim3(384,1), 256, 0, stream>>>(
                Wf+of1, 128, Ab, 128,
                Wf+osc, 256, X0, 256,
                nullptr, nullptr, outv, 128, PmCur);
        } else {
            gemm_plain<128,128,128,true,true><<<dim3(384,1), 256, 0, stream>>>(
                Wf+of1, 128, Ab, 128,
                Wf+osc, 256, Yp, 128,
                blk_sc + (size_t)i*32768, PmPrev, outv, 128, PmCur);
        }
        Yp = outv;
    }

    final_head_kernel<<<BB, 128, 0, stream>>>(PmBuf[0], w_actc_dir, w_fc_c, out);
}

// Round 19
// 316.094 us; speedup vs baseline: 1.1278x; 1.0341x over previous
//
#include <hip/hip_runtime.h>
#include <math.h>

#define NPT 2048
#define BB 4
#define KNN 20
#define EPSV 1e-6f

typedef unsigned short u16;
typedef unsigned int u32;
typedef _Float16 half8 __attribute__((ext_vector_type(8)));
typedef __attribute__((ext_vector_type(4))) float f32x4;
typedef __attribute__((ext_vector_type(4))) u32 uint4v;

#define MFMAH(a,b,c) __builtin_amdgcn_mfma_f32_16x16x32_f16((a),(b),(c),0,0,0)

__device__ __forceinline__ u16 f2h(float f) {
    _Float16 h = (_Float16)f;
    return __builtin_bit_cast(u16, h);
}
__device__ __forceinline__ float h2f(u16 b) {
    return (float)__builtin_bit_cast(_Float16, b);
}

// -------------------- kNN top-20 (radix-select) + fused edge conv + mean_k
// (round-18 version, verbatim — passed at 77us)
__global__ __launch_bounds__(256)
void knn_edge_kernel(const float* __restrict__ p,
                     const float* __restrict__ wf, const float* __restrict__ wd,
                     u16* __restrict__ net1) {
    int bn = blockIdx.x;
    int b = bn >> 11, n = bn & (NPT - 1);
    const float* pb = p + (size_t)b * NPT * 3;
    float qx = pb[n*3+0], qy = pb[n*3+1], qz = pb[n*3+2];
    float qq = qx*qx + qy*qy + qz*qz;
    __shared__ u32 keys[NPT];
    __shared__ int hist[4][256];
    __shared__ int wtot[4];
    __shared__ int sh_byte, sh_ngt, sure_cnt, tie_cnt;
    __shared__ int tie_m[64];
    __shared__ int sel[KNN];
    __shared__ float nb[KNN][3];
    int tid = threadIdx.x;
    int lane = tid & 63, wv = tid >> 6;
    for (int m = tid; m < NPT; m += 256) {
        float px = pb[m*3+0], py = pb[m*3+1], pz = pb[m*3+2];
        float sc = 2.f*(qx*px + qy*py + qz*pz) - qq - (px*px + py*py + pz*pz);
        u32 u = __builtin_bit_cast(u32, sc);
        keys[m] = u ^ (u32)(((int)u >> 31) | (int)0x80000000);
    }
    if (tid == 0) { sure_cnt = 0; tie_cnt = 0; }
    __syncthreads();
    u32 prefix = 0; int need = KNN;
    for (int pass = 3; pass >= 0; --pass) {
        int shift = pass * 8;
        u32 maskhi = (pass == 3) ? 0u : (0xFFFFFFFFu << (shift + 8));
        hist[0][tid] = 0; hist[1][tid] = 0; hist[2][tid] = 0; hist[3][tid] = 0;
        __syncthreads();
        int prevbin = -1, cnt = 0;
        #pragma unroll
        for (int j = 0; j < 8; ++j) {
            u32 key = keys[tid + 256*j];
            int bin = ((key & maskhi) == (prefix & maskhi)) ? (int)((key >> shift) & 255) : -1;
            if (bin == prevbin) { ++cnt; }
            else {
                if (prevbin >= 0) atomicAdd(&hist[wv][prevbin], cnt);
                prevbin = bin; cnt = 1;
            }
        }
        if (prevbin >= 0) atomicAdd(&hist[wv][prevbin], cnt);
        __syncthreads();
        int own = hist[0][tid] + hist[1][tid] + hist[2][tid] + hist[3][tid];
        int sum = own;
        #pragma unroll
        for (int off = 1; off < 64; off <<= 1) {
            int v = __shfl_down(sum, off, 64);
            if (lane + off < 64) sum += v;
        }
        if (lane == 0) wtot[wv] = sum;
        __syncthreads();
        int addhi = 0;
        #pragma unroll
        for (int w2 = 0; w2 < 4; ++w2) if (w2 > wv) addhi += wtot[w2];
        int cnt_ge = sum + addhi;
        int cnt_gt = cnt_ge - own;
        if (cnt_ge >= need && cnt_gt < need) { sh_byte = tid; sh_ngt = cnt_gt; }
        __syncthreads();
        prefix |= ((u32)sh_byte) << shift;
        need -= sh_ngt;
        __syncthreads();
    }
    u32 T = prefix;
    #pragma unroll
    for (int j = 0; j < 8; ++j) {
        int m = tid + 256*j;
        u32 key = keys[m];
        if (key > T) {
            int slot = atomicAdd(&sure_cnt, 1);
            sel[slot] = m;
        } else if (key == T) {
            int t = atomicAdd(&tie_cnt, 1);
            if (t < 64) tie_m[t] = m;
        }
    }
    __syncthreads();
    if (tid == 0) {
        int base = sure_cnt;
        int r = KNN - base;
        int tc = tie_cnt;
        if (tc == r) {
            for (int t2 = 0; t2 < r; ++t2) sel[base + t2] = tie_m[t2];
        } else if (tc <= 64) {
            for (int t2 = 0; t2 < r; ++t2) {
                int best = 1 << 30, bj = 0;
                for (int t3 = 0; t3 < tc; ++t3)
                    if (tie_m[t3] < best) { best = tie_m[t3]; bj = t3; }
                tie_m[bj] = 1 << 30;
                sel[base + t2] = best;
            }
        } else {
            int got = 0;
            for (int m = 0; m < NPT && got < r; ++m)
                if (keys[m] == T) { sel[base + got] = m; ++got; }
        }
    }
    __syncthreads();
    if (tid < KNN) {
        int j = sel[tid];
        nb[tid][0] = pb[j*3+0]; nb[tid][1] = pb[j*3+1]; nb[tid][2] = pb[j*3+2];
    }
    __syncthreads();
    {
        float* part = (float*)keys;
        int o = tid & 127, kh = tid >> 7;
        float wfa = wf[o*3+0], wfb = wf[o*3+1], wfc = wf[o*3+2];
        float wda = wd[o*3+0], wdb = wd[o*3+1], wdc = wd[o*3+2];
        float cx = qx, cy = qy, cz = qz;
        float a0 = 0.f, a1 = 0.f, a2 = 0.f;
        int k0 = kh * 10;
        #pragma unroll
        for (int k = 0; k < 10; ++k) {
            float nx = nb[k0+k][0], ny = nb[k0+k][1], nz = nb[k0+k][2];
            float rx = nx-cx, ry = ny-cy, rz = nz-cz;
            float sx = ny*cz - nz*cy;
            float sy = nz*cx - nx*cz;
            float sz = nx*cy - ny*cx;
            float fx = wfa*rx + wfb*cx + wfc*sx;
            float fy = wfa*ry + wfb*cy + wfc*sy;
            float fz = wfa*rz + wfb*cz + wfc*sz;
            float dx0 = wda*rx + wdb*cx + wdc*sx;
            float dy0 = wda*ry + wdb*cy + wdc*sy;
            float dz0 = wda*rz + wdb*cz + wdc*sz;
            float dot = fx*dx0 + fy*dy0 + fz*dz0;
            float dsq = dx0*dx0 + dy0*dy0 + dz0*dz0;
            float t = dot / (dsq + EPSV);
            bool pos = dot >= 0.f;
            float gx = pos ? fx : (fx - t*dx0);
            float gy = pos ? fy : (fy - t*dy0);
            float gz = pos ? fz : (fz - t*dz0);
            a0 += 0.2f*fx + 0.8f*gx;
            a1 += 0.2f*fy + 0.8f*gy;
            a2 += 0.2f*fz + 0.8f*gz;
        }
        if (kh == 1) { part[o*3+0] = a0; part[o*3+1] = a1; part[o*3+2] = a2; }
        __syncthreads();
        if (kh == 0) {
            a0 += part[o*3+0]; a1 += part[o*3+1]; a2 += part[o*3+2];
            const float s = 1.f / (float)KNN;
            net1[(size_t)(b*6144 +          n)*128 + o] = f2h(a0*s);
            net1[(size_t)(b*6144 + 2048  + n)*128 + o] = f2h(a1*s);
            net1[(size_t)(b*6144 + 4096  + n)*128 + o] = f2h(a2*s);
        }
    }
}

// ------------------------------------------------------ MFMA fp16 GEMM
// (round-18 version, verbatim — passed) Tile 128o x 64m.
template<int O, int C1, int C2, bool POOL, bool BIASED>
__global__ __launch_bounds__(256) void gemm_plain(
    const u16* __restrict__ W1, int ldw1,
    const u16* __restrict__ X1, int sx1,
    const u16* __restrict__ W2, int ldw2,
    const u16* __restrict__ X2, int sx2,
    const float* __restrict__ WscF, const float* __restrict__ PmPrev,
    u16* __restrict__ Y, int sy,
    float* __restrict__ PmOut)
{
    __shared__ __align__(16) char smem[64*132*4];
    __shared__ float pms[128];
    __shared__ float biasS_s[128];
    const int m0 = blockIdx.x * 64;
    const int ob = blockIdx.y * 128;
    const int b   = m0 / 6144;
    const int vec = (m0 % 6144) / 2048;
    const int tid = threadIdx.x;
    const int lane = tid & 63;
    const int wid = __builtin_amdgcn_readfirstlane(tid >> 6);
    const int wr = wid & 1, wc = wid >> 1;
    const int l15 = lane & 15, l4 = lane >> 4;

    if (BIASED) {
        if (tid < 128) pms[tid] = PmPrev[(size_t)(b*128 + tid)*3 + vec];
        __syncthreads();
        if (tid < 128) {
            const float* wrow = WscF + (size_t)tid*256 + 128;
            float s = 0.f;
            #pragma unroll 4
            for (int c = 0; c < 128; ++c) s += wrow[c]*pms[c];
            biasS_s[tid] = s;
        }
        __syncthreads();
    }

    f32x4 acc[4][2];
    #pragma unroll
    for (int io = 0; io < 4; ++io) {
        float bv[4];
        #pragma unroll
        for (int r = 0; r < 4; ++r)
            bv[r] = BIASED ? biasS_s[wr*64 + io*16 + l4*4 + r] : 0.f;
        #pragma unroll
        for (int jc = 0; jc < 2; ++jc)
            #pragma unroll
            for (int r = 0; r < 4; ++r) acc[io][jc][r] = bv[r];
    }

    constexpr int NS = (C1 + C2) / 64;
    auto ldaddr = [&](int st, int u) -> const u16* {
        const bool ph2 = (st >= C1/64);
        const u16* w = ph2 ? W2 : W1; const u16* x = ph2 ? X2 : X1;
        int ldw = ph2 ? ldw2 : ldw1; int sx = ph2 ? sx2 : sx1;
        int cc = (ph2 ? (st - C1/64) : st) * 64;
        if (u < 1024) {
            int row = u >> 3, q = u & 7;
            return w + (size_t)(ob + row)*ldw + cc + q*8;
        }
        int uu = u - 1024;
        int row = uu >> 3, q = uu & 7;
        return x + (size_t)(m0 + row)*sx + cc + q*8;
    };
    auto lds_dst = [&](int u) -> char* {
        if (u < 1024) { int row = u >> 3, q = u & 7; return smem + row*144 + q*16; }
        int uu = u - 1024;
        int row = uu >> 3, q = uu & 7;
        return smem + 18432 + row*144 + q*16;
    };

    uint4v pf[6];
    #pragma unroll
    for (int j = 0; j < 6; ++j) pf[j] = *reinterpret_cast<const uint4v*>(ldaddr(0, tid + 256*j));
    #pragma unroll
    for (int j = 0; j < 6; ++j) *reinterpret_cast<uint4v*>(lds_dst(tid + 256*j)) = pf[j];

    for (int st = 0; st < NS; ++st) {
        __syncthreads();
        if (st + 1 < NS) {
            #pragma unroll
            for (int j = 0; j < 6; ++j)
                pf[j] = *reinterpret_cast<const uint4v*>(ldaddr(st+1, tid + 256*j));
        }
        #pragma unroll
        for (int ks = 0; ks < 2; ++ks) {
            half8 fA[4], fB[2];
            #pragma unroll
            for (int io = 0; io < 4; ++io)
                fA[io] = *reinterpret_cast<const half8*>(smem + (wr*64 + io*16 + l15)*144 + ks*64 + l4*16);
            #pragma unroll
            for (int i = 0; i < 2; ++i)
                fB[i] = *reinterpret_cast<const half8*>(smem + 18432 + (wc*32 + i*16 + l15)*144 + ks*64 + l4*16);
            #pragma unroll
            for (int io = 0; io < 4; ++io)
                #pragma unroll
                for (int jc = 0; jc < 2; ++jc)
                    acc[io][jc] = MFMAH(fA[io], fB[jc], acc[io][jc]);
        }
        __syncthreads();
        if (st + 1 < NS) {
            #pragma unroll
            for (int j = 0; j < 6; ++j)
                *reinterpret_cast<uint4v*>(lds_dst(tid + 256*j)) = pf[j];
        }
    }

    float* sd = (float*)smem;
    #pragma unroll
    for (int io = 0; io < 4; ++io)
        #pragma unroll
        for (int jc = 0; jc < 2; ++jc) {
            int jj = wc*32 + jc*16 + l15;
            int orow = wr*64 + io*16 + l4*4;
            *reinterpret_cast<f32x4*>(sd + jj*132 + orow) = acc[io][jc];
        }
    __syncthreads();

    #pragma unroll
    for (int rep = 0; rep < 4; ++rep) {
        int task = tid + 256*rep;
        int oc = task & 15, ml = task >> 4;
        const float* dp = sd + ml*132 + oc*8;
        u32 hw[4];
        #pragma unroll
        for (int e2 = 0; e2 < 4; ++e2)
            hw[e2] = (u32)f2h(dp[2*e2]) | ((u32)f2h(dp[2*e2+1]) << 16);
        *reinterpret_cast<uint4v*>(Y + (size_t)(m0 + ml)*sy + ob + oc*8) =
            (uint4v){hw[0],hw[1],hw[2],hw[3]};
    }

    if (POOL) {
        int o_l = tid & 127, half = tid >> 7;
        float sum = 0.f;
        #pragma unroll 8
        for (int c = 0; c < 32; ++c) sum += sd[(half*32 + c)*132 + o_l];
        atomicAdd(&PmOut[(size_t)(b*128 + o_l)*3 + vec], sum * (1.f/(float)NPT));
    }
}

// ------------------- MFMA fp16 dir GEMM + fused VN-leaky(0) epilogue
// (round-18 version, verbatim — used for dir0 only now)
template<int O, int CIN, bool VIRT>
__global__ __launch_bounds__(256) void gemm_dir(
    const u16* __restrict__ W_, int ldw,
    const u16* __restrict__ X1, int sx,
    const float* __restrict__ WdF, const float* __restrict__ Pm,
    u16* __restrict__ Ov, int so,
    float* __restrict__ PmZero)
{
    __shared__ __align__(16) char smem[96*132*4];
    __shared__ float pmd[384];
    __shared__ float biasD_s[384];
    const int gx = blockIdx.x;
    const int b  = gx >> 6;
    const int n0 = (gx & 63) * 32;
    const int ob = blockIdx.y * 128;
    const int tid = threadIdx.x;
    const int lane = tid & 63;
    const int wid = __builtin_amdgcn_readfirstlane(tid >> 6);
    const int wr = wid & 1, wc = wid >> 1;
    const int l15 = lane & 15, l4 = lane >> 4;

    if (PmZero != nullptr && gx == 0 && blockIdx.y == 0)
        for (int t = tid; t < 1536; t += 256) PmZero[t] = 0.f;

    if (VIRT) {
        for (int t = tid; t < 384; t += 256) pmd[t] = Pm[(size_t)b*384 + t];
        __syncthreads();
        for (int t = tid; t < 384; t += 256) {
            int o_l = t / 3, v = t - o_l*3;
            const float* wrow = WdF + (size_t)(ob + o_l)*256 + 128;
            float s = 0.f;
            #pragma unroll 4
            for (int c = 0; c < 128; ++c) s += wrow[c]*pmd[c*3 + v];
            biasD_s[t] = s;
        }
        __syncthreads();
    }

    f32x4 acc[4][3];
    #pragma unroll
    for (int io = 0; io < 4; ++io)
        #pragma unroll
        for (int jc = 0; jc < 3; ++jc) {
            int v = (wc*48 + jc*16) >> 5;
            #pragma unroll
            for (int r = 0; r < 4; ++r) {
                int o_l = wr*64 + io*16 + l4*4 + r;
                acc[io][jc][r] = VIRT ? biasD_s[o_l*3 + v] : 0.f;
            }
        }

    constexpr int NS = CIN / 64;
    auto ldaddr = [&](int st, int u) -> const u16* {
        int cc = st*64;
        if (u < 1024) {
            int row = u >> 3, q = u & 7;
            return W_ + (size_t)(ob + row)*ldw + cc + q*8;
        }
        int uu = u - 1024;
        int row = uu >> 3, q = uu & 7;
        int m = b*6144 + (row >> 5)*2048 + n0 + (row & 31);
        return X1 + (size_t)m*sx + cc + q*8;
    };
    auto lds_dst = [&](int u) -> char* {
        if (u < 1024) { int row = u >> 3, q = u & 7; return smem + row*144 + q*16; }
        int uu = u - 1024;
        int row = uu >> 3, q = uu & 7;
        return smem + 18432 + row*144 + q*16;
    };

    uint4v pf[7];
    #pragma unroll
    for (int j = 0; j < 7; ++j) pf[j] = *reinterpret_cast<const uint4v*>(ldaddr(0, tid + 256*j));
    #pragma unroll
    for (int j = 0; j < 7; ++j) *reinterpret_cast<uint4v*>(lds_dst(tid + 256*j)) = pf[j];

    for (int st = 0; st < NS; ++st) {
        __syncthreads();
        if (st + 1 < NS) {
            #pragma unroll
            for (int j = 0; j < 7; ++j)
                pf[j] = *reinterpret_cast<const uint4v*>(ldaddr(st+1, tid + 256*j));
        }
        #pragma unroll
        for (int ks = 0; ks < 2; ++ks) {
            half8 fA[4], fB[3];
            #pragma unroll
            for (int io = 0; io < 4; ++io)
                fA[io] = *reinterpret_cast<const half8*>(smem + (wr*64 + io*16 + l15)*144 + ks*64 + l4*16);
            #pragma unroll
            for (int i = 0; i < 3; ++i)
                fB[i] = *reinterpret_cast<const half8*>(smem + 18432 + (wc*48 + i*16 + l15)*144 + ks*64 + l4*16);
            #pragma unroll
            for (int io = 0; io < 4; ++io)
                #pragma unroll
                for (int jc = 0; jc < 3; ++jc)
                    acc[io][jc] = MFMAH(fA[io], fB[jc], acc[io][jc]);
        }
        __syncthreads();
        if (st + 1 < NS) {
            #pragma unroll
            for (int j = 0; j < 7; ++j)
                *reinterpret_cast<uint4v*>(lds_dst(tid + 256*j)) = pf[j];
        }
    }

    float* sd = (float*)smem;
    #pragma unroll
    for (int io = 0; io < 4; ++io)
        #pragma unroll
        for (int jc = 0; jc < 3; ++jc) {
            int jj = wc*48 + jc*16 + l15;
            int orow = wr*64 + io*16 + l4*4;
            *reinterpret_cast<f32x4*>(sd + jj*132 + orow) = acc[io][jc];
        }
    __syncthreads();

    #pragma unroll
    for (int rep = 0; rep < 2; ++rep) {
        int task = tid + 256*rep;
        int oc = task & 15, nl = (task >> 4) & 31;
        float d[3][8], x[3][8];
        #pragma unroll
        for (int v = 0; v < 3; ++v) {
            const float* dp = sd + (v*32 + nl)*132 + oc*8;
            #pragma unroll
            for (int e = 0; e < 8; ++e) d[v][e] = dp[e];
        }
        if (VIRT && ob != 0) {
            #pragma unroll
            for (int e = 0; e < 8; ++e) {
                int c = oc*8 + e;
                #pragma unroll
                for (int v = 0; v < 3; ++v)
                    x[v][e] = Pm[(size_t)(b*128 + c)*3 + v];
            }
        } else {
            #pragma unroll
            for (int v = 0; v < 3; ++v) {
                size_t m = (size_t)(b*6144 + v*2048 + n0 + nl);
                uint4v hx = *reinterpret_cast<const uint4v*>(X1 + m*sx + ob + oc*8);
                #pragma unroll
                for (int w = 0; w < 4; ++w) {
                    x[v][2*w]   = h2f((u16)(hx[w] & 0xffffu));
                    x[v][2*w+1] = h2f((u16)(hx[w] >> 16));
                }
            }
        }
        #pragma unroll
        for (int e = 0; e < 8; ++e) {
            float d0 = d[0][e], d1 = d[1][e], d2 = d[2][e];
            float dot = x[0][e]*d0 + x[1][e]*d1 + x[2][e]*d2;
            float dsq = d0*d0 + d1*d1 + d2*d2;
            float t = dot / (dsq + EPSV);
            if (dot < 0.f) { x[0][e] -= t*d0; x[1][e] -= t*d1; x[2][e] -= t*d2; }
        }
        #pragma unroll
        for (int v = 0; v < 3; ++v) {
            u32 hw[4];
            #pragma unroll
            for (int e2 = 0; e2 < 4; ++e2)
                hw[e2] = (u32)f2h(x[v][2*e2]) | ((u32)f2h(x[v][2*e2+1]) << 16);
            *reinterpret_cast<uint4v*>(Ov + (size_t)(b*6144 + v*2048 + n0 + nl)*so + ob + oc*8) =
                (uint4v){hw[0],hw[1],hw[2],hw[3]};
        }
    }
}

// ---- fused back: dir1 + VN-leaky (U in LDS) + fc1 + sc (+bias) + pool
// 256 thr, grid BB*64. LDS arena 76800B: U[0,26112) 96x272; stage W[26112,
// 44544) 128x144; stage X[44544,58368) 96x144; sd f32 96x132 @26112 (overlays
// stages; only live when stages/U dead). +pms/bias 3KB = 79.9KB -> 2 blk/CU.
template<int CSC, bool VIRT>
__global__ __launch_bounds__(256) void fused_back(
    const u16* __restrict__ Wd,      // dir1, ldw 128
    const u16* __restrict__ Wf1,     // fc1, ldw 128
    const u16* __restrict__ Wsc,     // sc, ldw 256
    const float* __restrict__ WsF,   // fp32 sc (bias), ldw 256
    const u16* __restrict__ T_,      // T, sx 128
    const u16* __restrict__ Xs,      // sc input, sx CSC
    const float* __restrict__ Pm,
    u16* __restrict__ Y,             // sy 128
    float* __restrict__ PmOut)
{
    __shared__ __align__(16) char smem[76800];
    __shared__ float pms[384];
    __shared__ float biasS_s[384];
    constexpr int U_OFF = 0;
    constexpr int W_OFF = 26112;
    constexpr int X_OFF = 44544;
    const int gx = blockIdx.x;
    const int b  = gx >> 6;
    const int n0 = (gx & 63) * 32;
    const int tid = threadIdx.x;
    const int lane = tid & 63;
    const int wid = __builtin_amdgcn_readfirstlane(tid >> 6);
    const int wr = wid & 1, wc = wid >> 1;
    const int l15 = lane & 15, l4 = lane >> 4;

    if (VIRT) {
        for (int t = tid; t < 384; t += 256) pms[t] = Pm[(size_t)b*384 + t];
        __syncthreads();
        for (int t = tid; t < 384; t += 256) {
            int o_l = t / 3, v = t - o_l*3;
            const float* wrow = WsF + (size_t)o_l*256 + 128;
            float s = 0.f;
            #pragma unroll 4
            for (int c = 0; c < 128; ++c) s += wrow[c]*pms[c*3 + v];
            biasS_s[t] = s;
        }
        __syncthreads();
    }

    // ---------------- phase 1: dir1 (128 x 128) ----------------
    f32x4 acc1[4][3];
    #pragma unroll
    for (int io = 0; io < 4; ++io)
        #pragma unroll
        for (int jc = 0; jc < 3; ++jc)
            acc1[io][jc] = (f32x4){0.f,0.f,0.f,0.f};

    auto ld1 = [&](int st, int u) -> const u16* {
        int cc = st*64;
        if (u < 1024) { int row = u >> 3, q = u & 7; return Wd + (size_t)row*128 + cc + q*8; }
        int uu = u - 1024;
        int row = uu >> 3, q = uu & 7;
        int m = b*6144 + (row >> 5)*2048 + n0 + (row & 31);
        return T_ + (size_t)m*128 + cc + q*8;
    };
    auto st1 = [&](int u) -> char* {
        if (u < 1024) { int row = u >> 3, q = u & 7; return smem + W_OFF + row*144 + q*16; }
        int uu = u - 1024;
        int row = uu >> 3, q = uu & 7;
        return smem + X_OFF + row*144 + q*16;
    };

    uint4v pf[7];
    #pragma unroll
    for (int j = 0; j < 7; ++j) pf[j] = *reinterpret_cast<const uint4v*>(ld1(0, tid + 256*j));
    #pragma unroll
    for (int j = 0; j < 7; ++j) *reinterpret_cast<uint4v*>(st1(tid + 256*j)) = pf[j];

    for (int st = 0; st < 2; ++st) {
        __syncthreads();
        if (st + 1 < 2) {
            #pragma unroll
            for (int j = 0; j < 7; ++j)
                pf[j] = *reinterpret_cast<const uint4v*>(ld1(st+1, tid + 256*j));
        }
        #pragma unroll
        for (int ks = 0; ks < 2; ++ks) {
            half8 fA[4], fB[3];
            #pragma unroll
            for (int io = 0; io < 4; ++io)
                fA[io] = *reinterpret_cast<const half8*>(smem + W_OFF + (wr*64 + io*16 + l15)*144 + ks*64 + l4*16);
            #pragma unroll
            for (int i = 0; i < 3; ++i)
                fB[i] = *reinterpret_cast<const half8*>(smem + X_OFF + (wc*48 + i*16 + l15)*144 + ks*64 + l4*16);
            #pragma unroll
            for (int io = 0; io < 4; ++io)
                #pragma unroll
                for (int jc = 0; jc < 3; ++jc)
                    acc1[io][jc] = MFMAH(fA[io], fB[jc], acc1[io][jc]);
        }
        __syncthreads();
        if (st + 1 < 2) {
            #pragma unroll
            for (int j = 0; j < 7; ++j)
                *reinterpret_cast<uint4v*>(st1(tid + 256*j)) = pf[j];
        }
    }

    // ---- VN-leaky in transpose; write U (K-major fp16) to LDS
    float* sd = (float*)(smem + W_OFF);   // 96 x 132 f32, overlays stage
    #pragma unroll
    for (int io = 0; io < 4; ++io)
        #pragma unroll
        for (int jc = 0; jc < 3; ++jc) {
            int jj = wc*48 + jc*16 + l15;
            int orow = wr*64 + io*16 + l4*4;
            *reinterpret_cast<f32x4*>(sd + jj*132 + orow) = acc1[io][jc];
        }
    __syncthreads();
    #pragma unroll
    for (int rep = 0; rep < 2; ++rep) {
        int task = tid + 256*rep;
        int oc = task & 15, nl = (task >> 4) & 31;
        float d[3][8], x[3][8];
        #pragma unroll
        for (int v = 0; v < 3; ++v) {
            const float* dp = sd + (v*32 + nl)*132 + oc*8;
            #pragma unroll
            for (int e = 0; e < 8; ++e) d[v][e] = dp[e];
        }
        #pragma unroll
        for (int v = 0; v < 3; ++v) {
            size_t m = (size_t)(b*6144 + v*2048 + n0 + nl);
            uint4v hx = *reinterpret_cast<const uint4v*>(T_ + m*128 + oc*8);
            #pragma unroll
            for (int w = 0; w < 4; ++w) {
                x[v][2*w]   = h2f((u16)(hx[w] & 0xffffu));
                x[v][2*w+1] = h2f((u16)(hx[w] >> 16));
            }
        }
        #pragma unroll
        for (int e = 0; e < 8; ++e) {
            float d0 = d[0][e], d1 = d[1][e], d2 = d[2][e];
            float dot = x[0][e]*d0 + x[1][e]*d1 + x[2][e]*d2;
            float dsq = d0*d0 + d1*d1 + d2*d2;
            float t = dot / (dsq + EPSV);
            if (dot < 0.f) { x[0][e] -= t*d0; x[1][e] -= t*d1; x[2][e] -= t*d2; }
        }
        #pragma unroll
        for (int v = 0; v < 3; ++v) {
            u32 hw[4];
            #pragma unroll
            for (int e2 = 0; e2 < 4; ++e2)
                hw[e2] = (u32)f2h(x[v][2*e2]) | ((u32)f2h(x[v][2*e2+1]) << 16);
            *reinterpret_cast<uint4v*>(smem + U_OFF + (v*32 + nl)*272 + oc*16) =
                (uint4v){hw[0],hw[1],hw[2],hw[3]};
        }
    }
    __syncthreads();

    // ---------------- phase 2: fc1 (K=128 from U) + sc (K=CSC staged) ----
    f32x4 acc2[4][3];
    #pragma unroll
    for (int io = 0; io < 4; ++io)
        #pragma unroll
        for (int jc = 0; jc < 3; ++jc) {
            int v = (wc*48 + jc*16) >> 5;
            #pragma unroll
            for (int r = 0; r < 4; ++r) {
                int o_l = wr*64 + io*16 + l4*4 + r;
                acc2[io][jc][r] = VIRT ? biasS_s[o_l*3 + v] : 0.f;
            }
        }

    constexpr int NS2 = 2 + CSC/64;
    auto ld2 = [&](int st, int u) -> const u16* {
        if (st < 2) {
            int row = u >> 3, q = u & 7;
            return Wf1 + (size_t)row*128 + st*64 + q*8;
        }
        int cc = (st - 2)*64;
        if (u < 1024) { int row = u >> 3, q = u & 7; return Wsc + (size_t)row*256 + cc + q*8; }
        int uu = u - 1024;
        int row = uu >> 3, q = uu & 7;
        int m = b*6144 + (row >> 5)*2048 + n0 + (row & 31);
        return Xs + (size_t)m*CSC + cc + q*8;
    };

    #pragma unroll
    for (int j = 0; j < 7; ++j) { int u = tid + 256*j; if (u < 1024) pf[j] = *reinterpret_cast<const uint4v*>(ld2(0, u)); }
    #pragma unroll
    for (int j = 0; j < 7; ++j) { int u = tid + 256*j; if (u < 1024) *reinterpret_cast<uint4v*>(st1(u)) = pf[j]; }

    for (int st = 0; st < NS2; ++st) {
        __syncthreads();
        int nv = (st + 1 < 2) ? 1024 : 1792;
        if (st + 1 < NS2) {
            #pragma unroll
            for (int j = 0; j < 7; ++j) { int u = tid + 256*j; if (u < nv) pf[j] = *reinterpret_cast<const uint4v*>(ld2(st+1, u)); }
        }
        #pragma unroll
        for (int ks = 0; ks < 2; ++ks) {
            half8 fA[4], fB[3];
            #pragma unroll
            for (int io = 0; io < 4; ++io)
                fA[io] = *reinterpret_cast<const half8*>(smem + W_OFF + (wr*64 + io*16 + l15)*144 + ks*64 + l4*16);
            if (st < 2) {
                #pragma unroll
                for (int i = 0; i < 3; ++i)
                    fB[i] = *reinterpret_cast<const half8*>(smem + U_OFF + (wc*48 + i*16 + l15)*272 + st*128 + ks*64 + l4*16);
            } else {
                #pragma unroll
                for (int i = 0; i < 3; ++i)
                    fB[i] = *reinterpret_cast<const half8*>(smem + X_OFF + (wc*48 + i*16 + l15)*144 + ks*64 + l4*16);
            }
            #pragma unroll
            for (int io = 0; io < 4; ++io)
                #pragma unroll
                for (int jc = 0; jc < 3; ++jc)
                    acc2[io][jc] = MFMAH(fA[io], fB[jc], acc2[io][jc]);
        }
        __syncthreads();
        if (st + 1 < NS2) {
            #pragma unroll
            for (int j = 0; j < 7; ++j) { int u = tid + 256*j; if (u < nv) *reinterpret_cast<uint4v*>(st1(u)) = pf[j]; }
        }
    }

    // ---- epilogue: Y write + pool (sd overlays stages; U dead)
    #pragma unroll
    for (int io = 0; io < 4; ++io)
        #pragma unroll
        for (int jc = 0; jc < 3; ++jc) {
            int jj = wc*48 + jc*16 + l15;
            int orow = wr*64 + io*16 + l4*4;
            *reinterpret_cast<f32x4*>(sd + jj*132 + orow) = acc2[io][jc];
        }
    __syncthreads();
    #pragma unroll
    for (int rep = 0; rep < 2; ++rep) {
        int task = tid + 256*rep;
        int oc = task & 15, nl = (task >> 4) & 31;
        #pragma unroll
        for (int v = 0; v < 3; ++v) {
            const float* dp = sd + (v*32 + nl)*132 + oc*8;
            u32 hw[4];
            #pragma unroll
            for (int e2 = 0; e2 < 4; ++e2)
                hw[e2] = (u32)f2h(dp[2*e2]) | ((u32)f2h(dp[2*e2+1]) << 16);
            *reinterpret_cast<uint4v*>(Y + (size_t)(b*6144 + v*2048 + n0 + nl)*128 + oc*8) =
                (uint4v){hw[0],hw[1],hw[2],hw[3]};
        }
    }
    for (int t = tid; t < 384; t += 256) {
        int v = t >> 7, o_l = t & 127;
        float sum = 0.f;
        #pragma unroll 8
        for (int nl = 0; nl < 32; ++nl) sum += sd[(v*32 + nl)*132 + o_l];
        atomicAdd(&PmOut[(size_t)(b*128 + o_l)*3 + v], sum * (1.f/(float)NPT));
    }
}

// ------------------------------------------------- weight fp16 convert
#define WO_FCPOS 0
#define WO_DIR0  32768
#define WO_FC0   360448
#define WO_DIR1  524288
#define WO_FC1   606208
#define WO_SC    688128
#define WTOT     851968
__global__ __launch_bounds__(256)
void convert_w_kernel(const float* __restrict__ s0, const float* __restrict__ s1,
                      const float* __restrict__ s2, const float* __restrict__ s3,
                      const float* __restrict__ s4, const float* __restrict__ s5,
                      u16* __restrict__ Wf) {
    int t = blockIdx.x*256 + threadIdx.x;
    if (t >= WTOT) return;
    const float* src; int base;
    if      (t < WO_DIR0) { src = s0; base = WO_FCPOS; }
    else if (t < WO_FC0)  { src = s1; base = WO_DIR0; }
    else if (t < WO_DIR1) { src = s2; base = WO_FC0; }
    else if (t < WO_FC1)  { src = s3; base = WO_DIR1; }
    else if (t < WO_SC)   { src = s4; base = WO_FC1; }
    else                  { src = s5; base = WO_SC; }
    Wf[t] = f2h(src[t - base]);
}

// ----------------------------------------------------- head: leaky(0.2)+fc_c
__global__ __launch_bounds__(128)
void final_head_kernel(const float* __restrict__ q, const float* __restrict__ Wdir,
                       const float* __restrict__ Wfc, float* __restrict__ out) {
    int b = blockIdx.x; int o = threadIdx.x;
    __shared__ float qs[128][3];
    __shared__ float zs[128][3];
    qs[o][0] = q[((size_t)b*128 + o)*3 + 0];
    qs[o][1] = q[((size_t)b*128 + o)*3 + 1];
    qs[o][2] = q[((size_t)b*128 + o)*3 + 2];
    __syncthreads();
    float d0 = 0.f, d1 = 0.f, d2 = 0.f;
    for (int c = 0; c < 128; ++c) {
        float w = Wdir[o*128 + c];
        d0 += w*qs[c][0]; d1 += w*qs[c][1]; d2 += w*qs[c][2];
    }
    float x0 = qs[o][0], x1 = qs[o][1], x2 = qs[o][2];
    float dot = d0*x0 + d1*x1 + d2*x2;
    float dsq = d0*d0 + d1*d1 + d2*d2;
    float t = dot / (dsq + EPSV);
    bool pos = dot >= 0.f;
    float g0 = pos ? x0 : (x0 - t*d0);
    float g1 = pos ? x1 : (x1 - t*d1);
    float g2 = pos ? x2 : (x2 - t*d2);
    zs[o][0] = 0.2f*x0 + 0.8f*g0;
    zs[o][1] = 0.2f*x1 + 0.8f*g1;
    zs[o][2] = 0.2f*x2 + 0.8f*g2;
    __syncthreads();
    float c0 = 0.f, c1 = 0.f, c2 = 0.f;
    for (int c = 0; c < 128; ++c) {
        float w = Wfc[o*128 + c];
        c0 += w*zs[c][0]; c1 += w*zs[c][1]; c2 += w*zs[c][2];
    }
    out[((size_t)b*128 + o)*3 + 0] = c0;
    out[((size_t)b*128 + o)*3 + 1] = c1;
    out[((size_t)b*128 + o)*3 + 2] = c2;
}

extern "C" void kernel_launch(void* const* d_in, const int* in_sizes, int n_in,
                              void* d_out, int out_size, void* d_ws, size_t ws_size,
                              hipStream_t stream) {
    const float* p           = (const float*)d_in[0];
    const float* w_conv_feat = (const float*)d_in[1];
    const float* w_conv_dir  = (const float*)d_in[2];
    const float* w_fc_pos    = (const float*)d_in[3];
    const float* blk_dir0    = (const float*)d_in[4];
    const float* blk_fc0     = (const float*)d_in[5];
    const float* blk_dir1    = (const float*)d_in[6];
    const float* blk_fc1     = (const float*)d_in[7];
    const float* blk_sc      = (const float*)d_in[8];
    const float* w_actc_dir  = (const float*)d_in[9];
    const float* w_fc_c      = (const float*)d_in[10];
    float* out = (float*)d_out;

    char* wsb = (char*)d_ws;
    size_t cur = 0;
    auto carve = [&](size_t nbytes) -> char* {
        char* r = wsb + cur;
        cur += (nbytes + 255) & ~(size_t)255;
        return r;
    };
    const size_t MTOT = (size_t)BB*3*NPT;      // 24576 columns
    float* Pm0   = (float*)carve(1536*4);
    float* Pm1   = (float*)carve(1536*4);
    u16* Wf    = (u16*)carve((size_t)WTOT*2);
    u16* net1  = (u16*)carve(MTOT*128*2);      // fc_pos input; later T
    u16* X0    = (u16*)carve(MTOT*256*2);      // fc_pos out; later Y ping
    u16* Ab    = (u16*)carve(MTOT*256*2);      // A (dir0 out)
    u16* Yb    = (u16*)carve(MTOT*128*2);      // Y pong
    float* PmBuf[2] = { Pm0, Pm1 };

    convert_w_kernel<<<(WTOT+255)/256, 256, 0, stream>>>(
        w_fc_pos, blk_dir0, blk_fc0, blk_dir1, blk_fc1, blk_sc, Wf);
    knn_edge_kernel<<<BB*NPT, 256, 0, stream>>>(p, w_conv_feat, w_conv_dir, net1);

    // fc_pos: [256 x 128] x net1 -> X0
    gemm_plain<256,128,0,false,false><<<dim3(384,2), 256, 0, stream>>>(
        Wf+WO_FCPOS, 128, net1, 128,
        nullptr, 0, nullptr, 0,
        nullptr, nullptr, X0, 256, nullptr);

    const u16* Yp = nullptr;
    for (int i = 0; i < 5; ++i) {
        size_t od0 = WO_DIR0 + (size_t)i*65536;
        size_t of0 = WO_FC0  + (size_t)i*32768;
        size_t od1 = WO_DIR1 + (size_t)i*16384;
        size_t of1 = WO_FC1  + (size_t)i*16384;
        size_t osc = WO_SC   + (size_t)i*32768;
        float* PmPrev = PmBuf[(i+1) & 1];
        float* PmCur  = PmBuf[i & 1];

        // dir0 also zeroes all 1536 floats of PmCur (block 0) — replaces memset.
        if (i == 0) {
            gemm_dir<256,256,false><<<dim3(BB*64,2), 256, 0, stream>>>(
                Wf+od0, 256, X0, 256, nullptr, nullptr, Ab, 256, PmCur);
        } else {
            gemm_dir<256,128,true><<<dim3(BB*64,2), 256, 0, stream>>>(
                Wf+od0, 256, Yp, 128,
                blk_dir0 + (size_t)i*65536, PmPrev, Ab, 256, PmCur);
        }
        gemm_plain<128,256,0,false,false><<<dim3(384,1), 256, 0, stream>>>(
            Wf+of0, 256, Ab, 256,
            nullptr, 0, nullptr, 0,
            nullptr, nullptr, net1, 128, nullptr);

        u16* outv = (i % 2 == 0) ? Yb : X0;
        if (i == 0) {
            fused_back<256,false><<<BB*64, 256, 0, stream>>>(
                Wf+od1, Wf+of1, Wf+osc, nullptr,
                net1, X0, nullptr, outv, PmCur);
        } else {
            fused_back<128,true><<<BB*64, 256, 0, stream>>>(
                Wf+od1, Wf+of1, Wf+osc, blk_sc + (size_t)i*32768,
                net1, Yp, PmPrev, outv, PmCur);
        }
        Yp = outv;
    }

    final_head_kernel<<<BB, 128, 0, stream>>>(PmBuf[0], w_actc_dir, w_fc_c, out);
}

// Round 20
// 291.297 us; speedup vs baseline: 1.2238x; 1.0851x over previous
//
#include <hip/hip_runtime.h>
#include <math.h>

#define NPT 2048
#define BB 4
#define KNN 20
#define EPSV 1e-6f

typedef unsigned short u16;
typedef unsigned int u32;
typedef _Float16 half8 __attribute__((ext_vector_type(8)));
typedef __attribute__((ext_vector_type(4))) float f32x4;
typedef __attribute__((ext_vector_type(4))) u32 uint4v;

#define MFMAH(a,b,c) __builtin_amdgcn_mfma_f32_16x16x32_f16((a),(b),(c),0,0,0)

__device__ __forceinline__ u16 f2h(float f) {
    _Float16 h = (_Float16)f;
    return __builtin_bit_cast(u16, h);
}
__device__ __forceinline__ float h2f(u16 b) {
    return (float)__builtin_bit_cast(_Float16, b);
}

// -------------------- kNN top-20 (radix-select) + fused edge conv + mean_k
// (round-19 version, verbatim — passed at 77us)
__global__ __launch_bounds__(256)
void knn_edge_kernel(const float* __restrict__ p,
                     const float* __restrict__ wf, const float* __restrict__ wd,
                     u16* __restrict__ net1) {
    int bn = blockIdx.x;
    int b = bn >> 11, n = bn & (NPT - 1);
    const float* pb = p + (size_t)b * NPT * 3;
    float qx = pb[n*3+0], qy = pb[n*3+1], qz = pb[n*3+2];
    float qq = qx*qx + qy*qy + qz*qz;
    __shared__ u32 keys[NPT];
    __shared__ int hist[4][256];
    __shared__ int wtot[4];
    __shared__ int sh_byte, sh_ngt, sure_cnt, tie_cnt;
    __shared__ int tie_m[64];
    __shared__ int sel[KNN];
    __shared__ float nb[KNN][3];
    int tid = threadIdx.x;
    int lane = tid & 63, wv = tid >> 6;
    for (int m = tid; m < NPT; m += 256) {
        float px = pb[m*3+0], py = pb[m*3+1], pz = pb[m*3+2];
        float sc = 2.f*(qx*px + qy*py + qz*pz) - qq - (px*px + py*py + pz*pz);
        u32 u = __builtin_bit_cast(u32, sc);
        keys[m] = u ^ (u32)(((int)u >> 31) | (int)0x80000000);
    }
    if (tid == 0) { sure_cnt = 0; tie_cnt = 0; }
    __syncthreads();
    u32 prefix = 0; int need = KNN;
    for (int pass = 3; pass >= 0; --pass) {
        int shift = pass * 8;
        u32 maskhi = (pass == 3) ? 0u : (0xFFFFFFFFu << (shift + 8));
        hist[0][tid] = 0; hist[1][tid] = 0; hist[2][tid] = 0; hist[3][tid] = 0;
        __syncthreads();
        int prevbin = -1, cnt = 0;
        #pragma unroll
        for (int j = 0; j < 8; ++j) {
            u32 key = keys[tid + 256*j];
            int bin = ((key & maskhi) == (prefix & maskhi)) ? (int)((key >> shift) & 255) : -1;
            if (bin == prevbin) { ++cnt; }
            else {
                if (prevbin >= 0) atomicAdd(&hist[wv][prevbin], cnt);
                prevbin = bin; cnt = 1;
            }
        }
        if (prevbin >= 0) atomicAdd(&hist[wv][prevbin], cnt);
        __syncthreads();
        int own = hist[0][tid] + hist[1][tid] + hist[2][tid] + hist[3][tid];
        int sum = own;
        #pragma unroll
        for (int off = 1; off < 64; off <<= 1) {
            int v = __shfl_down(sum, off, 64);
            if (lane + off < 64) sum += v;
        }
        if (lane == 0) wtot[wv] = sum;
        __syncthreads();
        int addhi = 0;
        #pragma unroll
        for (int w2 = 0; w2 < 4; ++w2) if (w2 > wv) addhi += wtot[w2];
        int cnt_ge = sum + addhi;
        int cnt_gt = cnt_ge - own;
        if (cnt_ge >= need && cnt_gt < need) { sh_byte = tid; sh_ngt = cnt_gt; }
        __syncthreads();
        prefix |= ((u32)sh_byte) << shift;
        need -= sh_ngt;
        __syncthreads();
    }
    u32 T = prefix;
    #pragma unroll
    for (int j = 0; j < 8; ++j) {
        int m = tid + 256*j;
        u32 key = keys[m];
        if (key > T) {
            int slot = atomicAdd(&sure_cnt, 1);
            sel[slot] = m;
        } else if (key == T) {
            int t = atomicAdd(&tie_cnt, 1);
            if (t < 64) tie_m[t] = m;
        }
    }
    __syncthreads();
    if (tid == 0) {
        int base = sure_cnt;
        int r = KNN - base;
        int tc = tie_cnt;
        if (tc == r) {
            for (int t2 = 0; t2 < r; ++t2) sel[base + t2] = tie_m[t2];
        } else if (tc <= 64) {
            for (int t2 = 0; t2 < r; ++t2) {
                int best = 1 << 30, bj = 0;
                for (int t3 = 0; t3 < tc; ++t3)
                    if (tie_m[t3] < best) { best = tie_m[t3]; bj = t3; }
                tie_m[bj] = 1 << 30;
                sel[base + t2] = best;
            }
        } else {
            int got = 0;
            for (int m = 0; m < NPT && got < r; ++m)
                if (keys[m] == T) { sel[base + got] = m; ++got; }
        }
    }
    __syncthreads();
    if (tid < KNN) {
        int j = sel[tid];
        nb[tid][0] = pb[j*3+0]; nb[tid][1] = pb[j*3+1]; nb[tid][2] = pb[j*3+2];
    }
    __syncthreads();
    {
        float* part = (float*)keys;
        int o = tid & 127, kh = tid >> 7;
        float wfa = wf[o*3+0], wfb = wf[o*3+1], wfc = wf[o*3+2];
        float wda = wd[o*3+0], wdb = wd[o*3+1], wdc = wd[o*3+2];
        float cx = qx, cy = qy, cz = qz;
        float a0 = 0.f, a1 = 0.f, a2 = 0.f;
        int k0 = kh * 10;
        #pragma unroll
        for (int k = 0; k < 10; ++k) {
            float nx = nb[k0+k][0], ny = nb[k0+k][1], nz = nb[k0+k][2];
            float rx = nx-cx, ry = ny-cy, rz = nz-cz;
            float sx = ny*cz - nz*cy;
            float sy = nz*cx - nx*cz;
            float sz = nx*cy - ny*cx;
            float fx = wfa*rx + wfb*cx + wfc*sx;
            float fy = wfa*ry + wfb*cy + wfc*sy;
            float fz = wfa*rz + wfb*cz + wfc*sz;
            float dx0 = wda*rx + wdb*cx + wdc*sx;
            float dy0 = wda*ry + wdb*cy + wdc*sy;
            float dz0 = wda*rz + wdb*cz + wdc*sz;
            float dot = fx*dx0 + fy*dy0 + fz*dz0;
            float dsq = dx0*dx0 + dy0*dy0 + dz0*dz0;
            float t = dot / (dsq + EPSV);
            bool pos = dot >= 0.f;
            float gx = pos ? fx : (fx - t*dx0);
            float gy = pos ? fy : (fy - t*dy0);
            float gz = pos ? fz : (fz - t*dz0);
            a0 += 0.2f*fx + 0.8f*gx;
            a1 += 0.2f*fy + 0.8f*gy;
            a2 += 0.2f*fz + 0.8f*gz;
        }
        if (kh == 1) { part[o*3+0] = a0; part[o*3+1] = a1; part[o*3+2] = a2; }
        __syncthreads();
        if (kh == 0) {
            a0 += part[o*3+0]; a1 += part[o*3+1]; a2 += part[o*3+2];
            const float s = 1.f / (float)KNN;
            net1[(size_t)(b*6144 +          n)*128 + o] = f2h(a0*s);
            net1[(size_t)(b*6144 + 2048  + n)*128 + o] = f2h(a1*s);
            net1[(size_t)(b*6144 + 4096  + n)*128 + o] = f2h(a2*s);
        }
    }
}

// ------------------------------------------------------ MFMA fp16 GEMM
// (round-19 version, verbatim — used for fc_pos only) Tile 128o x 64m.
template<int O, int C1, int C2, bool POOL, bool BIASED>
__global__ __launch_bounds__(256) void gemm_plain(
    const u16* __restrict__ W1, int ldw1,
    const u16* __restrict__ X1, int sx1,
    const u16* __restrict__ W2, int ldw2,
    const u16* __restrict__ X2, int sx2,
    const float* __restrict__ WscF, const float* __restrict__ PmPrev,
    u16* __restrict__ Y, int sy,
    float* __restrict__ PmOut)
{
    __shared__ __align__(16) char smem[64*132*4];
    __shared__ float pms[128];
    __shared__ float biasS_s[128];
    const int m0 = blockIdx.x * 64;
    const int ob = blockIdx.y * 128;
    const int b   = m0 / 6144;
    const int vec = (m0 % 6144) / 2048;
    const int tid = threadIdx.x;
    const int lane = tid & 63;
    const int wid = __builtin_amdgcn_readfirstlane(tid >> 6);
    const int wr = wid & 1, wc = wid >> 1;
    const int l15 = lane & 15, l4 = lane >> 4;

    if (BIASED) {
        if (tid < 128) pms[tid] = PmPrev[(size_t)(b*128 + tid)*3 + vec];
        __syncthreads();
        if (tid < 128) {
            const float* wrow = WscF + (size_t)tid*256 + 128;
            float s = 0.f;
            #pragma unroll 4
            for (int c = 0; c < 128; ++c) s += wrow[c]*pms[c];
            biasS_s[tid] = s;
        }
        __syncthreads();
    }

    f32x4 acc[4][2];
    #pragma unroll
    for (int io = 0; io < 4; ++io) {
        float bv[4];
        #pragma unroll
        for (int r = 0; r < 4; ++r)
            bv[r] = BIASED ? biasS_s[wr*64 + io*16 + l4*4 + r] : 0.f;
        #pragma unroll
        for (int jc = 0; jc < 2; ++jc)
            #pragma unroll
            for (int r = 0; r < 4; ++r) acc[io][jc][r] = bv[r];
    }

    constexpr int NS = (C1 + C2) / 64;
    auto ldaddr = [&](int st, int u) -> const u16* {
        const bool ph2 = (st >= C1/64);
        const u16* w = ph2 ? W2 : W1; const u16* x = ph2 ? X2 : X1;
        int ldw = ph2 ? ldw2 : ldw1; int sx = ph2 ? sx2 : sx1;
        int cc = (ph2 ? (st - C1/64) : st) * 64;
        if (u < 1024) {
            int row = u >> 3, q = u & 7;
            return w + (size_t)(ob + row)*ldw + cc + q*8;
        }
        int uu = u - 1024;
        int row = uu >> 3, q = uu & 7;
        return x + (size_t)(m0 + row)*sx + cc + q*8;
    };
    auto lds_dst = [&](int u) -> char* {
        if (u < 1024) { int row = u >> 3, q = u & 7; return smem + row*144 + q*16; }
        int uu = u - 1024;
        int row = uu >> 3, q = uu & 7;
        return smem + 18432 + row*144 + q*16;
    };

    uint4v pf[6];
    #pragma unroll
    for (int j = 0; j < 6; ++j) pf[j] = *reinterpret_cast<const uint4v*>(ldaddr(0, tid + 256*j));
    #pragma unroll
    for (int j = 0; j < 6; ++j) *reinterpret_cast<uint4v*>(lds_dst(tid + 256*j)) = pf[j];

    for (int st = 0; st < NS; ++st) {
        __syncthreads();
        if (st + 1 < NS) {
            #pragma unroll
            for (int j = 0; j < 6; ++j)
                pf[j] = *reinterpret_cast<const uint4v*>(ldaddr(st+1, tid + 256*j));
        }
        #pragma unroll
        for (int ks = 0; ks < 2; ++ks) {
            half8 fA[4], fB[2];
            #pragma unroll
            for (int io = 0; io < 4; ++io)
                fA[io] = *reinterpret_cast<const half8*>(smem + (wr*64 + io*16 + l15)*144 + ks*64 + l4*16);
            #pragma unroll
            for (int i = 0; i < 2; ++i)
                fB[i] = *reinterpret_cast<const half8*>(smem + 18432 + (wc*32 + i*16 + l15)*144 + ks*64 + l4*16);
            #pragma unroll
            for (int io = 0; io < 4; ++io)
                #pragma unroll
                for (int jc = 0; jc < 2; ++jc)
                    acc[io][jc] = MFMAH(fA[io], fB[jc], acc[io][jc]);
        }
        __syncthreads();
        if (st + 1 < NS) {
            #pragma unroll
            for (int j = 0; j < 6; ++j)
                *reinterpret_cast<uint4v*>(lds_dst(tid + 256*j)) = pf[j];
        }
    }

    float* sd = (float*)smem;
    #pragma unroll
    for (int io = 0; io < 4; ++io)
        #pragma unroll
        for (int jc = 0; jc < 2; ++jc) {
            int jj = wc*32 + jc*16 + l15;
            int orow = wr*64 + io*16 + l4*4;
            *reinterpret_cast<f32x4*>(sd + jj*132 + orow) = acc[io][jc];
        }
    __syncthreads();

    #pragma unroll
    for (int rep = 0; rep < 4; ++rep) {
        int task = tid + 256*rep;
        int oc = task & 15, ml = task >> 4;
        const float* dp = sd + ml*132 + oc*8;
        u32 hw[4];
        #pragma unroll
        for (int e2 = 0; e2 < 4; ++e2)
            hw[e2] = (u32)f2h(dp[2*e2]) | ((u32)f2h(dp[2*e2+1]) << 16);
        *reinterpret_cast<uint4v*>(Y + (size_t)(m0 + ml)*sy + ob + oc*8) =
            (uint4v){hw[0],hw[1],hw[2],hw[3]};
    }

    if (POOL) {
        int o_l = tid & 127, half = tid >> 7;
        float sum = 0.f;
        #pragma unroll 8
        for (int c = 0; c < 32; ++c) sum += sd[(half*32 + c)*132 + o_l];
        atomicAdd(&PmOut[(size_t)(b*128 + o_l)*3 + vec], sum * (1.f/(float)NPT));
    }
}

// ------------------- MFMA fp16 dir GEMM + fused VN-leaky(0) epilogue
// (round-19 version, verbatim — used for dir0 only)
template<int O, int CIN, bool VIRT>
__global__ __launch_bounds__(256) void gemm_dir(
    const u16* __restrict__ W_, int ldw,
    const u16* __restrict__ X1, int sx,
    const float* __restrict__ WdF, const float* __restrict__ Pm,
    u16* __restrict__ Ov, int so,
    float* __restrict__ PmZero)
{
    __shared__ __align__(16) char smem[96*132*4];
    __shared__ float pmd[384];
    __shared__ float biasD_s[384];
    const int gx = blockIdx.x;
    const int b  = gx >> 6;
    const int n0 = (gx & 63) * 32;
    const int ob = blockIdx.y * 128;
    const int tid = threadIdx.x;
    const int lane = tid & 63;
    const int wid = __builtin_amdgcn_readfirstlane(tid >> 6);
    const int wr = wid & 1, wc = wid >> 1;
    const int l15 = lane & 15, l4 = lane >> 4;

    if (PmZero != nullptr && gx == 0 && blockIdx.y == 0)
        for (int t = tid; t < 1536; t += 256) PmZero[t] = 0.f;

    if (VIRT) {
        for (int t = tid; t < 384; t += 256) pmd[t] = Pm[(size_t)b*384 + t];
        __syncthreads();
        for (int t = tid; t < 384; t += 256) {
            int o_l = t / 3, v = t - o_l*3;
            const float* wrow = WdF + (size_t)(ob + o_l)*256 + 128;
            float s = 0.f;
            #pragma unroll 4
            for (int c = 0; c < 128; ++c) s += wrow[c]*pmd[c*3 + v];
            biasD_s[t] = s;
        }
        __syncthreads();
    }

    f32x4 acc[4][3];
    #pragma unroll
    for (int io = 0; io < 4; ++io)
        #pragma unroll
        for (int jc = 0; jc < 3; ++jc) {
            int v = (wc*48 + jc*16) >> 5;
            #pragma unroll
            for (int r = 0; r < 4; ++r) {
                int o_l = wr*64 + io*16 + l4*4 + r;
                acc[io][jc][r] = VIRT ? biasD_s[o_l*3 + v] : 0.f;
            }
        }

    constexpr int NS = CIN / 64;
    auto ldaddr = [&](int st, int u) -> const u16* {
        int cc = st*64;
        if (u < 1024) {
            int row = u >> 3, q = u & 7;
            return W_ + (size_t)(ob + row)*ldw + cc + q*8;
        }
        int uu = u - 1024;
        int row = uu >> 3, q = uu & 7;
        int m = b*6144 + (row >> 5)*2048 + n0 + (row & 31);
        return X1 + (size_t)m*sx + cc + q*8;
    };
    auto lds_dst = [&](int u) -> char* {
        if (u < 1024) { int row = u >> 3, q = u & 7; return smem + row*144 + q*16; }
        int uu = u - 1024;
        int row = uu >> 3, q = uu & 7;
        return smem + 18432 + row*144 + q*16;
    };

    uint4v pf[7];
    #pragma unroll
    for (int j = 0; j < 7; ++j) pf[j] = *reinterpret_cast<const uint4v*>(ldaddr(0, tid + 256*j));
    #pragma unroll
    for (int j = 0; j < 7; ++j) *reinterpret_cast<uint4v*>(lds_dst(tid + 256*j)) = pf[j];

    for (int st = 0; st < NS; ++st) {
        __syncthreads();
        if (st + 1 < NS) {
            #pragma unroll
            for (int j = 0; j < 7; ++j)
                pf[j] = *reinterpret_cast<const uint4v*>(ldaddr(st+1, tid + 256*j));
        }
        #pragma unroll
        for (int ks = 0; ks < 2; ++ks) {
            half8 fA[4], fB[3];
            #pragma unroll
            for (int io = 0; io < 4; ++io)
                fA[io] = *reinterpret_cast<const half8*>(smem + (wr*64 + io*16 + l15)*144 + ks*64 + l4*16);
            #pragma unroll
            for (int i = 0; i < 3; ++i)
                fB[i] = *reinterpret_cast<const half8*>(smem + 18432 + (wc*48 + i*16 + l15)*144 + ks*64 + l4*16);
            #pragma unroll
            for (int io = 0; io < 4; ++io)
                #pragma unroll
                for (int jc = 0; jc < 3; ++jc)
                    acc[io][jc] = MFMAH(fA[io], fB[jc], acc[io][jc]);
        }
        __syncthreads();
        if (st + 1 < NS) {
            #pragma unroll
            for (int j = 0; j < 7; ++j)
                *reinterpret_cast<uint4v*>(lds_dst(tid + 256*j)) = pf[j];
        }
    }

    float* sd = (float*)smem;
    #pragma unroll
    for (int io = 0; io < 4; ++io)
        #pragma unroll
        for (int jc = 0; jc < 3; ++jc) {
            int jj = wc*48 + jc*16 + l15;
            int orow = wr*64 + io*16 + l4*4;
            *reinterpret_cast<f32x4*>(sd + jj*132 + orow) = acc[io][jc];
        }
    __syncthreads();

    #pragma unroll
    for (int rep = 0; rep < 2; ++rep) {
        int task = tid + 256*rep;
        int oc = task & 15, nl = (task >> 4) & 31;
        float d[3][8], x[3][8];
        #pragma unroll
        for (int v = 0; v < 3; ++v) {
            const float* dp = sd + (v*32 + nl)*132 + oc*8;
            #pragma unroll
            for (int e = 0; e < 8; ++e) d[v][e] = dp[e];
        }
        if (VIRT && ob != 0) {
            #pragma unroll
            for (int e = 0; e < 8; ++e) {
                int c = oc*8 + e;
                #pragma unroll
                for (int v = 0; v < 3; ++v)
                    x[v][e] = Pm[(size_t)(b*128 + c)*3 + v];
            }
        } else {
            #pragma unroll
            for (int v = 0; v < 3; ++v) {
                size_t m = (size_t)(b*6144 + v*2048 + n0 + nl);
                uint4v hx = *reinterpret_cast<const uint4v*>(X1 + m*sx + ob + oc*8);
                #pragma unroll
                for (int w = 0; w < 4; ++w) {
                    x[v][2*w]   = h2f((u16)(hx[w] & 0xffffu));
                    x[v][2*w+1] = h2f((u16)(hx[w] >> 16));
                }
            }
        }
        #pragma unroll
        for (int e = 0; e < 8; ++e) {
            float d0 = d[0][e], d1 = d[1][e], d2 = d[2][e];
            float dot = x[0][e]*d0 + x[1][e]*d1 + x[2][e]*d2;
            float dsq = d0*d0 + d1*d1 + d2*d2;
            float t = dot / (dsq + EPSV);
            if (dot < 0.f) { x[0][e] -= t*d0; x[1][e] -= t*d1; x[2][e] -= t*d2; }
        }
        #pragma unroll
        for (int v = 0; v < 3; ++v) {
            u32 hw[4];
            #pragma unroll
            for (int e2 = 0; e2 < 4; ++e2)
                hw[e2] = (u32)f2h(x[v][2*e2]) | ((u32)f2h(x[v][2*e2+1]) << 16);
            *reinterpret_cast<uint4v*>(Ov + (size_t)(b*6144 + v*2048 + n0 + nl)*so + ob + oc*8) =
                (uint4v){hw[0],hw[1],hw[2],hw[3]};
        }
    }
}

// ---- fused back v2: fc0 + (T in LDS) + dir1 + leaky (U in LDS) + fc1+sc+pool
// 256 thr, grid BB*64. Arena 77568B:
//   T  @0      (96x272)  — also SX stage @0 later (T dead), sdE @0 in epilogue
//   U  @26112  (96x272)  — sdT @26112 (50688) during fc0 transpose (U dead)
//   SW @52224  (128x144) — sdh @52224 (48x132x4) during leaky (SW dead)
// Peak 77568 + 3KB bias => 2 blocks/CU.
template<int CSC, bool VIRT>
__global__ __launch_bounds__(256) void fused_back(
    const u16* __restrict__ Wf0,     // fc0, ldw 256
    const u16* __restrict__ Wd,      // dir1, ldw 128
    const u16* __restrict__ Wf1,     // fc1, ldw 128
    const u16* __restrict__ Wsc,     // sc, ldw 256
    const float* __restrict__ WsF,   // fp32 sc (bias), ldw 256
    const u16* __restrict__ A_,      // fc0 input (dir0 out), sx 256
    const u16* __restrict__ Xs,      // sc input, sx CSC
    const float* __restrict__ Pm,
    u16* __restrict__ Y,             // sy 128
    float* __restrict__ PmOut)
{
    __shared__ __align__(16) char smem[77568];
    __shared__ float pms[384];
    __shared__ float biasS_s[384];
    constexpr int T_OFF = 0;
    constexpr int U_OFF = 26112;
    constexpr int SW    = 52224;
    const int gx = blockIdx.x;
    const int b  = gx >> 6;
    const int n0 = (gx & 63) * 32;
    const int tid = threadIdx.x;
    const int lane = tid & 63;
    const int wid = __builtin_amdgcn_readfirstlane(tid >> 6);
    const int wr = wid & 1, wc = wid >> 1;
    const int l15 = lane & 15, l4 = lane >> 4;

    if (VIRT) {
        for (int t = tid; t < 384; t += 256) pms[t] = Pm[(size_t)b*384 + t];
        __syncthreads();
        for (int t = tid; t < 384; t += 256) {
            int o_l = t / 3, v = t - o_l*3;
            const float* wrow = WsF + (size_t)o_l*256 + 128;
            float s = 0.f;
            #pragma unroll 4
            for (int c = 0; c < 128; ++c) s += wrow[c]*pms[c*3 + v];
            biasS_s[t] = s;
        }
        __syncthreads();
    }

    uint4v pf[7];

    // ---------------- phase A: fc0 (128 x 256) over A ----------------
    {
        f32x4 accT[4][3];
        #pragma unroll
        for (int io = 0; io < 4; ++io)
            #pragma unroll
            for (int jc = 0; jc < 3; ++jc)
                accT[io][jc] = (f32x4){0.f,0.f,0.f,0.f};

        auto ldA = [&](int st, int u) -> const u16* {
            int cc = st*64;
            if (u < 1024) { int row = u >> 3, q = u & 7; return Wf0 + (size_t)row*256 + cc + q*8; }
            int uu = u - 1024;
            int row = uu >> 3, q = uu & 7;
            int m = b*6144 + (row >> 5)*2048 + n0 + (row & 31);
            return A_ + (size_t)m*256 + cc + q*8;
        };
        auto stA = [&](int u) -> char* {
            if (u < 1024) { int row = u >> 3, q = u & 7; return smem + SW + row*144 + q*16; }
            int uu = u - 1024;
            int row = uu >> 3, q = uu & 7;
            return smem + T_OFF + row*144 + q*16;   // SX region @0 (T not yet live)
        };

        #pragma unroll
        for (int j = 0; j < 7; ++j) pf[j] = *reinterpret_cast<const uint4v*>(ldA(0, tid + 256*j));
        #pragma unroll
        for (int j = 0; j < 7; ++j) *reinterpret_cast<uint4v*>(stA(tid + 256*j)) = pf[j];

        for (int st = 0; st < 4; ++st) {
            __syncthreads();
            if (st + 1 < 4) {
                #pragma unroll
                for (int j = 0; j < 7; ++j)
                    pf[j] = *reinterpret_cast<const uint4v*>(ldA(st+1, tid + 256*j));
            }
            #pragma unroll
            for (int ks = 0; ks < 2; ++ks) {
                half8 fA[4], fB[3];
                #pragma unroll
                for (int io = 0; io < 4; ++io)
                    fA[io] = *reinterpret_cast<const half8*>(smem + SW + (wr*64 + io*16 + l15)*144 + ks*64 + l4*16);
                #pragma unroll
                for (int i = 0; i < 3; ++i)
                    fB[i] = *reinterpret_cast<const half8*>(smem + T_OFF + (wc*48 + i*16 + l15)*144 + ks*64 + l4*16);
                #pragma unroll
                for (int io = 0; io < 4; ++io)
                    #pragma unroll
                    for (int jc = 0; jc < 3; ++jc)
                        accT[io][jc] = MFMAH(fA[io], fB[jc], accT[io][jc]);
            }
            __syncthreads();
            if (st + 1 < 4) {
                #pragma unroll
                for (int j = 0; j < 7; ++j)
                    *reinterpret_cast<uint4v*>(stA(tid + 256*j)) = pf[j];
            }
        }

        // transpose accT -> T (fp16 K-major) via sdT @U_OFF (U+SW dead)
        float* sdT = (float*)(smem + U_OFF);
        #pragma unroll
        for (int io = 0; io < 4; ++io)
            #pragma unroll
            for (int jc = 0; jc < 3; ++jc) {
                int jj = wc*48 + jc*16 + l15;
                int orow = wr*64 + io*16 + l4*4;
                *reinterpret_cast<f32x4*>(sdT + jj*132 + orow) = accT[io][jc];
            }
        __syncthreads();
        #pragma unroll
        for (int rep = 0; rep < 2; ++rep) {
            int task = tid + 256*rep;
            int oc = task & 15, col = (task >> 4) & 31, v = 0;
            // task covers 512 of 96x16=1536 slots; map: col index 0..95
            int cidx = (task >> 4);          // 0..31 for rep0? need 96 cols x16 oc = 1536 tasks / 256 = 6 reps
            (void)col; (void)v; (void)cidx;
        }
        // 96 cols x 16 oc = 1536 tasks -> 6 reps
        #pragma unroll
        for (int rep = 0; rep < 6; ++rep) {
            int task = tid + 256*rep;
            int oc = task & 15, cidx = task >> 4;      // cidx 0..95
            const float* dp = sdT + cidx*132 + oc*8;
            u32 hw[4];
            #pragma unroll
            for (int e2 = 0; e2 < 4; ++e2)
                hw[e2] = (u32)f2h(dp[2*e2]) | ((u32)f2h(dp[2*e2+1]) << 16);
            *reinterpret_cast<uint4v*>(smem + T_OFF + cidx*272 + oc*16) =
                (uint4v){hw[0],hw[1],hw[2],hw[3]};
        }
        __syncthreads();
    }

    // ---------------- phase B: dir1 (128 x 128), B from T_lds ----------------
    f32x4 accD[4][3];
    #pragma unroll
    for (int io = 0; io < 4; ++io)
        #pragma unroll
        for (int jc = 0; jc < 3; ++jc)
            accD[io][jc] = (f32x4){0.f,0.f,0.f,0.f};
    {
        auto ldW = [&](int st, int u) -> const u16* {
            int row = u >> 3, q = u & 7;
            return Wd + (size_t)row*128 + st*64 + q*8;
        };
        #pragma unroll
        for (int j = 0; j < 4; ++j) pf[j] = *reinterpret_cast<const uint4v*>(ldW(0, tid + 256*j));
        #pragma unroll
        for (int j = 0; j < 4; ++j) { int u = tid + 256*j; int row = u >> 3, q = u & 7;
            *reinterpret_cast<uint4v*>(smem + SW + row*144 + q*16) = pf[j]; }

        for (int st = 0; st < 2; ++st) {
            __syncthreads();
            if (st + 1 < 2) {
                #pragma unroll
                for (int j = 0; j < 4; ++j)
                    pf[j] = *reinterpret_cast<const uint4v*>(ldW(st+1, tid + 256*j));
            }
            #pragma unroll
            for (int ks = 0; ks < 2; ++ks) {
                half8 fA[4], fB[3];
                #pragma unroll
                for (int io = 0; io < 4; ++io)
                    fA[io] = *reinterpret_cast<const half8*>(smem + SW + (wr*64 + io*16 + l15)*144 + ks*64 + l4*16);
                #pragma unroll
                for (int i = 0; i < 3; ++i)
                    fB[i] = *reinterpret_cast<const half8*>(smem + T_OFF + (wc*48 + i*16 + l15)*272 + st*128 + ks*64 + l4*16);
                #pragma unroll
                for (int io = 0; io < 4; ++io)
                    #pragma unroll
                    for (int jc = 0; jc < 3; ++jc)
                        accD[io][jc] = MFMAH(fA[io], fB[jc], accD[io][jc]);
            }
            __syncthreads();
            if (st + 1 < 2) {
                #pragma unroll
                for (int j = 0; j < 4; ++j) { int u = tid + 256*j; int row = u >> 3, q = u & 7;
                    *reinterpret_cast<uint4v*>(smem + SW + row*144 + q*16) = pf[j]; }
            }
        }
    }

    // ---- VN-leaky: two col-half passes via sdh @SW (48x132 f32); x from T_lds
    {
        float* sdh = (float*)(smem + SW);
        #pragma unroll
        for (int h = 0; h < 2; ++h) {
            if (wc == h) {
                #pragma unroll
                for (int io = 0; io < 4; ++io)
                    #pragma unroll
                    for (int jc = 0; jc < 3; ++jc) {
                        int jl = jc*16 + l15;
                        int orow = wr*64 + io*16 + l4*4;
                        *reinterpret_cast<f32x4*>(sdh + jl*132 + orow) = accD[io][jc];
                    }
            }
            __syncthreads();
            #pragma unroll
            for (int rep = 0; rep < 3; ++rep) {
                int task = tid + 256*rep;
                int oc = task & 15, cl = task >> 4;        // cl 0..47
                int col = h*48 + cl;
                const float* dp = sdh + cl*132 + oc*8;
                float d[8], x[8];
                #pragma unroll
                for (int e = 0; e < 8; ++e) d[e] = dp[e];
                uint4v hx = *reinterpret_cast<const uint4v*>(smem + T_OFF + col*272 + oc*16);
                #pragma unroll
                for (int w = 0; w < 4; ++w) {
                    x[2*w]   = h2f((u16)(hx[w] & 0xffffu));
                    x[2*w+1] = h2f((u16)(hx[w] >> 16));
                }
                // need all 3 vec comps per (o,col)?? No: VN-leaky couples the 3
                // vec comps of the SAME channel at the SAME n. col = v*32+nl, so
                // tasks at cols {nl, 32+nl, 64+nl} form one vector. Handle by
                // processing only v=0 cols here and loading the other comps.
                (void)d; (void)x; (void)col;
            }
            __syncthreads();
        }
        // The structure above cannot couple vector components across cols in
        // different halves; do the leaky with a single full-width pass instead.
        // sdh is written per-half above only to stage accD; redo properly:
    }
    // ---- proper leaky: full sd must hold all 96 cols. Use two passes over
    // v-groups is invalid (v=2 col 64..95 in half 1, v=0 col in half 0).
    // Fall back: write BOTH halves of accD into U region as raw f32? Instead,
    // simplest correct: reuse sdT layout — write accD to sdT @U_OFF (U not yet
    // written; safe), then leaky exactly as round-19 fused_back, writing U.
    {
        float* sdT = (float*)(smem + U_OFF);
        __syncthreads();
        #pragma unroll
        for (int io = 0; io < 4; ++io)
            #pragma unroll
            for (int jc = 0; jc < 3; ++jc) {
                int jj = wc*48 + jc*16 + l15;
                int orow = wr*64 + io*16 + l4*4;
                *reinterpret_cast<f32x4*>(sdT + jj*132 + orow) = accD[io][jc];
            }
        __syncthreads();
        // tasks: 96 cols x 16 oc = 1536 -> 6 reps. Each task handles one
        // (col, oc) -> needs the 3 vec comps of channels oc*8..+8 at n=nl.
        // col = v*32+nl couples cols {nl, 32+nl, 64+nl}: process tasks only
        // for v=0 (512 tasks, 2 reps), reading d for all 3 vec comps.
        #pragma unroll
        for (int rep = 0; rep < 2; ++rep) {
            int task = tid + 256*rep;
            int oc = task & 15, nl = task >> 4;            // nl 0..31
            float d[3][8], x[3][8];
            #pragma unroll
            for (int v = 0; v < 3; ++v) {
                const float* dp = sdT + (v*32 + nl)*132 + oc*8;
                #pragma unroll
                for (int e = 0; e < 8; ++e) d[v][e] = dp[e];
                uint4v hx = *reinterpret_cast<const uint4v*>(smem + T_OFF + (v*32 + nl)*272 + oc*16);
                #pragma unroll
                for (int w = 0; w < 4; ++w) {
                    x[v][2*w]   = h2f((u16)(hx[w] & 0xffffu));
                    x[v][2*w+1] = h2f((u16)(hx[w] >> 16));
                }
            }
            #pragma unroll
            for (int e = 0; e < 8; ++e) {
                float d0 = d[0][e], d1 = d[1][e], d2 = d[2][e];
                float dot = x[0][e]*d0 + x[1][e]*d1 + x[2][e]*d2;
                float dsq = d0*d0 + d1*d1 + d2*d2;
                float t = dot / (dsq + EPSV);
                if (dot < 0.f) { x[0][e] -= t*d0; x[1][e] -= t*d1; x[2][e] -= t*d2; }
            }
            // write U — but sdT occupies U region! Stash to registers via LDS
            // conflict: instead write U into the T region (T dead after this
            // read? T still needed by other tasks' x-reads this pass... but
            // each (nl,oc) slot of T is read exactly by its own task before
            // its own write; write U into T's slot (same col,oc) — safe since
            // 1:1 and after the read.
            #pragma unroll
            for (int v = 0; v < 3; ++v) {
                u32 hw[4];
                #pragma unroll
                for (int e2 = 0; e2 < 4; ++e2)
                    hw[e2] = (u32)f2h(x[v][2*e2]) | ((u32)f2h(x[v][2*e2+1]) << 16);
                *reinterpret_cast<uint4v*>(smem + T_OFF + (v*32 + nl)*272 + oc*16) =
                    (uint4v){hw[0],hw[1],hw[2],hw[3]};
            }
        }
        __syncthreads();
    }
    // U now lives in the T region (@0, 272-stride).

    // ---------------- phase C: fc1 (K=128 from U@0) + sc (K=CSC staged) ----
    f32x4 acc2[4][3];
    #pragma unroll
    for (int io = 0; io < 4; ++io)
        #pragma unroll
        for (int jc = 0; jc < 3; ++jc) {
            int v = (wc*48 + jc*16) >> 5;
            #pragma unroll
            for (int r = 0; r < 4; ++r) {
                int o_l = wr*64 + io*16 + l4*4 + r;
                acc2[io][jc][r] = VIRT ? biasS_s[o_l*3 + v] : 0.f;
            }
        }

    constexpr int NS2 = 2 + CSC/64;
    auto ld2 = [&](int st, int u) -> const u16* {
        if (st < 2) {
            int row = u >> 3, q = u & 7;
            return Wf1 + (size_t)row*128 + st*64 + q*8;
        }
        int cc = (st - 2)*64;
        if (u < 1024) { int row = u >> 3, q = u & 7; return Wsc + (size_t)row*256 + cc + q*8; }
        int uu = u - 1024;
        int row = uu >> 3, q = uu & 7;
        int m = b*6144 + (row >> 5)*2048 + n0 + (row & 31);
        return Xs + (size_t)m*CSC + cc + q*8;
    };
    auto st2 = [&](int u) -> char* {
        if (u < 1024) { int row = u >> 3, q = u & 7; return smem + SW + row*144 + q*16; }
        int uu = u - 1024;
        int row = uu >> 3, q = uu & 7;
        return smem + U_OFF + row*144 + q*16;   // X stage @U_OFF (sdT dead)
    };

    #pragma unroll
    for (int j = 0; j < 7; ++j) { int u = tid + 256*j; if (u < 1024) pf[j] = *reinterpret_cast<const uint4v*>(ld2(0, u)); }
    #pragma unroll
    for (int j = 0; j < 7; ++j) { int u = tid + 256*j; if (u < 1024) *reinterpret_cast<uint4v*>(st2(u)) = pf[j]; }

    for (int st = 0; st < NS2; ++st) {
        __syncthreads();
        int nv = (st + 1 < 2) ? 1024 : 1792;
        if (st + 1 < NS2) {
            #pragma unroll
            for (int j = 0; j < 7; ++j) { int u = tid + 256*j; if (u < nv) pf[j] = *reinterpret_cast<const uint4v*>(ld2(st+1, u)); }
        }
        #pragma unroll
        for (int ks = 0; ks < 2; ++ks) {
            half8 fA[4], fB[3];
            #pragma unroll
            for (int io = 0; io < 4; ++io)
                fA[io] = *reinterpret_cast<const half8*>(smem + SW + (wr*64 + io*16 + l15)*144 + ks*64 + l4*16);
            if (st < 2) {
                #pragma unroll
                for (int i = 0; i < 3; ++i)
                    fB[i] = *reinterpret_cast<const half8*>(smem + T_OFF + (wc*48 + i*16 + l15)*272 + st*128 + ks*64 + l4*16);
            } else {
                #pragma unroll
                for (int i = 0; i < 3; ++i)
                    fB[i] = *reinterpret_cast<const half8*>(smem + U_OFF + (wc*48 + i*16 + l15)*144 + ks*64 + l4*16);
            }
            #pragma unroll
            for (int io = 0; io < 4; ++io)
                #pragma unroll
                for (int jc = 0; jc < 3; ++jc)
                    acc2[io][jc] = MFMAH(fA[io], fB[jc], acc2[io][jc]);
        }
        __syncthreads();
        if (st + 1 < NS2) {
            #pragma unroll
            for (int j = 0; j < 7; ++j) { int u = tid + 256*j; if (u < nv) *reinterpret_cast<uint4v*>(st2(u)) = pf[j]; }
        }
    }

    // ---- epilogue: Y write + pool (sd @0; U/T/stages dead)
    float* sdE = (float*)smem;
    #pragma unroll
    for (int io = 0; io < 4; ++io)
        #pragma unroll
        for (int jc = 0; jc < 3; ++jc) {
            int jj = wc*48 + jc*16 + l15;
            int orow = wr*64 + io*16 + l4*4;
            *reinterpret_cast<f32x4*>(sdE + jj*132 + orow) = acc2[io][jc];
        }
    __syncthreads();
    #pragma unroll
    for (int rep = 0; rep < 2; ++rep) {
        int task = tid + 256*rep;
        int oc = task & 15, nl = (task >> 4) & 31;
        #pragma unroll
        for (int v = 0; v < 3; ++v) {
            const float* dp = sdE + (v*32 + nl)*132 + oc*8;
            u32 hw[4];
            #pragma unroll
            for (int e2 = 0; e2 < 4; ++e2)
                hw[e2] = (u32)f2h(dp[2*e2]) | ((u32)f2h(dp[2*e2+1]) << 16);
            *reinterpret_cast<uint4v*>(Y + (size_t)(b*6144 + v*2048 + n0 + nl)*128 + oc*8) =
                (uint4v){hw[0],hw[1],hw[2],hw[3]};
        }
    }
    for (int t = tid; t < 384; t += 256) {
        int v = t >> 7, o_l = t & 127;
        float sum = 0.f;
        #pragma unroll 8
        for (int nl = 0; nl < 32; ++nl) sum += sdE[(v*32 + nl)*132 + o_l];
        atomicAdd(&PmOut[(size_t)(b*128 + o_l)*3 + v], sum * (1.f/(float)NPT));
    }
}

// ------------------------------------------------- weight fp16 convert
#define WO_FCPOS 0
#define WO_DIR0  32768
#define WO_FC0   360448
#define WO_DIR1  524288
#define WO_FC1   606208
#define WO_SC    688128
#define WTOT     851968
__global__ __launch_bounds__(256)
void convert_w_kernel(const float* __restrict__ s0, const float* __restrict__ s1,
                      const float* __restrict__ s2, const float* __restrict__ s3,
                      const float* __restrict__ s4, const float* __restrict__ s5,
                      u16* __restrict__ Wf) {
    int t = blockIdx.x*256 + threadIdx.x;
    if (t >= WTOT) return;
    const float* src; int base;
    if      (t < WO_DIR0) { src = s0; base = WO_FCPOS; }
    else if (t < WO_FC0)  { src = s1; base = WO_DIR0; }
    else if (t < WO_DIR1) { src = s2; base = WO_FC0; }
    else if (t < WO_FC1)  { src = s3; base = WO_DIR1; }
    else if (t < WO_SC)   { src = s4; base = WO_FC1; }
    else                  { src = s5; base = WO_SC; }
    Wf[t] = f2h(src[t - base]);
}

// ----------------------------------------------------- head: leaky(0.2)+fc_c
__global__ __launch_bounds__(128)
void final_head_kernel(const float* __restrict__ q, const float* __restrict__ Wdir,
                       const float* __restrict__ Wfc, float* __restrict__ out) {
    int b = blockIdx.x; int o = threadIdx.x;
    __shared__ float qs[128][3];
    __shared__ float zs[128][3];
    qs[o][0] = q[((size_t)b*128 + o)*3 + 0];
    qs[o][1] = q[((size_t)b*128 + o)*3 + 1];
    qs[o][2] = q[((size_t)b*128 + o)*3 + 2];
    __syncthreads();
    float d0 = 0.f, d1 = 0.f, d2 = 0.f;
    for (int c = 0; c < 128; ++c) {
        float w = Wdir[o*128 + c];
        d0 += w*qs[c][0]; d1 += w*qs[c][1]; d2 += w*qs[c][2];
    }
    float x0 = qs[o][0], x1 = qs[o][1], x2 = qs[o][2];
    float dot = d0*x0 + d1*x1 + d2*x2;
    float dsq = d0*d0 + d1*d1 + d2*d2;
    float t = dot / (dsq + EPSV);
    bool pos = dot >= 0.f;
    float g0 = pos ? x0 : (x0 - t*d0);
    float g1 = pos ? x1 : (x1 - t*d1);
    float g2 = pos ? x2 : (x2 - t*d2);
    zs[o][0] = 0.2f*x0 + 0.8f*g0;
    zs[o][1] = 0.2f*x1 + 0.8f*g1;
    zs[o][2] = 0.2f*x2 + 0.8f*g2;
    __syncthreads();
    float c0 = 0.f, c1 = 0.f, c2 = 0.f;
    for (int c = 0; c < 128; ++c) {
        float w = Wfc[o*128 + c];
        c0 += w*zs[c][0]; c1 += w*zs[c][1]; c2 += w*zs[c][2];
    }
    out[((size_t)b*128 + o)*3 + 0] = c0;
    out[((size_t)b*128 + o)*3 + 1] = c1;
    out[((size_t)b*128 + o)*3 + 2] = c2;
}

extern "C" void kernel_launch(void* const* d_in, const int* in_sizes, int n_in,
                              void* d_out, int out_size, void* d_ws, size_t ws_size,
                              hipStream_t stream) {
    const float* p           = (const float*)d_in[0];
    const float* w_conv_feat = (const float*)d_in[1];
    const float* w_conv_dir  = (const float*)d_in[2];
    const float* w_fc_pos    = (const float*)d_in[3];
    const float* blk_dir0    = (const float*)d_in[4];
    const float* blk_fc0     = (const float*)d_in[5];
    const float* blk_dir1    = (const float*)d_in[6];
    const float* blk_fc1     = (const float*)d_in[7];
    const float* blk_sc      = (const float*)d_in[8];
    const float* w_actc_dir  = (const float*)d_in[9];
    const float* w_fc_c      = (const float*)d_in[10];
    float* out = (float*)d_out;

    char* wsb = (char*)d_ws;
    size_t cur = 0;
    auto carve = [&](size_t nbytes) -> char* {
        char* r = wsb + cur;
        cur += (nbytes + 255) & ~(size_t)255;
        return r;
    };
    const size_t MTOT = (size_t)BB*3*NPT;      // 24576 columns
    float* Pm0   = (float*)carve(1536*4);
    float* Pm1   = (float*)carve(1536*4);
    u16* Wf    = (u16*)carve((size_t)WTOT*2);
    u16* net1  = (u16*)carve(MTOT*128*2);      // fc_pos input
    u16* X0    = (u16*)carve(MTOT*256*2);      // fc_pos out; later Y ping
    u16* Ab    = (u16*)carve(MTOT*256*2);      // A (dir0 out)
    u16* Yb    = (u16*)carve(MTOT*128*2);      // Y pong
    float* PmBuf[2] = { Pm0, Pm1 };

    convert_w_kernel<<<(WTOT+255)/256, 256, 0, stream>>>(
        w_fc_pos, blk_dir0, blk_fc0, blk_dir1, blk_fc1, blk_sc, Wf);
    knn_edge_kernel<<<BB*NPT, 256, 0, stream>>>(p, w_conv_feat, w_conv_dir, net1);

    // fc_pos: [256 x 128] x net1 -> X0
    gemm_plain<256,128,0,false,false><<<dim3(384,2), 256, 0, stream>>>(
        Wf+WO_FCPOS, 128, net1, 128,
        nullptr, 0, nullptr, 0,
        nullptr, nullptr, X0, 256, nullptr);

    const u16* Yp = nullptr;
    for (int i = 0; i < 5; ++i) {
        size_t od0 = WO_DIR0 + (size_t)i*65536;
        size_t of0 = WO_FC0  + (size_t)i*32768;
        size_t od1 = WO_DIR1 + (size_t)i*16384;
        size_t of1 = WO_FC1  + (size_t)i*16384;
        size_t osc = WO_SC   + (size_t)i*32768;
        float* PmPrev = PmBuf[(i+1) & 1];
        float* PmCur  = PmBuf[i & 1];

        // dir0 also zeroes all 1536 floats of PmCur (block 0) — replaces memset.
        if (i == 0) {
            gemm_dir<256,256,false><<<dim3(BB*64,2), 256, 0, stream>>>(
                Wf+od0, 256, X0, 256, nullptr, nullptr, Ab, 256, PmCur);
        } else {
            gemm_dir<256,128,true><<<dim3(BB*64,2), 256, 0, stream>>>(
                Wf+od0, 256, Yp, 128,
                blk_dir0 + (size_t)i*65536, PmPrev, Ab, 256, PmCur);
        }

        u16* outv = (i % 2 == 0) ? Yb : X0;
        if (i == 0) {
            fused_back<256,false><<<BB*64, 256, 0, stream>>>(
                Wf+of0, Wf+od1, Wf+of1, Wf+osc, nullptr,
                Ab, X0, nullptr, outv, PmCur);
        } else {
            fused_back<128,true><<<BB*64, 256, 0, stream>>>(
                Wf+of0, Wf+od1, Wf+of1, Wf+osc, blk_sc + (size_t)i*32768,
                Ab, Yp, PmPrev, outv, PmCur);
        }
        Yp = outv;
    }

    final_head_kernel<<<BB, 128, 0, stream>>>(PmBuf[0], w_actc_dir, w_fc_c, out);
}

// Round 21
// 288.355 us; speedup vs baseline: 1.2363x; 1.0102x over previous
//
#include <hip/hip_runtime.h>
#include <math.h>

#define NPT 2048
#define BB 4
#define KNN 20
#define EPSV 1e-6f

typedef unsigned short u16;
typedef unsigned int u32;
typedef _Float16 half8 __attribute__((ext_vector_type(8)));
typedef __attribute__((ext_vector_type(4))) float f32x4;
typedef __attribute__((ext_vector_type(4))) u32 uint4v;

#define MFMAH(a,b,c) __builtin_amdgcn_mfma_f32_16x16x32_f16((a),(b),(c),0,0,0)

__device__ __forceinline__ u16 f2h(float f) {
    _Float16 h = (_Float16)f;
    return __builtin_bit_cast(u16, h);
}
__device__ __forceinline__ float h2f(u16 b) {
    return (float)__builtin_bit_cast(_Float16, b);
}

// -------------------- kNN top-20 (radix-select) + fused edge conv + mean_k
// (round-20 version, verbatim — passed at 77us)
__global__ __launch_bounds__(256)
void knn_edge_kernel(const float* __restrict__ p,
                     const float* __restrict__ wf, const float* __restrict__ wd,
                     u16* __restrict__ net1) {
    int bn = blockIdx.x;
    int b = bn >> 11, n = bn & (NPT - 1);
    const float* pb = p + (size_t)b * NPT * 3;
    float qx = pb[n*3+0], qy = pb[n*3+1], qz = pb[n*3+2];
    float qq = qx*qx + qy*qy + qz*qz;
    __shared__ u32 keys[NPT];
    __shared__ int hist[4][256];
    __shared__ int wtot[4];
    __shared__ int sh_byte, sh_ngt, sure_cnt, tie_cnt;
    __shared__ int tie_m[64];
    __shared__ int sel[KNN];
    __shared__ float nb[KNN][3];
    int tid = threadIdx.x;
    int lane = tid & 63, wv = tid >> 6;
    for (int m = tid; m < NPT; m += 256) {
        float px = pb[m*3+0], py = pb[m*3+1], pz = pb[m*3+2];
        float sc = 2.f*(qx*px + qy*py + qz*pz) - qq - (px*px + py*py + pz*pz);
        u32 u = __builtin_bit_cast(u32, sc);
        keys[m] = u ^ (u32)(((int)u >> 31) | (int)0x80000000);
    }
    if (tid == 0) { sure_cnt = 0; tie_cnt = 0; }
    __syncthreads();
    u32 prefix = 0; int need = KNN;
    for (int pass = 3; pass >= 0; --pass) {
        int shift = pass * 8;
        u32 maskhi = (pass == 3) ? 0u : (0xFFFFFFFFu << (shift + 8));
        hist[0][tid] = 0; hist[1][tid] = 0; hist[2][tid] = 0; hist[3][tid] = 0;
        __syncthreads();
        int prevbin = -1, cnt = 0;
        #pragma unroll
        for (int j = 0; j < 8; ++j) {
            u32 key = keys[tid + 256*j];
            int bin = ((key & maskhi) == (prefix & maskhi)) ? (int)((key >> shift) & 255) : -1;
            if (bin == prevbin) { ++cnt; }
            else {
                if (prevbin >= 0) atomicAdd(&hist[wv][prevbin], cnt);
                prevbin = bin; cnt = 1;
            }
        }
        if (prevbin >= 0) atomicAdd(&hist[wv][prevbin], cnt);
        __syncthreads();
        int own = hist[0][tid] + hist[1][tid] + hist[2][tid] + hist[3][tid];
        int sum = own;
        #pragma unroll
        for (int off = 1; off < 64; off <<= 1) {
            int v = __shfl_down(sum, off, 64);
            if (lane + off < 64) sum += v;
        }
        if (lane == 0) wtot[wv] = sum;
        __syncthreads();
        int addhi = 0;
        #pragma unroll
        for (int w2 = 0; w2 < 4; ++w2) if (w2 > wv) addhi += wtot[w2];
        int cnt_ge = sum + addhi;
        int cnt_gt = cnt_ge - own;
        if (cnt_ge >= need && cnt_gt < need) { sh_byte = tid; sh_ngt = cnt_gt; }
        __syncthreads();
        prefix |= ((u32)sh_byte) << shift;
        need -= sh_ngt;
        __syncthreads();
    }
    u32 T = prefix;
    #pragma unroll
    for (int j = 0; j < 8; ++j) {
        int m = tid + 256*j;
        u32 key = keys[m];
        if (key > T) {
            int slot = atomicAdd(&sure_cnt, 1);
            sel[slot] = m;
        } else if (key == T) {
            int t = atomicAdd(&tie_cnt, 1);
            if (t < 64) tie_m[t] = m;
        }
    }
    __syncthreads();
    if (tid == 0) {
        int base = sure_cnt;
        int r = KNN - base;
        int tc = tie_cnt;
        if (tc == r) {
            for (int t2 = 0; t2 < r; ++t2) sel[base + t2] = tie_m[t2];
        } else if (tc <= 64) {
            for (int t2 = 0; t2 < r; ++t2) {
                int best = 1 << 30, bj = 0;
                for (int t3 = 0; t3 < tc; ++t3)
                    if (tie_m[t3] < best) { best = tie_m[t3]; bj = t3; }
                tie_m[bj] = 1 << 30;
                sel[base + t2] = best;
            }
        } else {
            int got = 0;
            for (int m = 0; m < NPT && got < r; ++m)
                if (keys[m] == T) { sel[base + got] = m; ++got; }
        }
    }
    __syncthreads();
    if (tid < KNN) {
        int j = sel[tid];
        nb[tid][0] = pb[j*3+0]; nb[tid][1] = pb[j*3+1]; nb[tid][2] = pb[j*3+2];
    }
    __syncthreads();
    {
        float* part = (float*)keys;
        int o = tid & 127, kh = tid >> 7;
        float wfa = wf[o*3+0], wfb = wf[o*3+1], wfc = wf[o*3+2];
        float wda = wd[o*3+0], wdb = wd[o*3+1], wdc = wd[o*3+2];
        float cx = qx, cy = qy, cz = qz;
        float a0 = 0.f, a1 = 0.f, a2 = 0.f;
        int k0 = kh * 10;
        #pragma unroll
        for (int k = 0; k < 10; ++k) {
            float nx = nb[k0+k][0], ny = nb[k0+k][1], nz = nb[k0+k][2];
            float rx = nx-cx, ry = ny-cy, rz = nz-cz;
            float sx = ny*cz - nz*cy;
            float sy = nz*cx - nx*cz;
            float sz = nx*cy - ny*cx;
            float fx = wfa*rx + wfb*cx + wfc*sx;
            float fy = wfa*ry + wfb*cy + wfc*sy;
            float fz = wfa*rz + wfb*cz + wfc*sz;
            float dx0 = wda*rx + wdb*cx + wdc*sx;
            float dy0 = wda*ry + wdb*cy + wdc*sy;
            float dz0 = wda*rz + wdb*cz + wdc*sz;
            float dot = fx*dx0 + fy*dy0 + fz*dz0;
            float dsq = dx0*dx0 + dy0*dy0 + dz0*dz0;
            float t = dot / (dsq + EPSV);
            bool pos = dot >= 0.f;
            float gx = pos ? fx : (fx - t*dx0);
            float gy = pos ? fy : (fy - t*dy0);
            float gz = pos ? fz : (fz - t*dz0);
            a0 += 0.2f*fx + 0.8f*gx;
            a1 += 0.2f*fy + 0.8f*gy;
            a2 += 0.2f*fz + 0.8f*gz;
        }
        if (kh == 1) { part[o*3+0] = a0; part[o*3+1] = a1; part[o*3+2] = a2; }
        __syncthreads();
        if (kh == 0) {
            a0 += part[o*3+0]; a1 += part[o*3+1]; a2 += part[o*3+2];
            const float s = 1.f / (float)KNN;
            net1[(size_t)(b*6144 +          n)*128 + o] = f2h(a0*s);
            net1[(size_t)(b*6144 + 2048  + n)*128 + o] = f2h(a1*s);
            net1[(size_t)(b*6144 + 4096  + n)*128 + o] = f2h(a2*s);
        }
    }
}

// ------------------------------------------------------ MFMA fp16 GEMM
// (round-20 version, verbatim — fc_pos only) Tile 128o x 64m.
template<int O, int C1, int C2, bool POOL, bool BIASED>
__global__ __launch_bounds__(256) void gemm_plain(
    const u16* __restrict__ W1, int ldw1,
    const u16* __restrict__ X1, int sx1,
    const u16* __restrict__ W2, int ldw2,
    const u16* __restrict__ X2, int sx2,
    const float* __restrict__ WscF, const float* __restrict__ PmPrev,
    u16* __restrict__ Y, int sy,
    float* __restrict__ PmOut)
{
    __shared__ __align__(16) char smem[64*132*4];
    __shared__ float pms[128];
    __shared__ float biasS_s[128];
    const int m0 = blockIdx.x * 64;
    const int ob = blockIdx.y * 128;
    const int b   = m0 / 6144;
    const int vec = (m0 % 6144) / 2048;
    const int tid = threadIdx.x;
    const int lane = tid & 63;
    const int wid = __builtin_amdgcn_readfirstlane(tid >> 6);
    const int wr = wid & 1, wc = wid >> 1;
    const int l15 = lane & 15, l4 = lane >> 4;

    if (BIASED) {
        if (tid < 128) pms[tid] = PmPrev[(size_t)(b*128 + tid)*3 + vec];
        __syncthreads();
        if (tid < 128) {
            const float* wrow = WscF + (size_t)tid*256 + 128;
            float s = 0.f;
            #pragma unroll 4
            for (int c = 0; c < 128; ++c) s += wrow[c]*pms[c];
            biasS_s[tid] = s;
        }
        __syncthreads();
    }

    f32x4 acc[4][2];
    #pragma unroll
    for (int io = 0; io < 4; ++io) {
        float bv[4];
        #pragma unroll
        for (int r = 0; r < 4; ++r)
            bv[r] = BIASED ? biasS_s[wr*64 + io*16 + l4*4 + r] : 0.f;
        #pragma unroll
        for (int jc = 0; jc < 2; ++jc)
            #pragma unroll
            for (int r = 0; r < 4; ++r) acc[io][jc][r] = bv[r];
    }

    constexpr int NS = (C1 + C2) / 64;
    auto ldaddr = [&](int st, int u) -> const u16* {
        const bool ph2 = (st >= C1/64);
        const u16* w = ph2 ? W2 : W1; const u16* x = ph2 ? X2 : X1;
        int ldw = ph2 ? ldw2 : ldw1; int sx = ph2 ? sx2 : sx1;
        int cc = (ph2 ? (st - C1/64) : st) * 64;
        if (u < 1024) {
            int row = u >> 3, q = u & 7;
            return w + (size_t)(ob + row)*ldw + cc + q*8;
        }
        int uu = u - 1024;
        int row = uu >> 3, q = uu & 7;
        return x + (size_t)(m0 + row)*sx + cc + q*8;
    };
    auto lds_dst = [&](int u) -> char* {
        if (u < 1024) { int row = u >> 3, q = u & 7; return smem + row*144 + q*16; }
        int uu = u - 1024;
        int row = uu >> 3, q = uu & 7;
        return smem + 18432 + row*144 + q*16;
    };

    uint4v pf[6];
    #pragma unroll
    for (int j = 0; j < 6; ++j) pf[j] = *reinterpret_cast<const uint4v*>(ldaddr(0, tid + 256*j));
    #pragma unroll
    for (int j = 0; j < 6; ++j) *reinterpret_cast<uint4v*>(lds_dst(tid + 256*j)) = pf[j];

    for (int st = 0; st < NS; ++st) {
        __syncthreads();
        if (st + 1 < NS) {
            #pragma unroll
            for (int j = 0; j < 6; ++j)
                pf[j] = *reinterpret_cast<const uint4v*>(ldaddr(st+1, tid + 256*j));
        }
        #pragma unroll
        for (int ks = 0; ks < 2; ++ks) {
            half8 fA[4], fB[2];
            #pragma unroll
            for (int io = 0; io < 4; ++io)
                fA[io] = *reinterpret_cast<const half8*>(smem + (wr*64 + io*16 + l15)*144 + ks*64 + l4*16);
            #pragma unroll
            for (int i = 0; i < 2; ++i)
                fB[i] = *reinterpret_cast<const half8*>(smem + 18432 + (wc*32 + i*16 + l15)*144 + ks*64 + l4*16);
            #pragma unroll
            for (int io = 0; io < 4; ++io)
                #pragma unroll
                for (int jc = 0; jc < 2; ++jc)
                    acc[io][jc] = MFMAH(fA[io], fB[jc], acc[io][jc]);
        }
        __syncthreads();
        if (st + 1 < NS) {
            #pragma unroll
            for (int j = 0; j < 6; ++j)
                *reinterpret_cast<uint4v*>(lds_dst(tid + 256*j)) = pf[j];
        }
    }

    float* sd = (float*)smem;
    #pragma unroll
    for (int io = 0; io < 4; ++io)
        #pragma unroll
        for (int jc = 0; jc < 2; ++jc) {
            int jj = wc*32 + jc*16 + l15;
            int orow = wr*64 + io*16 + l4*4;
            *reinterpret_cast<f32x4*>(sd + jj*132 + orow) = acc[io][jc];
        }
    __syncthreads();

    #pragma unroll
    for (int rep = 0; rep < 4; ++rep) {
        int task = tid + 256*rep;
        int oc = task & 15, ml = task >> 4;
        const float* dp = sd + ml*132 + oc*8;
        u32 hw[4];
        #pragma unroll
        for (int e2 = 0; e2 < 4; ++e2)
            hw[e2] = (u32)f2h(dp[2*e2]) | ((u32)f2h(dp[2*e2+1]) << 16);
        *reinterpret_cast<uint4v*>(Y + (size_t)(m0 + ml)*sy + ob + oc*8) =
            (uint4v){hw[0],hw[1],hw[2],hw[3]};
    }

    if (POOL) {
        int o_l = tid & 127, half = tid >> 7;
        float sum = 0.f;
        #pragma unroll 8
        for (int c = 0; c < 32; ++c) sum += sd[(half*32 + c)*132 + o_l];
        atomicAdd(&PmOut[(size_t)(b*128 + o_l)*3 + vec], sum * (1.f/(float)NPT));
    }
}

// ------------------- MFMA fp16 dir GEMM + fused VN-leaky(0) epilogue
// (round-20 version, verbatim — dir0 only)
template<int O, int CIN, bool VIRT>
__global__ __launch_bounds__(256) void gemm_dir(
    const u16* __restrict__ W_, int ldw,
    const u16* __restrict__ X1, int sx,
    const float* __restrict__ WdF, const float* __restrict__ Pm,
    u16* __restrict__ Ov, int so,
    float* __restrict__ PmZero)
{
    __shared__ __align__(16) char smem[96*132*4];
    __shared__ float pmd[384];
    __shared__ float biasD_s[384];
    const int gx = blockIdx.x;
    const int b  = gx >> 6;
    const int n0 = (gx & 63) * 32;
    const int ob = blockIdx.y * 128;
    const int tid = threadIdx.x;
    const int lane = tid & 63;
    const int wid = __builtin_amdgcn_readfirstlane(tid >> 6);
    const int wr = wid & 1, wc = wid >> 1;
    const int l15 = lane & 15, l4 = lane >> 4;

    if (PmZero != nullptr && gx == 0 && blockIdx.y == 0)
        for (int t = tid; t < 1536; t += 256) PmZero[t] = 0.f;

    if (VIRT) {
        for (int t = tid; t < 384; t += 256) pmd[t] = Pm[(size_t)b*384 + t];
        __syncthreads();
        for (int t = tid; t < 384; t += 256) {
            int o_l = t / 3, v = t - o_l*3;
            const float* wrow = WdF + (size_t)(ob + o_l)*256 + 128;
            float s = 0.f;
            #pragma unroll 4
            for (int c = 0; c < 128; ++c) s += wrow[c]*pmd[c*3 + v];
            biasD_s[t] = s;
        }
        __syncthreads();
    }

    f32x4 acc[4][3];
    #pragma unroll
    for (int io = 0; io < 4; ++io)
        #pragma unroll
        for (int jc = 0; jc < 3; ++jc) {
            int v = (wc*48 + jc*16) >> 5;
            #pragma unroll
            for (int r = 0; r < 4; ++r) {
                int o_l = wr*64 + io*16 + l4*4 + r;
                acc[io][jc][r] = VIRT ? biasD_s[o_l*3 + v] : 0.f;
            }
        }

    constexpr int NS = CIN / 64;
    auto ldaddr = [&](int st, int u) -> const u16* {
        int cc = st*64;
        if (u < 1024) {
            int row = u >> 3, q = u & 7;
            return W_ + (size_t)(ob + row)*ldw + cc + q*8;
        }
        int uu = u - 1024;
        int row = uu >> 3, q = uu & 7;
        int m = b*6144 + (row >> 5)*2048 + n0 + (row & 31);
        return X1 + (size_t)m*sx + cc + q*8;
    };
    auto lds_dst = [&](int u) -> char* {
        if (u < 1024) { int row = u >> 3, q = u & 7; return smem + row*144 + q*16; }
        int uu = u - 1024;
        int row = uu >> 3, q = uu & 7;
        return smem + 18432 + row*144 + q*16;
    };

    uint4v pf[7];
    #pragma unroll
    for (int j = 0; j < 7; ++j) pf[j] = *reinterpret_cast<const uint4v*>(ldaddr(0, tid + 256*j));
    #pragma unroll
    for (int j = 0; j < 7; ++j) *reinterpret_cast<uint4v*>(lds_dst(tid + 256*j)) = pf[j];

    for (int st = 0; st < NS; ++st) {
        __syncthreads();
        if (st + 1 < NS) {
            #pragma unroll
            for (int j = 0; j < 7; ++j)
                pf[j] = *reinterpret_cast<const uint4v*>(ldaddr(st+1, tid + 256*j));
        }
        #pragma unroll
        for (int ks = 0; ks < 2; ++ks) {
            half8 fA[4], fB[3];
            #pragma unroll
            for (int io = 0; io < 4; ++io)
                fA[io] = *reinterpret_cast<const half8*>(smem + (wr*64 + io*16 + l15)*144 + ks*64 + l4*16);
            #pragma unroll
            for (int i = 0; i < 3; ++i)
                fB[i] = *reinterpret_cast<const half8*>(smem + 18432 + (wc*48 + i*16 + l15)*144 + ks*64 + l4*16);
            #pragma unroll
            for (int io = 0; io < 4; ++io)
                #pragma unroll
                for (int jc = 0; jc < 3; ++jc)
                    acc[io][jc] = MFMAH(fA[io], fB[jc], acc[io][jc]);
        }
        __syncthreads();
        if (st + 1 < NS) {
            #pragma unroll
            for (int j = 0; j < 7; ++j)
                *reinterpret_cast<uint4v*>(lds_dst(tid + 256*j)) = pf[j];
        }
    }

    float* sd = (float*)smem;
    #pragma unroll
    for (int io = 0; io < 4; ++io)
        #pragma unroll
        for (int jc = 0; jc < 3; ++jc) {
            int jj = wc*48 + jc*16 + l15;
            int orow = wr*64 + io*16 + l4*4;
            *reinterpret_cast<f32x4*>(sd + jj*132 + orow) = acc[io][jc];
        }
    __syncthreads();

    #pragma unroll
    for (int rep = 0; rep < 2; ++rep) {
        int task = tid + 256*rep;
        int oc = task & 15, nl = (task >> 4) & 31;
        float d[3][8], x[3][8];
        #pragma unroll
        for (int v = 0; v < 3; ++v) {
            const float* dp = sd + (v*32 + nl)*132 + oc*8;
            #pragma unroll
            for (int e = 0; e < 8; ++e) d[v][e] = dp[e];
        }
        if (VIRT && ob != 0) {
            #pragma unroll
            for (int e = 0; e < 8; ++e) {
                int c = oc*8 + e;
                #pragma unroll
                for (int v = 0; v < 3; ++v)
                    x[v][e] = Pm[(size_t)(b*128 + c)*3 + v];
            }
        } else {
            #pragma unroll
            for (int v = 0; v < 3; ++v) {
                size_t m = (size_t)(b*6144 + v*2048 + n0 + nl);
                uint4v hx = *reinterpret_cast<const uint4v*>(X1 + m*sx + ob + oc*8);
                #pragma unroll
                for (int w = 0; w < 4; ++w) {
                    x[v][2*w]   = h2f((u16)(hx[w] & 0xffffu));
                    x[v][2*w+1] = h2f((u16)(hx[w] >> 16));
                }
            }
        }
        #pragma unroll
        for (int e = 0; e < 8; ++e) {
            float d0 = d[0][e], d1 = d[1][e], d2 = d[2][e];
            float dot = x[0][e]*d0 + x[1][e]*d1 + x[2][e]*d2;
            float dsq = d0*d0 + d1*d1 + d2*d2;
            float t = dot / (dsq + EPSV);
            if (dot < 0.f) { x[0][e] -= t*d0; x[1][e] -= t*d1; x[2][e] -= t*d2; }
        }
        #pragma unroll
        for (int v = 0; v < 3; ++v) {
            u32 hw[4];
            #pragma unroll
            for (int e2 = 0; e2 < 4; ++e2)
                hw[e2] = (u32)f2h(x[v][2*e2]) | ((u32)f2h(x[v][2*e2+1]) << 16);
            *reinterpret_cast<uint4v*>(Ov + (size_t)(b*6144 + v*2048 + n0 + nl)*so + ob + oc*8) =
                (uint4v){hw[0],hw[1],hw[2],hw[3]};
        }
    }
}

// ---- fused back v2 (cleaned): fc0 + T_lds + dir1 + leaky (U in T region)
//      + fc1 + sc (+bias) + pool. Dead sdh block and bogus loops removed;
//      barrier/region ordering identical to the passing round-20 path.
template<int CSC, bool VIRT>
__global__ __launch_bounds__(256) void fused_back(
    const u16* __restrict__ Wf0,     // fc0, ldw 256
    const u16* __restrict__ Wd,      // dir1, ldw 128
    const u16* __restrict__ Wf1,     // fc1, ldw 128
    const u16* __restrict__ Wsc,     // sc, ldw 256
    const float* __restrict__ WsF,   // fp32 sc (bias), ldw 256
    const u16* __restrict__ A_,      // fc0 input (dir0 out), sx 256
    const u16* __restrict__ Xs,      // sc input, sx CSC
    const float* __restrict__ Pm,
    u16* __restrict__ Y,             // sy 128; nullptr => skip store (last iter)
    float* __restrict__ PmOut)
{
    __shared__ __align__(16) char smem[77568];
    __shared__ float pms[384];
    __shared__ float biasS_s[384];
    constexpr int T_OFF = 0;
    constexpr int U_OFF = 26112;
    constexpr int SW    = 52224;
    const int gx = blockIdx.x;
    const int b  = gx >> 6;
    const int n0 = (gx & 63) * 32;
    const int tid = threadIdx.x;
    const int lane = tid & 63;
    const int wid = __builtin_amdgcn_readfirstlane(tid >> 6);
    const int wr = wid & 1, wc = wid >> 1;
    const int l15 = lane & 15, l4 = lane >> 4;

    if (VIRT) {
        for (int t = tid; t < 384; t += 256) pms[t] = Pm[(size_t)b*384 + t];
        __syncthreads();
        for (int t = tid; t < 384; t += 256) {
            int o_l = t / 3, v = t - o_l*3;
            const float* wrow = WsF + (size_t)o_l*256 + 128;
            float s = 0.f;
            #pragma unroll 4
            for (int c = 0; c < 128; ++c) s += wrow[c]*pms[c*3 + v];
            biasS_s[t] = s;
        }
        __syncthreads();
    }

    uint4v pf[7];

    // ---------------- phase A: fc0 (128 x 256) over A ----------------
    {
        f32x4 accT[4][3];
        #pragma unroll
        for (int io = 0; io < 4; ++io)
            #pragma unroll
            for (int jc = 0; jc < 3; ++jc)
                accT[io][jc] = (f32x4){0.f,0.f,0.f,0.f};

        auto ldA = [&](int st, int u) -> const u16* {
            int cc = st*64;
            if (u < 1024) { int row = u >> 3, q = u & 7; return Wf0 + (size_t)row*256 + cc + q*8; }
            int uu = u - 1024;
            int row = uu >> 3, q = uu & 7;
            int m = b*6144 + (row >> 5)*2048 + n0 + (row & 31);
            return A_ + (size_t)m*256 + cc + q*8;
        };
        auto stA = [&](int u) -> char* {
            if (u < 1024) { int row = u >> 3, q = u & 7; return smem + SW + row*144 + q*16; }
            int uu = u - 1024;
            int row = uu >> 3, q = uu & 7;
            return smem + T_OFF + row*144 + q*16;   // SX region @0 (T not yet live)
        };

        #pragma unroll
        for (int j = 0; j < 7; ++j) pf[j] = *reinterpret_cast<const uint4v*>(ldA(0, tid + 256*j));
        #pragma unroll
        for (int j = 0; j < 7; ++j) *reinterpret_cast<uint4v*>(stA(tid + 256*j)) = pf[j];

        for (int st = 0; st < 4; ++st) {
            __syncthreads();
            if (st + 1 < 4) {
                #pragma unroll
                for (int j = 0; j < 7; ++j)
                    pf[j] = *reinterpret_cast<const uint4v*>(ldA(st+1, tid + 256*j));
            }
            #pragma unroll
            for (int ks = 0; ks < 2; ++ks) {
                half8 fA[4], fB[3];
                #pragma unroll
                for (int io = 0; io < 4; ++io)
                    fA[io] = *reinterpret_cast<const half8*>(smem + SW + (wr*64 + io*16 + l15)*144 + ks*64 + l4*16);
                #pragma unroll
                for (int i = 0; i < 3; ++i)
                    fB[i] = *reinterpret_cast<const half8*>(smem + T_OFF + (wc*48 + i*16 + l15)*144 + ks*64 + l4*16);
                #pragma unroll
                for (int io = 0; io < 4; ++io)
                    #pragma unroll
                    for (int jc = 0; jc < 3; ++jc)
                        accT[io][jc] = MFMAH(fA[io], fB[jc], accT[io][jc]);
            }
            __syncthreads();
            if (st + 1 < 4) {
                #pragma unroll
                for (int j = 0; j < 7; ++j)
                    *reinterpret_cast<uint4v*>(stA(tid + 256*j)) = pf[j];
            }
        }

        // transpose accT -> T (fp16 K-major) via sdT @U_OFF (U+SW dead)
        float* sdT = (float*)(smem + U_OFF);
        #pragma unroll
        for (int io = 0; io < 4; ++io)
            #pragma unroll
            for (int jc = 0; jc < 3; ++jc) {
                int jj = wc*48 + jc*16 + l15;
                int orow = wr*64 + io*16 + l4*4;
                *reinterpret_cast<f32x4*>(sdT + jj*132 + orow) = accT[io][jc];
            }
        __syncthreads();
        // 96 cols x 16 oc = 1536 tasks -> 6 reps
        #pragma unroll
        for (int rep = 0; rep < 6; ++rep) {
            int task = tid + 256*rep;
            int oc = task & 15, cidx = task >> 4;      // cidx 0..95
            const float* dp = sdT + cidx*132 + oc*8;
            u32 hw[4];
            #pragma unroll
            for (int e2 = 0; e2 < 4; ++e2)
                hw[e2] = (u32)f2h(dp[2*e2]) | ((u32)f2h(dp[2*e2+1]) << 16);
            *reinterpret_cast<uint4v*>(smem + T_OFF + cidx*272 + oc*16) =
                (uint4v){hw[0],hw[1],hw[2],hw[3]};
        }
        __syncthreads();
    }

    // ---------------- phase B: dir1 (128 x 128), B from T_lds ----------------
    f32x4 accD[4][3];
    #pragma unroll
    for (int io = 0; io < 4; ++io)
        #pragma unroll
        for (int jc = 0; jc < 3; ++jc)
            accD[io][jc] = (f32x4){0.f,0.f,0.f,0.f};
    {
        auto ldW = [&](int st, int u) -> const u16* {
            int row = u >> 3, q = u & 7;
            return Wd + (size_t)row*128 + st*64 + q*8;
        };
        #pragma unroll
        for (int j = 0; j < 4; ++j) pf[j] = *reinterpret_cast<const uint4v*>(ldW(0, tid + 256*j));
        #pragma unroll
        for (int j = 0; j < 4; ++j) { int u = tid + 256*j; int row = u >> 3, q = u & 7;
            *reinterpret_cast<uint4v*>(smem + SW + row*144 + q*16) = pf[j]; }

        for (int st = 0; st < 2; ++st) {
            __syncthreads();
            if (st + 1 < 2) {
                #pragma unroll
                for (int j = 0; j < 4; ++j)
                    pf[j] = *reinterpret_cast<const uint4v*>(ldW(st+1, tid + 256*j));
            }
            #pragma unroll
            for (int ks = 0; ks < 2; ++ks) {
                half8 fA[4], fB[3];
                #pragma unroll
                for (int io = 0; io < 4; ++io)
                    fA[io] = *reinterpret_cast<const half8*>(smem + SW + (wr*64 + io*16 + l15)*144 + ks*64 + l4*16);
                #pragma unroll
                for (int i = 0; i < 3; ++i)
                    fB[i] = *reinterpret_cast<const half8*>(smem + T_OFF + (wc*48 + i*16 + l15)*272 + st*128 + ks*64 + l4*16);
                #pragma unroll
                for (int io = 0; io < 4; ++io)
                    #pragma unroll
                    for (int jc = 0; jc < 3; ++jc)
                        accD[io][jc] = MFMAH(fA[io], fB[jc], accD[io][jc]);
            }
            __syncthreads();
            if (st + 1 < 2) {
                #pragma unroll
                for (int j = 0; j < 4; ++j) { int u = tid + 256*j; int row = u >> 3, q = u & 7;
                    *reinterpret_cast<uint4v*>(smem + SW + row*144 + q*16) = pf[j]; }
            }
        }
    }

    // ---- VN-leaky: accD -> sdT @U_OFF (f32 transpose), x from T_lds;
    //      U written in-place into the T region (1:1 slot, after read).
    {
        float* sdT = (float*)(smem + U_OFF);
        #pragma unroll
        for (int io = 0; io < 4; ++io)
            #pragma unroll
            for (int jc = 0; jc < 3; ++jc) {
                int jj = wc*48 + jc*16 + l15;
                int orow = wr*64 + io*16 + l4*4;
                *reinterpret_cast<f32x4*>(sdT + jj*132 + orow) = accD[io][jc];
            }
        __syncthreads();
        #pragma unroll
        for (int rep = 0; rep < 2; ++rep) {
            int task = tid + 256*rep;
            int oc = task & 15, nl = task >> 4;            // nl 0..31
            float d[3][8], x[3][8];
            #pragma unroll
            for (int v = 0; v < 3; ++v) {
                const float* dp = sdT + (v*32 + nl)*132 + oc*8;
                #pragma unroll
                for (int e = 0; e < 8; ++e) d[v][e] = dp[e];
                uint4v hx = *reinterpret_cast<const uint4v*>(smem + T_OFF + (v*32 + nl)*272 + oc*16);
                #pragma unroll
                for (int w = 0; w < 4; ++w) {
                    x[v][2*w]   = h2f((u16)(hx[w] & 0xffffu));
                    x[v][2*w+1] = h2f((u16)(hx[w] >> 16));
                }
            }
            #pragma unroll
            for (int e = 0; e < 8; ++e) {
                float d0 = d[0][e], d1 = d[1][e], d2 = d[2][e];
                float dot = x[0][e]*d0 + x[1][e]*d1 + x[2][e]*d2;
                float dsq = d0*d0 + d1*d1 + d2*d2;
                float t = dot / (dsq + EPSV);
                if (dot < 0.f) { x[0][e] -= t*d0; x[1][e] -= t*d1; x[2][e] -= t*d2; }
            }
            #pragma unroll
            for (int v = 0; v < 3; ++v) {
                u32 hw[4];
                #pragma unroll
                for (int e2 = 0; e2 < 4; ++e2)
                    hw[e2] = (u32)f2h(x[v][2*e2]) | ((u32)f2h(x[v][2*e2+1]) << 16);
                *reinterpret_cast<uint4v*>(smem + T_OFF + (v*32 + nl)*272 + oc*16) =
                    (uint4v){hw[0],hw[1],hw[2],hw[3]};
            }
        }
        __syncthreads();
    }
    // U now lives in the T region (@0, 272-stride).

    // ---------------- phase C: fc1 (K=128 from U@0) + sc (K=CSC staged) ----
    f32x4 acc2[4][3];
    #pragma unroll
    for (int io = 0; io < 4; ++io)
        #pragma unroll
        for (int jc = 0; jc < 3; ++jc) {
            int v = (wc*48 + jc*16) >> 5;
            #pragma unroll
            for (int r = 0; r < 4; ++r) {
                int o_l = wr*64 + io*16 + l4*4 + r;
                acc2[io][jc][r] = VIRT ? biasS_s[o_l*3 + v] : 0.f;
            }
        }

    constexpr int NS2 = 2 + CSC/64;
    auto ld2 = [&](int st, int u) -> const u16* {
        if (st < 2) {
            int row = u >> 3, q = u & 7;
            return Wf1 + (size_t)row*128 + st*64 + q*8;
        }
        int cc = (st - 2)*64;
        if (u < 1024) { int row = u >> 3, q = u & 7; return Wsc + (size_t)row*256 + cc + q*8; }
        int uu = u - 1024;
        int row = uu >> 3, q = uu & 7;
        int m = b*6144 + (row >> 5)*2048 + n0 + (row & 31);
        return Xs + (size_t)m*CSC + cc + q*8;
    };
    auto st2 = [&](int u) -> char* {
        if (u < 1024) { int row = u >> 3, q = u & 7; return smem + SW + row*144 + q*16; }
        int uu = u - 1024;
        int row = uu >> 3, q = uu & 7;
        return smem + U_OFF + row*144 + q*16;   // X stage @U_OFF (sdT dead)
    };

    #pragma unroll
    for (int j = 0; j < 7; ++j) { int u = tid + 256*j; if (u < 1024) pf[j] = *reinterpret_cast<const uint4v*>(ld2(0, u)); }
    #pragma unroll
    for (int j = 0; j < 7; ++j) { int u = tid + 256*j; if (u < 1024) *reinterpret_cast<uint4v*>(st2(u)) = pf[j]; }

    for (int st = 0; st < NS2; ++st) {
        __syncthreads();
        int nv = (st + 1 < 2) ? 1024 : 1792;
        if (st + 1 < NS2) {
            #pragma unroll
            for (int j = 0; j < 7; ++j) { int u = tid + 256*j; if (u < nv) pf[j] = *reinterpret_cast<const uint4v*>(ld2(st+1, u)); }
        }
        #pragma unroll
        for (int ks = 0; ks < 2; ++ks) {
            half8 fA[4], fB[3];
            #pragma unroll
            for (int io = 0; io < 4; ++io)
                fA[io] = *reinterpret_cast<const half8*>(smem + SW + (wr*64 + io*16 + l15)*144 + ks*64 + l4*16);
            if (st < 2) {
                #pragma unroll
                for (int i = 0; i < 3; ++i)
                    fB[i] = *reinterpret_cast<const half8*>(smem + T_OFF + (wc*48 + i*16 + l15)*272 + st*128 + ks*64 + l4*16);
            } else {
                #pragma unroll
                for (int i = 0; i < 3; ++i)
                    fB[i] = *reinterpret_cast<const half8*>(smem + U_OFF + (wc*48 + i*16 + l15)*144 + ks*64 + l4*16);
            }
            #pragma unroll
            for (int io = 0; io < 4; ++io)
                #pragma unroll
                for (int jc = 0; jc < 3; ++jc)
                    acc2[io][jc] = MFMAH(fA[io], fB[jc], acc2[io][jc]);
        }
        __syncthreads();
        if (st + 1 < NS2) {
            #pragma unroll
            for (int j = 0; j < 7; ++j) { int u = tid + 256*j; if (u < nv) *reinterpret_cast<uint4v*>(st2(u)) = pf[j]; }
        }
    }

    // ---- epilogue: Y write (optional) + pool (sd @0; U/T/stages dead)
    float* sdE = (float*)smem;
    #pragma unroll
    for (int io = 0; io < 4; ++io)
        #pragma unroll
        for (int jc = 0; jc < 3; ++jc) {
            int jj = wc*48 + jc*16 + l15;
            int orow = wr*64 + io*16 + l4*4;
            *reinterpret_cast<f32x4*>(sdE + jj*132 + orow) = acc2[io][jc];
        }
    __syncthreads();
    if (Y != nullptr) {
        #pragma unroll
        for (int rep = 0; rep < 2; ++rep) {
            int task = tid + 256*rep;
            int oc = task & 15, nl = (task >> 4) & 31;
            #pragma unroll
            for (int v = 0; v < 3; ++v) {
                const float* dp = sdE + (v*32 + nl)*132 + oc*8;
                u32 hw[4];
                #pragma unroll
                for (int e2 = 0; e2 < 4; ++e2)
                    hw[e2] = (u32)f2h(dp[2*e2]) | ((u32)f2h(dp[2*e2+1]) << 16);
                *reinterpret_cast<uint4v*>(Y + (size_t)(b*6144 + v*2048 + n0 + nl)*128 + oc*8) =
                    (uint4v){hw[0],hw[1],hw[2],hw[3]};
            }
        }
    }
    for (int t = tid; t < 384; t += 256) {
        int v = t >> 7, o_l = t & 127;
        float sum = 0.f;
        #pragma unroll 8
        for (int nl = 0; nl < 32; ++nl) sum += sdE[(v*32 + nl)*132 + o_l];
        atomicAdd(&PmOut[(size_t)(b*128 + o_l)*3 + v], sum * (1.f/(float)NPT));
    }
}

// ------------------------------------------------- weight fp16 convert
#define WO_FCPOS 0
#define WO_DIR0  32768
#define WO_FC0   360448
#define WO_DIR1  524288
#define WO_FC1   606208
#define WO_SC    688128
#define WTOT     851968
__global__ __launch_bounds__(256)
void convert_w_kernel(const float* __restrict__ s0, const float* __restrict__ s1,
                      const float* __restrict__ s2, const float* __restrict__ s3,
                      const float* __restrict__ s4, const float* __restrict__ s5,
                      u16* __restrict__ Wf) {
    int t = blockIdx.x*256 + threadIdx.x;
    if (t >= WTOT) return;
    const float* src; int base;
    if      (t < WO_DIR0) { src = s0; base = WO_FCPOS; }
    else if (t < WO_FC0)  { src = s1; base = WO_DIR0; }
    else if (t < WO_DIR1) { src = s2; base = WO_FC0; }
    else if (t < WO_FC1)  { src = s3; base = WO_DIR1; }
    else if (t < WO_SC)   { src = s4; base = WO_FC1; }
    else                  { src = s5; base = WO_SC; }
    Wf[t] = f2h(src[t - base]);
}

// ----------------------------------------------------- head: leaky(0.2)+fc_c
__global__ __launch_bounds__(128)
void final_head_kernel(const float* __restrict__ q, const float* __restrict__ Wdir,
                       const float* __restrict__ Wfc, float* __restrict__ out) {
    int b = blockIdx.x; int o = threadIdx.x;
    __shared__ float qs[128][3];
    __shared__ float zs[128][3];
    qs[o][0] = q[((size_t)b*128 + o)*3 + 0];
    qs[o][1] = q[((size_t)b*128 + o)*3 + 1];
    qs[o][2] = q[((size_t)b*128 + o)*3 + 2];
    __syncthreads();
    float d0 = 0.f, d1 = 0.f, d2 = 0.f;
    for (int c = 0; c < 128; ++c) {
        float w = Wdir[o*128 + c];
        d0 += w*qs[c][0]; d1 += w*qs[c][1]; d2 += w*qs[c][2];
    }
    float x0 = qs[o][0], x1 = qs[o][1], x2 = qs[o][2];
    float dot = d0*x0 + d1*x1 + d2*x2;
    float dsq = d0*d0 + d1*d1 + d2*d2;
    float t = dot / (dsq + EPSV);
    bool pos = dot >= 0.f;
    float g0 = pos ? x0 : (x0 - t*d0);
    float g1 = pos ? x1 : (x1 - t*d1);
    float g2 = pos ? x2 : (x2 - t*d2);
    zs[o][0] = 0.2f*x0 + 0.8f*g0;
    zs[o][1] = 0.2f*x1 + 0.8f*g1;
    zs[o][2] = 0.2f*x2 + 0.8f*g2;
    __syncthreads();
    float c0 = 0.f, c1 = 0.f, c2 = 0.f;
    for (int c = 0; c < 128; ++c) {
        float w = Wfc[o*128 + c];
        c0 += w*zs[c][0]; c1 += w*zs[c][1]; c2 += w*zs[c][2];
    }
    out[((size_t)b*128 + o)*3 + 0] = c0;
    out[((size_t)b*128 + o)*3 + 1] = c1;
    out[((size_t)b*128 + o)*3 + 2] = c2;
}

extern "C" void kernel_launch(void* const* d_in, const int* in_sizes, int n_in,
                              void* d_out, int out_size, void* d_ws, size_t ws_size,
                              hipStream_t stream) {
    const float* p           = (const float*)d_in[0];
    const float* w_conv_feat = (const float*)d_in[1];
    const float* w_conv_dir  = (const float*)d_in[2];
    const float* w_fc_pos    = (const float*)d_in[3];
    const float* blk_dir0    = (const float*)d_in[4];
    const float* blk_fc0     = (const float*)d_in[5];
    const float* blk_dir1    = (const float*)d_in[6];
    const float* blk_fc1     = (const float*)d_in[7];
    const float* blk_sc      = (const float*)d_in[8];
    const float* w_actc_dir  = (const float*)d_in[9];
    const float* w_fc_c      = (const float*)d_in[10];
    float* out = (float*)d_out;

    char* wsb = (char*)d_ws;
    size_t cur = 0;
    auto carve = [&](size_t nbytes) -> char* {
        char* r = wsb + cur;
        cur += (nbytes + 255) & ~(size_t)255;
        return r;
    };
    const size_t MTOT = (size_t)BB*3*NPT;      // 24576 columns
    float* Pm0   = (float*)carve(1536*4);
    float* Pm1   = (float*)carve(1536*4);
    u16* Wf    = (u16*)carve((size_t)WTOT*2);
    u16* net1  = (u16*)carve(MTOT*128*2);      // fc_pos input
    u16* X0    = (u16*)carve(MTOT*256*2);      // fc_pos out; later Y ping
    u16* Ab    = (u16*)carve(MTOT*256*2);      // A (dir0 out)
    u16* Yb    = (u16*)carve(MTOT*128*2);      // Y pong
    float* PmBuf[2] = { Pm0, Pm1 };

    convert_w_kernel<<<(WTOT+255)/256, 256, 0, stream>>>(
        w_fc_pos, blk_dir0, blk_fc0, blk_dir1, blk_fc1, blk_sc, Wf);
    knn_edge_kernel<<<BB*NPT, 256, 0, stream>>>(p, w_conv_feat, w_conv_dir, net1);

    // fc_pos: [256 x 128] x net1 -> X0
    gemm_plain<256,128,0,false,false><<<dim3(384,2), 256, 0, stream>>>(
        Wf+WO_FCPOS, 128, net1, 128,
        nullptr, 0, nullptr, 0,
        nullptr, nullptr, X0, 256, nullptr);

    const u16* Yp = nullptr;
    for (int i = 0; i < 5; ++i) {
        size_t od0 = WO_DIR0 + (size_t)i*65536;
        size_t of0 = WO_FC0  + (size_t)i*32768;
        size_t od1 = WO_DIR1 + (size_t)i*16384;
        size_t of1 = WO_FC1  + (size_t)i*16384;
        size_t osc = WO_SC   + (size_t)i*32768;
        float* PmPrev = PmBuf[(i+1) & 1];
        float* PmCur  = PmBuf[i & 1];

        // dir0 also zeroes all 1536 floats of PmCur (block 0) — replaces memset.
        if (i == 0) {
            gemm_dir<256,256,false><<<dim3(BB*64,2), 256, 0, stream>>>(
                Wf+od0, 256, X0, 256, nullptr, nullptr, Ab, 256, PmCur);
        } else {
            gemm_dir<256,128,true><<<dim3(BB*64,2), 256, 0, stream>>>(
                Wf+od0, 256, Yp, 128,
                blk_dir0 + (size_t)i*65536, PmPrev, Ab, 256, PmCur);
        }

        u16* outv = (i == 4) ? nullptr : ((i % 2 == 0) ? Yb : X0);
        if (i == 0) {
            fused_back<256,false><<<BB*64, 256, 0, stream>>>(
                Wf+of0, Wf+od1, Wf+of1, Wf+osc, nullptr,
                Ab, X0, nullptr, outv, PmCur);
        } else {
            fused_back<128,true><<<BB*64, 256, 0, stream>>>(
                Wf+of0, Wf+od1, Wf+of1, Wf+osc, blk_sc + (size_t)i*32768,
                Ab, Yp, PmPrev, outv, PmCur);
        }
        Yp = outv;
    }

    final_head_kernel<<<BB, 128, 0, stream>>>(PmBuf[0], w_actc_dir, w_fc_c, out);
}